// Round 1
// baseline (849.618 us; speedup 1.0000x reference)
//
#include <hip/hip_runtime.h>
#include <math.h>

// Dims (fixed by problem): B=2, N=4096, C=256, nc=150, T=4, TN=16384, heads=8, hd=32, hid=1024, H=W=64

// ---------------- block reduction helpers (blockDim.x == 256) ----------------
__device__ __forceinline__ float bred_sum(float v, float* red) {
  int tid = threadIdx.x;
  red[tid] = v; __syncthreads();
  #pragma unroll
  for (int s = 128; s > 0; s >>= 1) {
    if (tid < s) red[tid] += red[tid + s];
    __syncthreads();
  }
  float r = red[0]; __syncthreads();
  return r;
}
__device__ __forceinline__ float bred_max(float v, float* red) {
  int tid = threadIdx.x;
  red[tid] = v; __syncthreads();
  #pragma unroll
  for (int s = 128; s > 0; s >>= 1) {
    if (tid < s) red[tid] = fmaxf(red[tid], red[tid + s]);
    __syncthreads();
  }
  float r = red[0]; __syncthreads();
  return r;
}

// ---------------- generic fp32 GEMM: out[m][n] = alpha*(sum_k A[m,k]*W[n,k] + bias[n]) ----------------
// tile 128M x 64N, K-chunk 16, 256 threads, 8x4 acc/thread
__global__ __launch_bounds__(256) void gemm_nt(
    const float* __restrict__ A, const float* __restrict__ W,
    const float* __restrict__ bias, float* __restrict__ out,
    int M, int N, int K, float alpha)
{
  __shared__ __align__(16) float As[16][132];
  __shared__ __align__(16) float Ws[16][68];
  const int tid = threadIdx.x;
  const int m0 = blockIdx.x * 128;
  const int n0 = blockIdx.y * 64;
  const int tm = tid & 15;   // rows tm*8..+7
  const int tn = tid >> 4;   // cols tn*4..+3
  float acc[8][4];
  #pragma unroll
  for (int i = 0; i < 8; ++i)
    #pragma unroll
    for (int j = 0; j < 4; ++j) acc[i][j] = 0.f;

  const int lr = tid >> 2;        // 0..63
  const int lk = (tid & 3) * 4;   // 0,4,8,12

  for (int k0 = 0; k0 < K; k0 += 16) {
    #pragma unroll
    for (int p = 0; p < 2; ++p) {
      int r = lr + p * 64;
      int gm = m0 + r;
      float4 v = make_float4(0.f, 0.f, 0.f, 0.f);
      if (gm < M) v = *(const float4*)&A[(size_t)gm * K + k0 + lk];
      As[lk + 0][r] = v.x; As[lk + 1][r] = v.y; As[lk + 2][r] = v.z; As[lk + 3][r] = v.w;
    }
    {
      float4 v = *(const float4*)&W[(size_t)(n0 + lr) * K + k0 + lk];
      Ws[lk + 0][lr] = v.x; Ws[lk + 1][lr] = v.y; Ws[lk + 2][lr] = v.z; Ws[lk + 3][lr] = v.w;
    }
    __syncthreads();
    #pragma unroll
    for (int kk = 0; kk < 16; ++kk) {
      float4 a0 = *(const float4*)&As[kk][tm * 8];
      float4 a1 = *(const float4*)&As[kk][tm * 8 + 4];
      float4 w0 = *(const float4*)&Ws[kk][tn * 4];
      float av[8] = {a0.x, a0.y, a0.z, a0.w, a1.x, a1.y, a1.z, a1.w};
      float wv[4] = {w0.x, w0.y, w0.z, w0.w};
      #pragma unroll
      for (int i = 0; i < 8; ++i)
        #pragma unroll
        for (int j = 0; j < 4; ++j)
          acc[i][j] = fmaf(av[i], wv[j], acc[i][j]);
    }
    __syncthreads();
  }
  float4 bv = *(const float4*)&bias[n0 + tn * 4];
  float bb[4] = {bv.x, bv.y, bv.z, bv.w};
  #pragma unroll
  for (int i = 0; i < 8; ++i) {
    int gm = m0 + tm * 8 + i;
    if (gm >= M) continue;
    float4 r;
    r.x = alpha * (acc[i][0] + bb[0]);
    r.y = alpha * (acc[i][1] + bb[1]);
    r.z = alpha * (acc[i][2] + bb[2]);
    r.w = alpha * (acc[i][3] + bb[3]);
    *(float4*)&out[(size_t)gm * N + n0 + tn * 4] = r;
  }
}

// ---------------- cl[b][k][ti*4096+n] = sum_c xf[b,ti,n,c]*cw[k,c] ----------------
__global__ __launch_bounds__(256) void gemm_cl(
    const float* __restrict__ x, const float* __restrict__ mem,
    const float* __restrict__ cw, float* __restrict__ cl)
{
  __shared__ __align__(16) float As[16][132];
  __shared__ __align__(16) float Ws[16][68];
  const int tid = threadIdx.x;
  const int m0 = blockIdx.x * 128;        // global row over (b,ti,n)
  const int n0 = blockIdx.y * 64;         // cluster col
  const int bt = m0 >> 12;
  const int b = bt >> 2, ti = bt & 3;
  const int nbase = m0 & 4095;
  const float* Abase = (ti < 3) ? (mem + (size_t)(b * 3 + ti) * 4096 * 256)
                                : (x + (size_t)b * 4096 * 256);
  const int tm = tid & 15, tn = tid >> 4;
  float acc[8][4];
  #pragma unroll
  for (int i = 0; i < 8; ++i)
    #pragma unroll
    for (int j = 0; j < 4; ++j) acc[i][j] = 0.f;
  const int lr = tid >> 2, lk = (tid & 3) * 4;
  for (int k0 = 0; k0 < 256; k0 += 16) {
    #pragma unroll
    for (int p = 0; p < 2; ++p) {
      int r = lr + p * 64;
      float4 v = *(const float4*)&Abase[(size_t)(nbase + r) * 256 + k0 + lk];
      As[lk + 0][r] = v.x; As[lk + 1][r] = v.y; As[lk + 2][r] = v.z; As[lk + 3][r] = v.w;
    }
    {
      int gn = n0 + lr;
      float4 v = make_float4(0.f, 0.f, 0.f, 0.f);
      if (gn < 150) v = *(const float4*)&cw[(size_t)gn * 256 + k0 + lk];
      Ws[lk + 0][lr] = v.x; Ws[lk + 1][lr] = v.y; Ws[lk + 2][lr] = v.z; Ws[lk + 3][lr] = v.w;
    }
    __syncthreads();
    #pragma unroll
    for (int kk = 0; kk < 16; ++kk) {
      float4 a0 = *(const float4*)&As[kk][tm * 8];
      float4 a1 = *(const float4*)&As[kk][tm * 8 + 4];
      float4 w0 = *(const float4*)&Ws[kk][tn * 4];
      float av[8] = {a0.x, a0.y, a0.z, a0.w, a1.x, a1.y, a1.z, a1.w};
      float wv[4] = {w0.x, w0.y, w0.z, w0.w};
      #pragma unroll
      for (int i = 0; i < 8; ++i)
        #pragma unroll
        for (int j = 0; j < 4; ++j)
          acc[i][j] = fmaf(av[i], wv[j], acc[i][j]);
    }
    __syncthreads();
  }
  #pragma unroll
  for (int j = 0; j < 4; ++j) {
    int kc = n0 + tn * 4 + j;
    if (kc >= 150) continue;
    float4 r0 = make_float4(acc[0][j], acc[1][j], acc[2][j], acc[3][j]);
    float4 r1 = make_float4(acc[4][j], acc[5][j], acc[6][j], acc[7][j]);
    float* dst = cl + ((size_t)b * 150 + kc) * 16384 + ti * 4096 + nbase + tm * 8;
    *(float4*)&dst[0] = r0;
    *(float4*)&dst[4] = r1;
  }
}

// ---------------- per-column cosine clip factors ----------------
__global__ __launch_bounds__(256) void cos_stats(
    const float* __restrict__ z, const float* __restrict__ cl,
    const float* __restrict__ p1, const float* __restrict__ p2,
    float* __restrict__ cosz, float* __restrict__ coscl)
{
  int gid = blockIdx.x * 256 + threadIdx.x;  // 0..32767
  int b = gid >> 14, m = gid & 16383;
  const float* zp = z + (size_t)b * 150 * 16384 + m;
  const float* cp = cl + (size_t)b * 150 * 16384 + m;
  float d1 = 0, s1 = 0, pn1 = 0, d2 = 0, s2 = 0, pn2 = 0;
  for (int k = 0; k < 150; ++k) {
    float zv = zp[(size_t)k * 16384];
    float cv = cp[(size_t)k * 16384];
    float a = p1[k], bq = p2[k];
    d1 += zv * a;  s1 += zv * zv;  pn1 += a * a;
    d2 += cv * bq; s2 += cv * cv;  pn2 += bq * bq;
  }
  float c1 = d1 / (fmaxf(sqrtf(s1), 1e-12f) * fmaxf(sqrtf(pn1), 1e-12f));
  float c2 = d2 / (fmaxf(sqrtf(s2), 1e-12f) * fmaxf(sqrtf(pn2), 1e-12f));
  cosz[gid]  = fminf(fmaxf(c1, 0.f), 1.f);
  coscl[gid] = fminf(fmaxf(c2, 0.f), 1.f);
}

// ---------------- fused K=300 GEMM: csz[b][k'][m] = 0.5*(coscl*cl@tdt2 + cosz*z@tdt1); also writes assigned ----------------
__global__ __launch_bounds__(256) void gemm_csz(
    const float* __restrict__ cl, const float* __restrict__ z,
    const float* __restrict__ coscl, const float* __restrict__ cosz,
    const float* __restrict__ tdt2, const float* __restrict__ tdt1,
    float* __restrict__ csz, float* __restrict__ asg)
{
  __shared__ __align__(16) float As[16][132];
  __shared__ __align__(16) float Ws[16][68];
  const int tid = threadIdx.x;
  const int m0 = blockIdx.x * 128;
  const int b = m0 >> 14;
  const int mm = m0 & 16383;
  const int n0 = blockIdx.y * 64;
  const int tm = tid & 15, tn = tid >> 4;
  float acc[8][4];
  #pragma unroll
  for (int i = 0; i < 8; ++i)
    #pragma unroll
    for (int j = 0; j < 4; ++j) acc[i][j] = 0.f;
  const int amr = (tid & 31) * 4;
  const int akk = tid >> 5;        // 0..7
  const int wnn = (tid & 15) * 4;
  const int wkk = tid >> 4;        // 0..15
  for (int k0 = 0; k0 < 300; k0 += 16) {
    #pragma unroll
    for (int p = 0; p < 2; ++p) {
      int kki = akk + p * 8;
      int kg = k0 + kki;
      float4 v = make_float4(0.f, 0.f, 0.f, 0.f);
      if (kg < 150) {
        v = *(const float4*)&cl[((size_t)b * 150 + kg) * 16384 + mm + amr];
        float4 cs = *(const float4*)&coscl[(size_t)b * 16384 + mm + amr];
        v.x *= cs.x; v.y *= cs.y; v.z *= cs.z; v.w *= cs.w;
      } else if (kg < 300) {
        v = *(const float4*)&z[((size_t)b * 150 + (kg - 150)) * 16384 + mm + amr];
        float4 cs = *(const float4*)&cosz[(size_t)b * 16384 + mm + amr];
        v.x *= cs.x; v.y *= cs.y; v.z *= cs.z; v.w *= cs.w;
      }
      *(float4*)&As[kki][amr] = v;
    }
    {
      int kg = k0 + wkk;
      #pragma unroll
      for (int j = 0; j < 4; ++j) {
        int gn = n0 + wnn + j;
        float t = 0.f;
        if (gn < 150) {
          if (kg < 150) t = tdt2[kg * 150 + gn];
          else if (kg < 300) t = tdt1[(kg - 150) * 150 + gn];
        }
        Ws[wkk][wnn + j] = t;
      }
    }
    __syncthreads();
    #pragma unroll
    for (int kk = 0; kk < 16; ++kk) {
      float4 a0 = *(const float4*)&As[kk][tm * 8];
      float4 a1 = *(const float4*)&As[kk][tm * 8 + 4];
      float4 w0 = *(const float4*)&Ws[kk][tn * 4];
      float av[8] = {a0.x, a0.y, a0.z, a0.w, a1.x, a1.y, a1.z, a1.w};
      float wv[4] = {w0.x, w0.y, w0.z, w0.w};
      #pragma unroll
      for (int i = 0; i < 8; ++i)
        #pragma unroll
        for (int j = 0; j < 4; ++j)
          acc[i][j] = fmaf(av[i], wv[j], acc[i][j]);
    }
    __syncthreads();
  }
  const int ti = mm >> 12;
  const int nn = mm & 4095;
  #pragma unroll
  for (int j = 0; j < 4; ++j) {
    int kc = n0 + tn * 4 + j;
    if (kc >= 150) continue;
    float4 r0 = make_float4(0.5f * acc[0][j], 0.5f * acc[1][j], 0.5f * acc[2][j], 0.5f * acc[3][j]);
    float4 r1 = make_float4(0.5f * acc[4][j], 0.5f * acc[5][j], 0.5f * acc[6][j], 0.5f * acc[7][j]);
    size_t o1 = ((size_t)b * 150 + kc) * 16384 + mm + tm * 8;
    *(float4*)&csz[o1] = r0;
    *(float4*)&csz[o1 + 4] = r1;
    size_t o2 = (((size_t)b * 4 + ti) * 150 + kc) * 4096 + nn + tm * 8;
    *(float4*)&asg[o2] = r0;
    *(float4*)&asg[o2 + 4] = r1;
  }
}

// ---------------- softmax stats per (b,ti,k) row of 4096 ----------------
__global__ __launch_bounds__(256) void softmax_stats(
    const float* __restrict__ csz, float* __restrict__ mr, float* __restrict__ lr_)
{
  __shared__ float red[256];
  int row = blockIdx.x;           // bt*150 + k
  int bt = row / 150, k = row % 150;
  int b = bt >> 2, ti = bt & 3;
  const float* p = csz + ((size_t)b * 150 + k) * 16384 + ti * 4096;
  float v[16];
  float mx = -1e30f;
  #pragma unroll
  for (int i = 0; i < 16; ++i) { v[i] = p[i * 256 + threadIdx.x]; mx = fmaxf(mx, v[i]); }
  mx = bred_max(mx, red);
  float s = 0.f;
  #pragma unroll
  for (int i = 0; i < 16; ++i) s += expf(v[i] - mx);
  s = bred_sum(s, red);
  if (threadIdx.x == 0) { mr[row] = mx; lr_[row] = s; }
}

// ---------------- cen partials: part[sp][bt][k][c] = sum_{n in split} exp(center-m)*xf[n][c] ----------------
__global__ __launch_bounds__(256) void gemm_cen(
    const float* __restrict__ csz, const float* __restrict__ x, const float* __restrict__ mem,
    const float* __restrict__ mr, float* __restrict__ part)
{
  __shared__ __align__(16) float As[32][164];
  __shared__ __align__(16) float Bs[32][36];
  const int tid = threadIdx.x;
  const int c0 = blockIdx.x * 32;
  const int bt = blockIdx.y;
  const int sp = blockIdx.z;
  const int b = bt >> 2, ti = bt & 3;
  const float* xf = (ti < 3) ? (mem + (size_t)(b * 3 + ti) * 4096 * 256)
                             : (x + (size_t)b * 4096 * 256);
  const float* crow = csz + (size_t)b * 150 * 16384 + ti * 4096;
  const int tmr = tid >> 3;   // 0..31
  const int tnc = tid & 7;    // 0..7
  float acc[5][4];
  #pragma unroll
  for (int i = 0; i < 5; ++i)
    #pragma unroll
    for (int j = 0; j < 4; ++j) acc[i][j] = 0.f;
  const int ann = tnc * 4;
  for (int n0 = sp * 1024; n0 < sp * 1024 + 1024; n0 += 32) {
    #pragma unroll
    for (int p = 0; p < 5; ++p) {
      int kcl = tmr + p * 32;   // 0..159
      float4 v = make_float4(0.f, 0.f, 0.f, 0.f);
      if (kcl < 150) {
        v = *(const float4*)&crow[(size_t)kcl * 16384 + n0 + ann];
        float mrv = mr[bt * 150 + kcl];
        v.x = expf(v.x - mrv); v.y = expf(v.y - mrv); v.z = expf(v.z - mrv); v.w = expf(v.w - mrv);
      }
      As[ann + 0][kcl] = v.x; As[ann + 1][kcl] = v.y; As[ann + 2][kcl] = v.z; As[ann + 3][kcl] = v.w;
    }
    {
      int nr = tid >> 3;
      int cc = (tid & 7) * 4;
      float4 v = *(const float4*)&xf[(size_t)(n0 + nr) * 256 + c0 + cc];
      *(float4*)&Bs[nr][cc] = v;
    }
    __syncthreads();
    #pragma unroll
    for (int kk = 0; kk < 32; ++kk) {
      float4 bv = *(const float4*)&Bs[kk][tnc * 4];
      #pragma unroll
      for (int i = 0; i < 5; ++i) {
        float a = As[kk][tmr * 5 + i];
        acc[i][0] = fmaf(a, bv.x, acc[i][0]);
        acc[i][1] = fmaf(a, bv.y, acc[i][1]);
        acc[i][2] = fmaf(a, bv.z, acc[i][2]);
        acc[i][3] = fmaf(a, bv.w, acc[i][3]);
      }
    }
    __syncthreads();
  }
  #pragma unroll
  for (int i = 0; i < 5; ++i) {
    int kcl = tmr * 5 + i;
    if (kcl >= 150) continue;
    float4 r = make_float4(acc[i][0], acc[i][1], acc[i][2], acc[i][3]);
    *(float4*)&part[(((size_t)sp * 8 + bt) * 150 + kcl) * 256 + c0 + tnc * 4] = r;
  }
}

__global__ __launch_bounds__(256) void reduce_cen(
    const float* __restrict__ part, const float* __restrict__ lr_, float* __restrict__ cen)
{
  int row = blockIdx.x;  // 0..1199 = bt*150+k
  int c = threadIdx.x;
  float s = 0.f;
  #pragma unroll
  for (int sp = 0; sp < 4; ++sp)
    s += part[((size_t)sp * 1200 + row) * 256 + c];
  cen[(size_t)row * 256 + c] = s / lr_[row];
}

// ---------------- similarity gate + LN -> C_in ----------------
__global__ __launch_bounds__(256) void gate_ln(
    const float* __restrict__ cen, const float* __restrict__ alpha_, const float* __restrict__ beta_,
    const float* __restrict__ nw, const float* __restrict__ nb, float* __restrict__ cin)
{
  __shared__ float red[256];
  int bk = blockIdx.x;       // b*150 + k
  int b = bk / 150, k = bk % 150;
  int c = threadIdx.x;
  const float* base = cen + ((size_t)b * 4 * 150) * 256;
  float lc  = base[((size_t)3 * 150 + k) * 256 + c];
  float p0  = base[((size_t)0 * 150 + k) * 256 + c];
  float p1v = base[((size_t)1 * 150 + k) * 256 + c];
  float p2v = base[((size_t)2 * 150 + k) * 256 + c];
  float nl = bred_sum(lc * lc, red);
  float q0 = bred_sum(p0 * p0, red);
  float q1 = bred_sum(p1v * p1v, red);
  float q2 = bred_sum(p2v * p2v, red);
  float d0 = bred_sum(lc * p0, red);
  float d1 = bred_sum(lc * p1v, red);
  float d2 = bred_sum(lc * p2v, red);
  float al = alpha_[0], be = beta_[0];
  float snl = sqrtf(nl);
  float g0 = 1.f / (1.f + expf(-(be + al * (d0 / fmaxf(snl * sqrtf(q0), 1e-8f)))));
  float g1 = 1.f / (1.f + expf(-(be + al * (d1 / fmaxf(snl * sqrtf(q1), 1e-8f)))));
  float g2 = 1.f / (1.f + expf(-(be + al * (d2 / fmaxf(snl * sqrtf(q2), 1e-8f)))));
  float ci = lc + g0 * p0 + g1 * p1v + g2 * p2v;
  float mu = bred_sum(ci, red) * (1.f / 256.f);
  float df = ci - mu;
  float var = bred_sum(df * df, red) * (1.f / 256.f);
  cin[(size_t)bk * 256 + c] = df * rsqrtf(var + 1e-5f) * nw[c] + nb[c];
}

// ---------------- attention: per (b,h) q(4096x32) vs K/V(150x32) ----------------
__global__ __launch_bounds__(128) void attn_k(
    const float* __restrict__ q, const float* __restrict__ ks, const float* __restrict__ vs,
    float* __restrict__ o)
{
  __shared__ float Ks[150][32];
  __shared__ float Vs[150][32];
  int bid = blockIdx.x;
  int ntile = bid & 31, bh = bid >> 5;
  int b = bh >> 3, h = bh & 7;
  for (int idx = threadIdx.x; idx < 4800; idx += 128) {
    int kc = idx >> 5, d = idx & 31;
    Ks[kc][d] = ks[((size_t)b * 150 + kc) * 256 + h * 32 + d];
    Vs[kc][d] = vs[((size_t)b * 150 + kc) * 256 + h * 32 + d];
  }
  __syncthreads();
  int n = ntile * 128 + threadIdx.x;
  const float* qp = q + ((size_t)b * 4096 + n) * 256 + h * 32;
  float qr[32];
  #pragma unroll
  for (int d4 = 0; d4 < 8; ++d4) {
    float4 v = *(const float4*)&qp[d4 * 4];
    qr[d4 * 4 + 0] = v.x; qr[d4 * 4 + 1] = v.y; qr[d4 * 4 + 2] = v.z; qr[d4 * 4 + 3] = v.w;
  }
  float m = -1e30f, l = 0.f;
  for (int kc = 0; kc < 150; ++kc) {
    float s = 0.f;
    #pragma unroll
    for (int d = 0; d < 32; ++d) s = fmaf(qr[d], Ks[kc][d], s);
    float nm = fmaxf(m, s);
    l = l * expf(m - nm) + expf(s - nm);
    m = nm;
  }
  float inv = 1.f / l;
  float acc[32];
  #pragma unroll
  for (int d = 0; d < 32; ++d) acc[d] = 0.f;
  for (int kc = 0; kc < 150; ++kc) {
    float s = 0.f;
    #pragma unroll
    for (int d = 0; d < 32; ++d) s = fmaf(qr[d], Ks[kc][d], s);
    float w = expf(s - m);
    #pragma unroll
    for (int d = 0; d < 32; ++d) acc[d] = fmaf(w, Vs[kc][d], acc[d]);
  }
  float* op = o + ((size_t)b * 4096 + n) * 256 + h * 32;
  #pragma unroll
  for (int d4 = 0; d4 < 8; ++d4) {
    float4 v = make_float4(acc[d4 * 4] * inv, acc[d4 * 4 + 1] * inv,
                           acc[d4 * 4 + 2] * inv, acc[d4 * 4 + 3] * inv);
    *(float4*)&op[d4 * 4] = v;
  }
}

// ---------------- dst = res + LN(src) ----------------
__global__ __launch_bounds__(256) void ln_res(
    const float* __restrict__ src, const float* __restrict__ res,
    const float* __restrict__ nw, const float* __restrict__ nb, float* __restrict__ dst)
{
  __shared__ float red[256];
  size_t row = blockIdx.x;
  int c = threadIdx.x;
  float v = src[row * 256 + c];
  float mu = bred_sum(v, red) * (1.f / 256.f);
  float df = v - mu;
  float var = bred_sum(df * df, red) * (1.f / 256.f);
  dst[row * 256 + c] = res[row * 256 + c] + df * rsqrtf(var + 1e-5f) * nw[c] + nb[c];
}

// ---------------- depthwise 3x3 conv + bias + exact gelu ----------------
__global__ __launch_bounds__(256) void conv_gelu(
    const float* __restrict__ h, const float* __restrict__ w, const float* __restrict__ bias,
    float* __restrict__ hc)
{
  int bid = blockIdx.x;
  int chunk = bid & 3;
  int pix = bid >> 2;             // 0..8191
  int b = pix >> 12;
  int n = pix & 4095;
  int y = n >> 6, xx = n & 63;
  int ch = chunk * 256 + threadIdx.x;
  float acc = bias[ch];
  #pragma unroll
  for (int dy = 0; dy < 3; ++dy) {
    int yy = y + dy - 1;
    if (yy < 0 || yy > 63) continue;
    #pragma unroll
    for (int dx = 0; dx < 3; ++dx) {
      int xv = xx + dx - 1;
      if (xv < 0 || xv > 63) continue;
      acc = fmaf(h[((size_t)b * 4096 + yy * 64 + xv) * 1024 + ch], w[ch * 9 + dy * 3 + dx], acc);
    }
  }
  float g = 0.5f * acc * (1.f + erff(acc * 0.70710678118654752f));
  hc[((size_t)b * 4096 + n) * 1024 + ch] = g;
}

extern "C" void kernel_launch(void* const* d_in, const int* in_sizes, int n_in,
                              void* d_out, int out_size, void* d_ws, size_t ws_size,
                              hipStream_t stream)
{
  (void)in_sizes; (void)n_in; (void)out_size; (void)ws_size;
  const float* x    = (const float*)d_in[0];
  const float* z    = (const float*)d_in[1];
  const float* mem  = (const float*)d_in[2];
  const float* cw   = (const float*)d_in[3];
  const float* p1   = (const float*)d_in[4];
  const float* tdt1 = (const float*)d_in[5];
  const float* p2   = (const float*)d_in[6];
  const float* tdt2 = (const float*)d_in[7];
  const float* sal  = (const float*)d_in[8];
  const float* sbe  = (const float*)d_in[9];
  const float* q_w  = (const float*)d_in[10];
  const float* q_b  = (const float*)d_in[11];
  const float* k_w  = (const float*)d_in[12];
  const float* k_b  = (const float*)d_in[13];
  const float* v_w  = (const float*)d_in[14];
  const float* v_b  = (const float*)d_in[15];
  const float* pj_w = (const float*)d_in[16];
  const float* pj_b = (const float*)d_in[17];
  const float* nw   = (const float*)d_in[18];
  const float* nb   = (const float*)d_in[19];
  const float* f1w  = (const float*)d_in[20];
  const float* f1b  = (const float*)d_in[21];
  const float* dww  = (const float*)d_in[22];
  const float* dwb  = (const float*)d_in[23];
  const float* f2w  = (const float*)d_in[24];
  const float* f2b  = (const float*)d_in[25];

  float* out = (float*)d_out;                  // (2,4096,256)
  float* csz = out + 2097152;                  // (2,150,16384)
  float* asg = csz + 4915200;                  // (2,4,150,4096)

  // workspace layout (floats); total 21,029,888 floats = 84.1 MB, with safe reuse
  float* ws    = (float*)d_ws;
  float* cl    = ws;                 // 4,915,200   dead after gemm_csz
  float* coscl = ws + 4915200;       // 32,768
  float* cosz  = ws + 4948000;       // 32,768
  float* mr    = ws + 4980800;       // 1,200
  float* lr_   = ws + 4982016;       // 1,200
  float* part  = ws + 4983232;       // 1,228,800
  float* cen   = ws + 6212032;       // 307,200
  float* cin   = ws + 6519232;       // 76,800
  float* q     = ws + 6596032;       // 2,097,152   dead after attn
  float* ksb   = ws + 8693184;       // 76,800      dead after attn
  float* vsb   = ws + 8769984;       // 76,800      dead after attn
  float* o     = ws + 8846784;       // 2,097,152   dead after proj gemm
  float* h     = ws;                 // 8,388,608   (reuses cl..q region, all dead by then)
  float* hc    = ws + 8446976;       // 8,388,608   (reuses q tail/k/v/o, all dead)
  float* tmp   = ws + 16835584;      // 2,097,152
  float* out1  = ws + 18932736;      // 2,097,152

  dim3 blk(256);
  // 1. cl = xf @ cw^T  (written in (B,nc,T*N) layout)
  gemm_cl<<<dim3(256, 3), blk, 0, stream>>>(x, mem, cw, cl);
  // 2. cosine clip factors
  cos_stats<<<dim3(128), blk, 0, stream>>>(z, cl, p1, p2, cosz, coscl);
  // 3. cluster_x_z + assigned (fused K=300 GEMM)
  gemm_csz<<<dim3(256, 3), blk, 0, stream>>>(cl, z, coscl, cosz, tdt2, tdt1, csz, asg);
  // 4. softmax stats over N
  softmax_stats<<<dim3(1200), blk, 0, stream>>>(csz, mr, lr_);
  // 5. cen = softmax(center) @ xf  (split-K x4)
  gemm_cen<<<dim3(8, 8, 4), blk, 0, stream>>>(csz, x, mem, mr, part);
  reduce_cen<<<dim3(1200), blk, 0, stream>>>(part, lr_, cen);
  // 6. gate + LN -> C_in
  gate_ln<<<dim3(300), blk, 0, stream>>>(cen, sal, sbe, nw, nb, cin);
  // 7. q/k/v
  gemm_nt<<<dim3(64, 4), blk, 0, stream>>>(x, q_w, q_b, q, 8192, 256, 256, 0.17677669529663687f);
  gemm_nt<<<dim3(3, 4), blk, 0, stream>>>(cin, k_w, k_b, ksb, 300, 256, 256, 1.f);
  gemm_nt<<<dim3(3, 4), blk, 0, stream>>>(cin, v_w, v_b, vsb, 300, 256, 256, 1.f);
  // 8. attention
  attn_k<<<dim3(512), dim3(128), 0, stream>>>(q, ksb, vsb, o);
  // 9. proj + LN + residual
  gemm_nt<<<dim3(64, 4), blk, 0, stream>>>(o, pj_w, pj_b, tmp, 8192, 256, 256, 1.f);
  ln_res<<<dim3(8192), blk, 0, stream>>>(tmp, x, nw, nb, out1);
  // 10. MLP with depthwise conv
  gemm_nt<<<dim3(64, 16), blk, 0, stream>>>(out1, f1w, f1b, h, 8192, 1024, 256, 1.f);
  conv_gelu<<<dim3(32768), blk, 0, stream>>>(h, dww, dwb, hc);
  gemm_nt<<<dim3(64, 4), blk, 0, stream>>>(hc, f2w, f2b, tmp, 8192, 256, 1024, 1.f);
  ln_res<<<dim3(8192), blk, 0, stream>>>(tmp, out1, nw, nb, out);
}

// Round 2
// 751.675 us; speedup vs baseline: 1.1303x; 1.1303x over previous
//
#include <hip/hip_runtime.h>
#include <math.h>

// Dims (fixed by problem): B=2, N=4096, C=256, nc=150, T=4, TN=16384, heads=8, hd=32, hid=1024, H=W=64

// ---------------- block reduction helpers (blockDim.x == 256) ----------------
__device__ __forceinline__ float bred_sum(float v, float* red) {
  int tid = threadIdx.x;
  red[tid] = v; __syncthreads();
  #pragma unroll
  for (int s = 128; s > 0; s >>= 1) {
    if (tid < s) red[tid] += red[tid + s];
    __syncthreads();
  }
  float r = red[0]; __syncthreads();
  return r;
}
__device__ __forceinline__ float bred_max(float v, float* red) {
  int tid = threadIdx.x;
  red[tid] = v; __syncthreads();
  #pragma unroll
  for (int s = 128; s > 0; s >>= 1) {
    if (tid < s) red[tid] = fmaxf(red[tid], red[tid + s]);
    __syncthreads();
  }
  float r = red[0]; __syncthreads();
  return r;
}

// ---------------- generic fp32 GEMM: out[m][n] = alpha*(sum_k A[m,k]*W[n,k] + bias[n]) ----------------
// tile 128M x 64N, K-chunk 16, 256 threads, 8x4 acc/thread
__global__ __launch_bounds__(256) void gemm_nt(
    const float* __restrict__ A, const float* __restrict__ W,
    const float* __restrict__ bias, float* __restrict__ out,
    int M, int N, int K, float alpha)
{
  __shared__ __align__(16) float As[16][132];
  __shared__ __align__(16) float Ws[16][68];
  const int tid = threadIdx.x;
  const int m0 = blockIdx.x * 128;
  const int n0 = blockIdx.y * 64;
  const int tm = tid & 15;   // rows tm*8..+7
  const int tn = tid >> 4;   // cols tn*4..+3
  float acc[8][4];
  #pragma unroll
  for (int i = 0; i < 8; ++i)
    #pragma unroll
    for (int j = 0; j < 4; ++j) acc[i][j] = 0.f;

  const int lr = tid >> 2;        // 0..63
  const int lk = (tid & 3) * 4;   // 0,4,8,12

  for (int k0 = 0; k0 < K; k0 += 16) {
    #pragma unroll
    for (int p = 0; p < 2; ++p) {
      int r = lr + p * 64;
      int gm = m0 + r;
      float4 v = make_float4(0.f, 0.f, 0.f, 0.f);
      if (gm < M) v = *(const float4*)&A[(size_t)gm * K + k0 + lk];
      As[lk + 0][r] = v.x; As[lk + 1][r] = v.y; As[lk + 2][r] = v.z; As[lk + 3][r] = v.w;
    }
    {
      float4 v = *(const float4*)&W[(size_t)(n0 + lr) * K + k0 + lk];
      Ws[lk + 0][lr] = v.x; Ws[lk + 1][lr] = v.y; Ws[lk + 2][lr] = v.z; Ws[lk + 3][lr] = v.w;
    }
    __syncthreads();
    #pragma unroll
    for (int kk = 0; kk < 16; ++kk) {
      float4 a0 = *(const float4*)&As[kk][tm * 8];
      float4 a1 = *(const float4*)&As[kk][tm * 8 + 4];
      float4 w0 = *(const float4*)&Ws[kk][tn * 4];
      float av[8] = {a0.x, a0.y, a0.z, a0.w, a1.x, a1.y, a1.z, a1.w};
      float wv[4] = {w0.x, w0.y, w0.z, w0.w};
      #pragma unroll
      for (int i = 0; i < 8; ++i)
        #pragma unroll
        for (int j = 0; j < 4; ++j)
          acc[i][j] = fmaf(av[i], wv[j], acc[i][j]);
    }
    __syncthreads();
  }
  float4 bv = *(const float4*)&bias[n0 + tn * 4];
  float bb[4] = {bv.x, bv.y, bv.z, bv.w};
  #pragma unroll
  for (int i = 0; i < 8; ++i) {
    int gm = m0 + tm * 8 + i;
    if (gm >= M) continue;
    float4 r;
    r.x = alpha * (acc[i][0] + bb[0]);
    r.y = alpha * (acc[i][1] + bb[1]);
    r.z = alpha * (acc[i][2] + bb[2]);
    r.w = alpha * (acc[i][3] + bb[3]);
    *(float4*)&out[(size_t)gm * N + n0 + tn * 4] = r;
  }
}

// ---------------- cl[b][k][ti*4096+n] = sum_c xf[b,ti,n,c]*cw[k,c] ----------------
__global__ __launch_bounds__(256) void gemm_cl(
    const float* __restrict__ x, const float* __restrict__ mem,
    const float* __restrict__ cw, float* __restrict__ cl)
{
  __shared__ __align__(16) float As[16][132];
  __shared__ __align__(16) float Ws[16][68];
  const int tid = threadIdx.x;
  const int m0 = blockIdx.x * 128;        // global row over (b,ti,n)
  const int n0 = blockIdx.y * 64;         // cluster col
  const int bt = m0 >> 12;
  const int b = bt >> 2, ti = bt & 3;
  const int nbase = m0 & 4095;
  const float* Abase = (ti < 3) ? (mem + (size_t)(b * 3 + ti) * 4096 * 256)
                                : (x + (size_t)b * 4096 * 256);
  const int tm = tid & 15, tn = tid >> 4;
  float acc[8][4];
  #pragma unroll
  for (int i = 0; i < 8; ++i)
    #pragma unroll
    for (int j = 0; j < 4; ++j) acc[i][j] = 0.f;
  const int lr = tid >> 2, lk = (tid & 3) * 4;
  for (int k0 = 0; k0 < 256; k0 += 16) {
    #pragma unroll
    for (int p = 0; p < 2; ++p) {
      int r = lr + p * 64;
      float4 v = *(const float4*)&Abase[(size_t)(nbase + r) * 256 + k0 + lk];
      As[lk + 0][r] = v.x; As[lk + 1][r] = v.y; As[lk + 2][r] = v.z; As[lk + 3][r] = v.w;
    }
    {
      int gn = n0 + lr;
      float4 v = make_float4(0.f, 0.f, 0.f, 0.f);
      if (gn < 150) v = *(const float4*)&cw[(size_t)gn * 256 + k0 + lk];
      Ws[lk + 0][lr] = v.x; Ws[lk + 1][lr] = v.y; Ws[lk + 2][lr] = v.z; Ws[lk + 3][lr] = v.w;
    }
    __syncthreads();
    #pragma unroll
    for (int kk = 0; kk < 16; ++kk) {
      float4 a0 = *(const float4*)&As[kk][tm * 8];
      float4 a1 = *(const float4*)&As[kk][tm * 8 + 4];
      float4 w0 = *(const float4*)&Ws[kk][tn * 4];
      float av[8] = {a0.x, a0.y, a0.z, a0.w, a1.x, a1.y, a1.z, a1.w};
      float wv[4] = {w0.x, w0.y, w0.z, w0.w};
      #pragma unroll
      for (int i = 0; i < 8; ++i)
        #pragma unroll
        for (int j = 0; j < 4; ++j)
          acc[i][j] = fmaf(av[i], wv[j], acc[i][j]);
    }
    __syncthreads();
  }
  #pragma unroll
  for (int j = 0; j < 4; ++j) {
    int kc = n0 + tn * 4 + j;
    if (kc >= 150) continue;
    float4 r0 = make_float4(acc[0][j], acc[1][j], acc[2][j], acc[3][j]);
    float4 r1 = make_float4(acc[4][j], acc[5][j], acc[6][j], acc[7][j]);
    float* dst = cl + ((size_t)b * 150 + kc) * 16384 + ti * 4096 + nbase + tm * 8;
    *(float4*)&dst[0] = r0;
    *(float4*)&dst[4] = r1;
  }
}

// ---------------- per-column cosine clip factors (split: y=0 -> z, y=1 -> cl) ----------------
__global__ __launch_bounds__(256) void cos_stats(
    const float* __restrict__ z, const float* __restrict__ cl,
    const float* __restrict__ p1, const float* __restrict__ p2,
    float* __restrict__ cosz, float* __restrict__ coscl)
{
  int which = blockIdx.y;
  int gid = blockIdx.x * 256 + threadIdx.x;  // 0..32767
  int b = gid >> 14, m = gid & 16383;
  const float* src = which ? cl : z;
  const float* pr  = which ? p2 : p1;
  const float* sp = src + (size_t)b * 150 * 16384 + m;
  float d0 = 0, d1 = 0, s0 = 0, s1 = 0, pn = 0;
  for (int k = 0; k < 150; k += 2) {
    float v0 = sp[(size_t)k * 16384];
    float v1 = sp[(size_t)(k + 1) * 16384];
    float a0 = pr[k], a1 = pr[k + 1];
    d0 += v0 * a0; s0 += v0 * v0;
    d1 += v1 * a1; s1 += v1 * v1;
    pn += a0 * a0 + a1 * a1;
  }
  float c = (d0 + d1) / (fmaxf(sqrtf(s0 + s1), 1e-12f) * fmaxf(sqrtf(pn), 1e-12f));
  c = fminf(fmaxf(c, 0.f), 1.f);
  (which ? coscl : cosz)[gid] = c;
}

// ---------------- fused K=300 GEMM: csz[b][k'][m] = 0.5*(coscl*cl@tdt2 + cosz*z@tdt1); also writes assigned ----------------
__global__ __launch_bounds__(256) void gemm_csz(
    const float* __restrict__ cl, const float* __restrict__ z,
    const float* __restrict__ coscl, const float* __restrict__ cosz,
    const float* __restrict__ tdt2, const float* __restrict__ tdt1,
    float* __restrict__ csz, float* __restrict__ asg)
{
  __shared__ __align__(16) float As[16][132];
  __shared__ __align__(16) float Ws[16][68];
  const int tid = threadIdx.x;
  const int m0 = blockIdx.x * 128;
  const int b = m0 >> 14;
  const int mm = m0 & 16383;
  const int n0 = blockIdx.y * 64;
  const int tm = tid & 15, tn = tid >> 4;
  float acc[8][4];
  #pragma unroll
  for (int i = 0; i < 8; ++i)
    #pragma unroll
    for (int j = 0; j < 4; ++j) acc[i][j] = 0.f;
  const int amr = (tid & 31) * 4;
  const int akk = tid >> 5;        // 0..7
  const int wnn = (tid & 15) * 4;
  const int wkk = tid >> 4;        // 0..15
  for (int k0 = 0; k0 < 300; k0 += 16) {
    #pragma unroll
    for (int p = 0; p < 2; ++p) {
      int kki = akk + p * 8;
      int kg = k0 + kki;
      float4 v = make_float4(0.f, 0.f, 0.f, 0.f);
      if (kg < 150) {
        v = *(const float4*)&cl[((size_t)b * 150 + kg) * 16384 + mm + amr];
        float4 cs = *(const float4*)&coscl[(size_t)b * 16384 + mm + amr];
        v.x *= cs.x; v.y *= cs.y; v.z *= cs.z; v.w *= cs.w;
      } else if (kg < 300) {
        v = *(const float4*)&z[((size_t)b * 150 + (kg - 150)) * 16384 + mm + amr];
        float4 cs = *(const float4*)&cosz[(size_t)b * 16384 + mm + amr];
        v.x *= cs.x; v.y *= cs.y; v.z *= cs.z; v.w *= cs.w;
      }
      *(float4*)&As[kki][amr] = v;
    }
    {
      int kg = k0 + wkk;
      #pragma unroll
      for (int j = 0; j < 4; ++j) {
        int gn = n0 + wnn + j;
        float t = 0.f;
        if (gn < 150) {
          if (kg < 150) t = tdt2[kg * 150 + gn];
          else if (kg < 300) t = tdt1[(kg - 150) * 150 + gn];
        }
        Ws[wkk][wnn + j] = t;
      }
    }
    __syncthreads();
    #pragma unroll
    for (int kk = 0; kk < 16; ++kk) {
      float4 a0 = *(const float4*)&As[kk][tm * 8];
      float4 a1 = *(const float4*)&As[kk][tm * 8 + 4];
      float4 w0 = *(const float4*)&Ws[kk][tn * 4];
      float av[8] = {a0.x, a0.y, a0.z, a0.w, a1.x, a1.y, a1.z, a1.w};
      float wv[4] = {w0.x, w0.y, w0.z, w0.w};
      #pragma unroll
      for (int i = 0; i < 8; ++i)
        #pragma unroll
        for (int j = 0; j < 4; ++j)
          acc[i][j] = fmaf(av[i], wv[j], acc[i][j]);
    }
    __syncthreads();
  }
  const int ti = mm >> 12;
  const int nn = mm & 4095;
  #pragma unroll
  for (int j = 0; j < 4; ++j) {
    int kc = n0 + tn * 4 + j;
    if (kc >= 150) continue;
    float4 r0 = make_float4(0.5f * acc[0][j], 0.5f * acc[1][j], 0.5f * acc[2][j], 0.5f * acc[3][j]);
    float4 r1 = make_float4(0.5f * acc[4][j], 0.5f * acc[5][j], 0.5f * acc[6][j], 0.5f * acc[7][j]);
    size_t o1 = ((size_t)b * 150 + kc) * 16384 + mm + tm * 8;
    *(float4*)&csz[o1] = r0;
    *(float4*)&csz[o1 + 4] = r1;
    size_t o2 = (((size_t)b * 4 + ti) * 150 + kc) * 4096 + nn + tm * 8;
    *(float4*)&asg[o2] = r0;
    *(float4*)&asg[o2 + 4] = r1;
  }
}

// ---------------- softmax stats per (b,ti,k) row of 4096 ----------------
__global__ __launch_bounds__(256) void softmax_stats(
    const float* __restrict__ csz, float* __restrict__ mr, float* __restrict__ lr_)
{
  __shared__ float red[256];
  int row = blockIdx.x;           // bt*150 + k
  int bt = row / 150, k = row % 150;
  int b = bt >> 2, ti = bt & 3;
  const float* p = csz + ((size_t)b * 150 + k) * 16384 + ti * 4096;
  float v[16];
  float mx = -1e30f;
  #pragma unroll
  for (int i = 0; i < 16; ++i) { v[i] = p[i * 256 + threadIdx.x]; mx = fmaxf(mx, v[i]); }
  mx = bred_max(mx, red);
  float s = 0.f;
  #pragma unroll
  for (int i = 0; i < 16; ++i) s += expf(v[i] - mx);
  s = bred_sum(s, red);
  if (threadIdx.x == 0) { mr[row] = mx; lr_[row] = s; }
}

// ---------------- cen partials: part[sp][bt][k][c] = sum_{n in split} exp(center-m)*xf[n][c] ----------------
// grid (c0:8, bt:8, sp:16); LDS As[k][n] so stage-in is contiguous b128 (conflict-free),
// FMA loop reads float4 of As rows and Bs rows.
__global__ __launch_bounds__(256) void gemm_cen(
    const float* __restrict__ csz, const float* __restrict__ x, const float* __restrict__ mem,
    const float* __restrict__ mr, float* __restrict__ part)
{
  __shared__ __align__(16) float As[160][36];
  __shared__ __align__(16) float Bs[32][36];
  const int tid = threadIdx.x;
  const int c0 = blockIdx.x * 32;
  const int bt = blockIdx.y;
  const int sp = blockIdx.z;      // 0..15
  const int b = bt >> 2, ti = bt & 3;
  const float* xf = (ti < 3) ? (mem + (size_t)(b * 3 + ti) * 4096 * 256)
                             : (x + (size_t)b * 4096 * 256);
  const float* crow = csz + (size_t)b * 150 * 16384 + ti * 4096;
  const int tmr = tid >> 3;   // 0..31
  const int tnc = tid & 7;    // 0..7
  const int ann = tnc * 4;    // n-offset 0..28
  float acc[5][4];
  #pragma unroll
  for (int i = 0; i < 5; ++i)
    #pragma unroll
    for (int j = 0; j < 4; ++j) acc[i][j] = 0.f;

  for (int n0 = sp * 256; n0 < sp * 256 + 256; n0 += 32) {
    #pragma unroll
    for (int p = 0; p < 5; ++p) {
      int kcl = tmr + p * 32;      // 0..159
      float4 v = make_float4(0.f, 0.f, 0.f, 0.f);
      if (kcl < 150) {
        v = *(const float4*)&crow[(size_t)kcl * 16384 + n0 + ann];
        float mrv = mr[bt * 150 + kcl];
        v.x = expf(v.x - mrv); v.y = expf(v.y - mrv);
        v.z = expf(v.z - mrv); v.w = expf(v.w - mrv);
      }
      *(float4*)&As[kcl][ann] = v;
    }
    {
      int nr = tid >> 3;
      int cc = (tid & 7) * 4;
      *(float4*)&Bs[nr][cc] = *(const float4*)&xf[(size_t)(n0 + nr) * 256 + c0 + cc];
    }
    __syncthreads();
    #pragma unroll
    for (int kk = 0; kk < 32; kk += 4) {
      float4 b0 = *(const float4*)&Bs[kk + 0][tnc * 4];
      float4 b1 = *(const float4*)&Bs[kk + 1][tnc * 4];
      float4 b2 = *(const float4*)&Bs[kk + 2][tnc * 4];
      float4 b3 = *(const float4*)&Bs[kk + 3][tnc * 4];
      #pragma unroll
      for (int i = 0; i < 5; ++i) {
        float4 a = *(const float4*)&As[tmr * 5 + i][kk];
        acc[i][0] = fmaf(a.x, b0.x, acc[i][0]);
        acc[i][1] = fmaf(a.x, b0.y, acc[i][1]);
        acc[i][2] = fmaf(a.x, b0.z, acc[i][2]);
        acc[i][3] = fmaf(a.x, b0.w, acc[i][3]);
        acc[i][0] = fmaf(a.y, b1.x, acc[i][0]);
        acc[i][1] = fmaf(a.y, b1.y, acc[i][1]);
        acc[i][2] = fmaf(a.y, b1.z, acc[i][2]);
        acc[i][3] = fmaf(a.y, b1.w, acc[i][3]);
        acc[i][0] = fmaf(a.z, b2.x, acc[i][0]);
        acc[i][1] = fmaf(a.z, b2.y, acc[i][1]);
        acc[i][2] = fmaf(a.z, b2.z, acc[i][2]);
        acc[i][3] = fmaf(a.z, b2.w, acc[i][3]);
        acc[i][0] = fmaf(a.w, b3.x, acc[i][0]);
        acc[i][1] = fmaf(a.w, b3.y, acc[i][1]);
        acc[i][2] = fmaf(a.w, b3.z, acc[i][2]);
        acc[i][3] = fmaf(a.w, b3.w, acc[i][3]);
      }
    }
    __syncthreads();
  }
  #pragma unroll
  for (int i = 0; i < 5; ++i) {
    int kcl = tmr * 5 + i;
    if (kcl >= 150) continue;
    float4 r = make_float4(acc[i][0], acc[i][1], acc[i][2], acc[i][3]);
    *(float4*)&part[(((size_t)sp * 8 + bt) * 150 + kcl) * 256 + c0 + tnc * 4] = r;
  }
}

__global__ __launch_bounds__(256) void reduce_cen(
    const float* __restrict__ part, const float* __restrict__ lr_, float* __restrict__ cen)
{
  int row = blockIdx.x;  // 0..1199 = bt*150+k
  int c = threadIdx.x;
  float s = 0.f;
  #pragma unroll
  for (int sp = 0; sp < 16; ++sp)
    s += part[((size_t)sp * 1200 + row) * 256 + c];
  cen[(size_t)row * 256 + c] = s / lr_[row];
}

// ---------------- similarity gate + LN -> C_in ----------------
__global__ __launch_bounds__(256) void gate_ln(
    const float* __restrict__ cen, const float* __restrict__ alpha_, const float* __restrict__ beta_,
    const float* __restrict__ nw, const float* __restrict__ nb, float* __restrict__ cin)
{
  __shared__ float red[256];
  int bk = blockIdx.x;       // b*150 + k
  int b = bk / 150, k = bk % 150;
  int c = threadIdx.x;
  const float* base = cen + ((size_t)b * 4 * 150) * 256;
  float lc  = base[((size_t)3 * 150 + k) * 256 + c];
  float p0  = base[((size_t)0 * 150 + k) * 256 + c];
  float p1v = base[((size_t)1 * 150 + k) * 256 + c];
  float p2v = base[((size_t)2 * 150 + k) * 256 + c];
  float nl = bred_sum(lc * lc, red);
  float q0 = bred_sum(p0 * p0, red);
  float q1 = bred_sum(p1v * p1v, red);
  float q2 = bred_sum(p2v * p2v, red);
  float d0 = bred_sum(lc * p0, red);
  float d1 = bred_sum(lc * p1v, red);
  float d2 = bred_sum(lc * p2v, red);
  float al = alpha_[0], be = beta_[0];
  float snl = sqrtf(nl);
  float g0 = 1.f / (1.f + expf(-(be + al * (d0 / fmaxf(snl * sqrtf(q0), 1e-8f)))));
  float g1 = 1.f / (1.f + expf(-(be + al * (d1 / fmaxf(snl * sqrtf(q1), 1e-8f)))));
  float g2 = 1.f / (1.f + expf(-(be + al * (d2 / fmaxf(snl * sqrtf(q2), 1e-8f)))));
  float ci = lc + g0 * p0 + g1 * p1v + g2 * p2v;
  float mu = bred_sum(ci, red) * (1.f / 256.f);
  float df = ci - mu;
  float var = bred_sum(df * df, red) * (1.f / 256.f);
  cin[(size_t)bk * 256 + c] = df * rsqrtf(var + 1e-5f) * nw[c] + nb[c];
}

// ---------------- attention: per (b,h) q(4096x32) vs K/V(150x32) ----------------
__global__ __launch_bounds__(128) void attn_k(
    const float* __restrict__ q, const float* __restrict__ ks, const float* __restrict__ vs,
    float* __restrict__ o)
{
  __shared__ float Ks[150][32];
  __shared__ float Vs[150][32];
  int bid = blockIdx.x;
  int ntile = bid & 31, bh = bid >> 5;
  int b = bh >> 3, h = bh & 7;
  for (int idx = threadIdx.x; idx < 4800; idx += 128) {
    int kc = idx >> 5, d = idx & 31;
    Ks[kc][d] = ks[((size_t)b * 150 + kc) * 256 + h * 32 + d];
    Vs[kc][d] = vs[((size_t)b * 150 + kc) * 256 + h * 32 + d];
  }
  __syncthreads();
  int n = ntile * 128 + threadIdx.x;
  const float* qp = q + ((size_t)b * 4096 + n) * 256 + h * 32;
  float qr[32];
  #pragma unroll
  for (int d4 = 0; d4 < 8; ++d4) {
    float4 v = *(const float4*)&qp[d4 * 4];
    qr[d4 * 4 + 0] = v.x; qr[d4 * 4 + 1] = v.y; qr[d4 * 4 + 2] = v.z; qr[d4 * 4 + 3] = v.w;
  }
  float m = -1e30f, l = 0.f;
  for (int kc = 0; kc < 150; ++kc) {
    float s = 0.f;
    #pragma unroll
    for (int d = 0; d < 32; ++d) s = fmaf(qr[d], Ks[kc][d], s);
    float nm = fmaxf(m, s);
    l = l * expf(m - nm) + expf(s - nm);
    m = nm;
  }
  float inv = 1.f / l;
  float acc[32];
  #pragma unroll
  for (int d = 0; d < 32; ++d) acc[d] = 0.f;
  for (int kc = 0; kc < 150; ++kc) {
    float s = 0.f;
    #pragma unroll
    for (int d = 0; d < 32; ++d) s = fmaf(qr[d], Ks[kc][d], s);
    float w = expf(s - m);
    #pragma unroll
    for (int d = 0; d < 32; ++d) acc[d] = fmaf(w, Vs[kc][d], acc[d]);
  }
  float* op = o + ((size_t)b * 4096 + n) * 256 + h * 32;
  #pragma unroll
  for (int d4 = 0; d4 < 8; ++d4) {
    float4 v = make_float4(acc[d4 * 4] * inv, acc[d4 * 4 + 1] * inv,
                           acc[d4 * 4 + 2] * inv, acc[d4 * 4 + 3] * inv);
    *(float4*)&op[d4 * 4] = v;
  }
}

// ---------------- dst = res + LN(src) ----------------
__global__ __launch_bounds__(256) void ln_res(
    const float* __restrict__ src, const float* __restrict__ res,
    const float* __restrict__ nw, const float* __restrict__ nb, float* __restrict__ dst)
{
  __shared__ float red[256];
  size_t row = blockIdx.x;
  int c = threadIdx.x;
  float v = src[row * 256 + c];
  float mu = bred_sum(v, red) * (1.f / 256.f);
  float df = v - mu;
  float var = bred_sum(df * df, red) * (1.f / 256.f);
  dst[row * 256 + c] = res[row * 256 + c] + df * rsqrtf(var + 1e-5f) * nw[c] + nb[c];
}

// ---------------- depthwise 3x3 conv + bias + exact gelu ----------------
__global__ __launch_bounds__(256) void conv_gelu(
    const float* __restrict__ h, const float* __restrict__ w, const float* __restrict__ bias,
    float* __restrict__ hc)
{
  int bid = blockIdx.x;
  int chunk = bid & 3;
  int pix = bid >> 2;             // 0..8191
  int b = pix >> 12;
  int n = pix & 4095;
  int y = n >> 6, xx = n & 63;
  int ch = chunk * 256 + threadIdx.x;
  float acc = bias[ch];
  #pragma unroll
  for (int dy = 0; dy < 3; ++dy) {
    int yy = y + dy - 1;
    if (yy < 0 || yy > 63) continue;
    #pragma unroll
    for (int dx = 0; dx < 3; ++dx) {
      int xv = xx + dx - 1;
      if (xv < 0 || xv > 63) continue;
      acc = fmaf(h[((size_t)b * 4096 + yy * 64 + xv) * 1024 + ch], w[ch * 9 + dy * 3 + dx], acc);
    }
  }
  float g = 0.5f * acc * (1.f + erff(acc * 0.70710678118654752f));
  hc[((size_t)b * 4096 + n) * 1024 + ch] = g;
}

extern "C" void kernel_launch(void* const* d_in, const int* in_sizes, int n_in,
                              void* d_out, int out_size, void* d_ws, size_t ws_size,
                              hipStream_t stream)
{
  (void)in_sizes; (void)n_in; (void)out_size; (void)ws_size;
  const float* x    = (const float*)d_in[0];
  const float* z    = (const float*)d_in[1];
  const float* mem  = (const float*)d_in[2];
  const float* cw   = (const float*)d_in[3];
  const float* p1   = (const float*)d_in[4];
  const float* tdt1 = (const float*)d_in[5];
  const float* p2   = (const float*)d_in[6];
  const float* tdt2 = (const float*)d_in[7];
  const float* sal  = (const float*)d_in[8];
  const float* sbe  = (const float*)d_in[9];
  const float* q_w  = (const float*)d_in[10];
  const float* q_b  = (const float*)d_in[11];
  const float* k_w  = (const float*)d_in[12];
  const float* k_b  = (const float*)d_in[13];
  const float* v_w  = (const float*)d_in[14];
  const float* v_b  = (const float*)d_in[15];
  const float* pj_w = (const float*)d_in[16];
  const float* pj_b = (const float*)d_in[17];
  const float* nw   = (const float*)d_in[18];
  const float* nb   = (const float*)d_in[19];
  const float* f1w  = (const float*)d_in[20];
  const float* f1b  = (const float*)d_in[21];
  const float* dww  = (const float*)d_in[22];
  const float* dwb  = (const float*)d_in[23];
  const float* f2w  = (const float*)d_in[24];
  const float* f2b  = (const float*)d_in[25];

  float* out = (float*)d_out;                  // (2,4096,256)
  float* csz = out + 2097152;                  // (2,150,16384)
  float* asg = csz + 4915200;                  // (2,4,150,4096)

  // workspace layout (floats); total ~21.0M floats = 84.1 MB, with safe reuse
  float* ws    = (float*)d_ws;
  float* cl    = ws;                 // 4,915,200   dead after gemm_csz
  float* part  = ws;                 // 4,915,200   (reuses cl region; alive gemm_cen..reduce_cen)
  float* coscl = ws + 4915200;       // 32,768
  float* cosz  = ws + 4948000;       // 32,768
  float* mr    = ws + 4980800;       // 1,200
  float* lr_   = ws + 4982016;       // 1,200
  float* cen   = ws + 6212032;       // 307,200
  float* cin   = ws + 6519232;       // 76,800
  float* q     = ws + 6596032;       // 2,097,152   dead after attn
  float* ksb   = ws + 8693184;       // 76,800      dead after attn
  float* vsb   = ws + 8769984;       // 76,800      dead after attn
  float* o     = ws + 8846784;       // 2,097,152   dead after proj gemm
  float* h     = ws;                 // 8,388,608   (reuses cl/part.. region, all dead by then)
  float* hc    = ws + 8446976;       // 8,388,608   (reuses q tail/k/v/o, all dead)
  float* tmp   = ws + 16835584;      // 2,097,152
  float* out1  = ws + 18932736;      // 2,097,152

  dim3 blk(256);
  // 1. cl = xf @ cw^T  (written in (B,nc,T*N) layout)
  gemm_cl<<<dim3(256, 3), blk, 0, stream>>>(x, mem, cw, cl);
  // 2. cosine clip factors
  cos_stats<<<dim3(128, 2), blk, 0, stream>>>(z, cl, p1, p2, cosz, coscl);
  // 3. cluster_x_z + assigned (fused K=300 GEMM)
  gemm_csz<<<dim3(256, 3), blk, 0, stream>>>(cl, z, coscl, cosz, tdt2, tdt1, csz, asg);
  // 4. softmax stats over N
  softmax_stats<<<dim3(1200), blk, 0, stream>>>(csz, mr, lr_);
  // 5. cen = softmax(center) @ xf  (split-K x16)
  gemm_cen<<<dim3(8, 8, 16), blk, 0, stream>>>(csz, x, mem, mr, part);
  reduce_cen<<<dim3(1200), blk, 0, stream>>>(part, lr_, cen);
  // 6. gate + LN -> C_in
  gate_ln<<<dim3(300), blk, 0, stream>>>(cen, sal, sbe, nw, nb, cin);
  // 7. q/k/v
  gemm_nt<<<dim3(64, 4), blk, 0, stream>>>(x, q_w, q_b, q, 8192, 256, 256, 0.17677669529663687f);
  gemm_nt<<<dim3(3, 4), blk, 0, stream>>>(cin, k_w, k_b, ksb, 300, 256, 256, 1.f);
  gemm_nt<<<dim3(3, 4), blk, 0, stream>>>(cin, v_w, v_b, vsb, 300, 256, 256, 1.f);
  // 8. attention
  attn_k<<<dim3(512), dim3(128), 0, stream>>>(q, ksb, vsb, o);
  // 9. proj + LN + residual
  gemm_nt<<<dim3(64, 4), blk, 0, stream>>>(o, pj_w, pj_b, tmp, 8192, 256, 256, 1.f);
  ln_res<<<dim3(8192), blk, 0, stream>>>(tmp, x, nw, nb, out1);
  // 10. MLP with depthwise conv
  gemm_nt<<<dim3(64, 16), blk, 0, stream>>>(out1, f1w, f1b, h, 8192, 1024, 256, 1.f);
  conv_gelu<<<dim3(32768), blk, 0, stream>>>(h, dww, dwb, hc);
  gemm_nt<<<dim3(64, 4), blk, 0, stream>>>(hc, f2w, f2b, tmp, 8192, 256, 1024, 1.f);
  ln_res<<<dim3(8192), blk, 0, stream>>>(tmp, out1, nw, nb, out);
}

// Round 3
// 617.840 us; speedup vs baseline: 1.3751x; 1.2166x over previous
//
#include <hip/hip_runtime.h>
#include <math.h>

// Dims (fixed by problem): B=2, N=4096, C=256, nc=150, T=4, TN=16384, heads=8, hd=32, hid=1024, H=W=64

typedef __attribute__((ext_vector_type(8))) short bf16x8;
typedef __attribute__((ext_vector_type(4))) float f32x4;

__device__ __forceinline__ short f2b(float f) {
  union { float f; unsigned int u; } c; c.f = f;
  unsigned int r = (c.u + 0x7fffu + ((c.u >> 16) & 1u)) >> 16;
  return (short)r;
}

// ---------------- block reduction helpers (blockDim.x == 256) ----------------
__device__ __forceinline__ float bred_sum(float v, float* red) {
  int tid = threadIdx.x;
  red[tid] = v; __syncthreads();
  #pragma unroll
  for (int s = 128; s > 0; s >>= 1) {
    if (tid < s) red[tid] += red[tid + s];
    __syncthreads();
  }
  float r = red[0]; __syncthreads();
  return r;
}
__device__ __forceinline__ float bred_max(float v, float* red) {
  int tid = threadIdx.x;
  red[tid] = v; __syncthreads();
  #pragma unroll
  for (int s = 128; s > 0; s >>= 1) {
    if (tid < s) red[tid] = fmaxf(red[tid], red[tid + s]);
    __syncthreads();
  }
  float r = red[0]; __syncthreads();
  return r;
}

// ---------------- bf16 MFMA GEMM: out[m][n] = alpha*(sum_k A[m,k]*W[n,k] + bias[n]) ----------------
// Requires M%128==0, N%64==0, K%64==0. fp32 inputs converted RNE->bf16 at LDS staging.
// tile 128M x 64N, BK=64, 256 threads = 4 waves (2M x 2N), each wave 64x32 via 4x2 16x16x32 mfma.
__global__ __launch_bounds__(256) void gemm_mfma(
    const float* __restrict__ A, const float* __restrict__ W,
    const float* __restrict__ bias, float* __restrict__ out,
    int M, int N, int K, float alpha)
{
  __shared__ __align__(16) short As[128 * 72];   // stride 72 bf16 = 144B (16B-aligned rows, bank-spread)
  __shared__ __align__(16) short Bs[64 * 72];
  const int tid = threadIdx.x;
  const int m0 = blockIdx.x * 128;
  const int n0 = blockIdx.y * 64;
  const int wave = tid >> 6;
  const int lane = tid & 63;
  const int wm = wave & 1, wn = wave >> 1;
  const int t16 = lane & 15;
  const int k8 = (lane >> 4) * 8;

  f32x4 acc[4][2];
  #pragma unroll
  for (int i = 0; i < 4; ++i)
    #pragma unroll
    for (int j = 0; j < 2; ++j)
      acc[i][j] = (f32x4){0.f, 0.f, 0.f, 0.f};

  const int sr = tid >> 2;        // 0..63
  const int sk = (tid & 3) * 16;  // 0,16,32,48

  for (int k0 = 0; k0 < K; k0 += 64) {
    // stage A rows sr, sr+64 (16 fp32 each -> 16 bf16)
    #pragma unroll
    for (int p = 0; p < 2; ++p) {
      const int row = sr + p * 64;
      const float* ap = &A[(size_t)(m0 + row) * K + k0 + sk];
      float4 v0 = *(const float4*)&ap[0];
      float4 v1 = *(const float4*)&ap[4];
      float4 v2 = *(const float4*)&ap[8];
      float4 v3 = *(const float4*)&ap[12];
      bf16x8 w0, w1;
      w0[0] = f2b(v0.x); w0[1] = f2b(v0.y); w0[2] = f2b(v0.z); w0[3] = f2b(v0.w);
      w0[4] = f2b(v1.x); w0[5] = f2b(v1.y); w0[6] = f2b(v1.z); w0[7] = f2b(v1.w);
      w1[0] = f2b(v2.x); w1[1] = f2b(v2.y); w1[2] = f2b(v2.z); w1[3] = f2b(v2.w);
      w1[4] = f2b(v3.x); w1[5] = f2b(v3.y); w1[6] = f2b(v3.z); w1[7] = f2b(v3.w);
      *(bf16x8*)&As[row * 72 + sk] = w0;
      *(bf16x8*)&As[row * 72 + sk + 8] = w1;
    }
    // stage B row sr
    {
      const float* wp = &W[(size_t)(n0 + sr) * K + k0 + sk];
      float4 v0 = *(const float4*)&wp[0];
      float4 v1 = *(const float4*)&wp[4];
      float4 v2 = *(const float4*)&wp[8];
      float4 v3 = *(const float4*)&wp[12];
      bf16x8 w0, w1;
      w0[0] = f2b(v0.x); w0[1] = f2b(v0.y); w0[2] = f2b(v0.z); w0[3] = f2b(v0.w);
      w0[4] = f2b(v1.x); w0[5] = f2b(v1.y); w0[6] = f2b(v1.z); w0[7] = f2b(v1.w);
      w1[0] = f2b(v2.x); w1[1] = f2b(v2.y); w1[2] = f2b(v2.z); w1[3] = f2b(v2.w);
      w1[4] = f2b(v3.x); w1[5] = f2b(v3.y); w1[6] = f2b(v3.z); w1[7] = f2b(v3.w);
      *(bf16x8*)&Bs[sr * 72 + sk] = w0;
      *(bf16x8*)&Bs[sr * 72 + sk + 8] = w1;
    }
    __syncthreads();
    #pragma unroll
    for (int ks = 0; ks < 2; ++ks) {
      const int kofs = ks * 32 + k8;
      bf16x8 af0 = *(const bf16x8*)&As[(wm * 64 +  0 + t16) * 72 + kofs];
      bf16x8 af1 = *(const bf16x8*)&As[(wm * 64 + 16 + t16) * 72 + kofs];
      bf16x8 af2 = *(const bf16x8*)&As[(wm * 64 + 32 + t16) * 72 + kofs];
      bf16x8 af3 = *(const bf16x8*)&As[(wm * 64 + 48 + t16) * 72 + kofs];
      bf16x8 bf0 = *(const bf16x8*)&Bs[(wn * 32 +  0 + t16) * 72 + kofs];
      bf16x8 bf1 = *(const bf16x8*)&Bs[(wn * 32 + 16 + t16) * 72 + kofs];
      acc[0][0] = __builtin_amdgcn_mfma_f32_16x16x32_bf16(af0, bf0, acc[0][0], 0, 0, 0);
      acc[1][0] = __builtin_amdgcn_mfma_f32_16x16x32_bf16(af1, bf0, acc[1][0], 0, 0, 0);
      acc[2][0] = __builtin_amdgcn_mfma_f32_16x16x32_bf16(af2, bf0, acc[2][0], 0, 0, 0);
      acc[3][0] = __builtin_amdgcn_mfma_f32_16x16x32_bf16(af3, bf0, acc[3][0], 0, 0, 0);
      acc[0][1] = __builtin_amdgcn_mfma_f32_16x16x32_bf16(af0, bf1, acc[0][1], 0, 0, 0);
      acc[1][1] = __builtin_amdgcn_mfma_f32_16x16x32_bf16(af1, bf1, acc[1][1], 0, 0, 0);
      acc[2][1] = __builtin_amdgcn_mfma_f32_16x16x32_bf16(af2, bf1, acc[2][1], 0, 0, 0);
      acc[3][1] = __builtin_amdgcn_mfma_f32_16x16x32_bf16(af3, bf1, acc[3][1], 0, 0, 0);
    }
    __syncthreads();
  }
  // epilogue: D[row=(lane>>4)*4+reg][col=lane&15]
  const int r4 = (lane >> 4) * 4;
  #pragma unroll
  for (int ni = 0; ni < 2; ++ni) {
    const int gcol = n0 + wn * 32 + ni * 16 + t16;
    const float bb = bias[gcol];
    #pragma unroll
    for (int mi = 0; mi < 4; ++mi) {
      #pragma unroll
      for (int r = 0; r < 4; ++r) {
        const int gm = m0 + wm * 64 + mi * 16 + r4 + r;
        out[(size_t)gm * N + gcol] = alpha * (acc[mi][ni][r] + bb);
      }
    }
  }
}

// ---------------- generic fp32 GEMM (small shapes only: k/v) ----------------
__global__ __launch_bounds__(256) void gemm_nt(
    const float* __restrict__ A, const float* __restrict__ W,
    const float* __restrict__ bias, float* __restrict__ out,
    int M, int N, int K, float alpha)
{
  __shared__ __align__(16) float As[16][132];
  __shared__ __align__(16) float Ws[16][68];
  const int tid = threadIdx.x;
  const int m0 = blockIdx.x * 128;
  const int n0 = blockIdx.y * 64;
  const int tm = tid & 15;
  const int tn = tid >> 4;
  float acc[8][4];
  #pragma unroll
  for (int i = 0; i < 8; ++i)
    #pragma unroll
    for (int j = 0; j < 4; ++j) acc[i][j] = 0.f;

  const int lr = tid >> 2;
  const int lk = (tid & 3) * 4;

  for (int k0 = 0; k0 < K; k0 += 16) {
    #pragma unroll
    for (int p = 0; p < 2; ++p) {
      int r = lr + p * 64;
      int gm = m0 + r;
      float4 v = make_float4(0.f, 0.f, 0.f, 0.f);
      if (gm < M) v = *(const float4*)&A[(size_t)gm * K + k0 + lk];
      As[lk + 0][r] = v.x; As[lk + 1][r] = v.y; As[lk + 2][r] = v.z; As[lk + 3][r] = v.w;
    }
    {
      float4 v = *(const float4*)&W[(size_t)(n0 + lr) * K + k0 + lk];
      Ws[lk + 0][lr] = v.x; Ws[lk + 1][lr] = v.y; Ws[lk + 2][lr] = v.z; Ws[lk + 3][lr] = v.w;
    }
    __syncthreads();
    #pragma unroll
    for (int kk = 0; kk < 16; ++kk) {
      float4 a0 = *(const float4*)&As[kk][tm * 8];
      float4 a1 = *(const float4*)&As[kk][tm * 8 + 4];
      float4 w0 = *(const float4*)&Ws[kk][tn * 4];
      float av[8] = {a0.x, a0.y, a0.z, a0.w, a1.x, a1.y, a1.z, a1.w};
      float wv[4] = {w0.x, w0.y, w0.z, w0.w};
      #pragma unroll
      for (int i = 0; i < 8; ++i)
        #pragma unroll
        for (int j = 0; j < 4; ++j)
          acc[i][j] = fmaf(av[i], wv[j], acc[i][j]);
    }
    __syncthreads();
  }
  float4 bv = *(const float4*)&bias[n0 + tn * 4];
  float bb[4] = {bv.x, bv.y, bv.z, bv.w};
  #pragma unroll
  for (int i = 0; i < 8; ++i) {
    int gm = m0 + tm * 8 + i;
    if (gm >= M) continue;
    float4 r;
    r.x = alpha * (acc[i][0] + bb[0]);
    r.y = alpha * (acc[i][1] + bb[1]);
    r.z = alpha * (acc[i][2] + bb[2]);
    r.w = alpha * (acc[i][3] + bb[3]);
    *(float4*)&out[(size_t)gm * N + n0 + tn * 4] = r;
  }
}

// ---------------- cl[b][k][ti*4096+n] = sum_c xf[b,ti,n,c]*cw[k,c] ----------------
__global__ __launch_bounds__(256) void gemm_cl(
    const float* __restrict__ x, const float* __restrict__ mem,
    const float* __restrict__ cw, float* __restrict__ cl)
{
  __shared__ __align__(16) float As[16][132];
  __shared__ __align__(16) float Ws[16][68];
  const int tid = threadIdx.x;
  const int m0 = blockIdx.x * 128;
  const int n0 = blockIdx.y * 64;
  const int bt = m0 >> 12;
  const int b = bt >> 2, ti = bt & 3;
  const int nbase = m0 & 4095;
  const float* Abase = (ti < 3) ? (mem + (size_t)(b * 3 + ti) * 4096 * 256)
                                : (x + (size_t)b * 4096 * 256);
  const int tm = tid & 15, tn = tid >> 4;
  float acc[8][4];
  #pragma unroll
  for (int i = 0; i < 8; ++i)
    #pragma unroll
    for (int j = 0; j < 4; ++j) acc[i][j] = 0.f;
  const int lr = tid >> 2, lk = (tid & 3) * 4;
  for (int k0 = 0; k0 < 256; k0 += 16) {
    #pragma unroll
    for (int p = 0; p < 2; ++p) {
      int r = lr + p * 64;
      float4 v = *(const float4*)&Abase[(size_t)(nbase + r) * 256 + k0 + lk];
      As[lk + 0][r] = v.x; As[lk + 1][r] = v.y; As[lk + 2][r] = v.z; As[lk + 3][r] = v.w;
    }
    {
      int gn = n0 + lr;
      float4 v = make_float4(0.f, 0.f, 0.f, 0.f);
      if (gn < 150) v = *(const float4*)&cw[(size_t)gn * 256 + k0 + lk];
      Ws[lk + 0][lr] = v.x; Ws[lk + 1][lr] = v.y; Ws[lk + 2][lr] = v.z; Ws[lk + 3][lr] = v.w;
    }
    __syncthreads();
    #pragma unroll
    for (int kk = 0; kk < 16; ++kk) {
      float4 a0 = *(const float4*)&As[kk][tm * 8];
      float4 a1 = *(const float4*)&As[kk][tm * 8 + 4];
      float4 w0 = *(const float4*)&Ws[kk][tn * 4];
      float av[8] = {a0.x, a0.y, a0.z, a0.w, a1.x, a1.y, a1.z, a1.w};
      float wv[4] = {w0.x, w0.y, w0.z, w0.w};
      #pragma unroll
      for (int i = 0; i < 8; ++i)
        #pragma unroll
        for (int j = 0; j < 4; ++j)
          acc[i][j] = fmaf(av[i], wv[j], acc[i][j]);
    }
    __syncthreads();
  }
  #pragma unroll
  for (int j = 0; j < 4; ++j) {
    int kc = n0 + tn * 4 + j;
    if (kc >= 150) continue;
    float4 r0 = make_float4(acc[0][j], acc[1][j], acc[2][j], acc[3][j]);
    float4 r1 = make_float4(acc[4][j], acc[5][j], acc[6][j], acc[7][j]);
    float* dst = cl + ((size_t)b * 150 + kc) * 16384 + ti * 4096 + nbase + tm * 8;
    *(float4*)&dst[0] = r0;
    *(float4*)&dst[4] = r1;
  }
}

// ---------------- per-column cosine clip factors (split: y=0 -> z, y=1 -> cl) ----------------
__global__ __launch_bounds__(256) void cos_stats(
    const float* __restrict__ z, const float* __restrict__ cl,
    const float* __restrict__ p1, const float* __restrict__ p2,
    float* __restrict__ cosz, float* __restrict__ coscl)
{
  int which = blockIdx.y;
  int gid = blockIdx.x * 256 + threadIdx.x;
  int b = gid >> 14, m = gid & 16383;
  const float* src = which ? cl : z;
  const float* pr  = which ? p2 : p1;
  const float* sp = src + (size_t)b * 150 * 16384 + m;
  float d0 = 0, d1 = 0, s0 = 0, s1 = 0, pn = 0;
  for (int k = 0; k < 150; k += 2) {
    float v0 = sp[(size_t)k * 16384];
    float v1 = sp[(size_t)(k + 1) * 16384];
    float a0 = pr[k], a1 = pr[k + 1];
    d0 += v0 * a0; s0 += v0 * v0;
    d1 += v1 * a1; s1 += v1 * v1;
    pn += a0 * a0 + a1 * a1;
  }
  float c = (d0 + d1) / (fmaxf(sqrtf(s0 + s1), 1e-12f) * fmaxf(sqrtf(pn), 1e-12f));
  c = fminf(fmaxf(c, 0.f), 1.f);
  (which ? coscl : cosz)[gid] = c;
}

// ---------------- fused K=300 GEMM: csz + assigned ----------------
__global__ __launch_bounds__(256) void gemm_csz(
    const float* __restrict__ cl, const float* __restrict__ z,
    const float* __restrict__ coscl, const float* __restrict__ cosz,
    const float* __restrict__ tdt2, const float* __restrict__ tdt1,
    float* __restrict__ csz, float* __restrict__ asg)
{
  __shared__ __align__(16) float As[16][132];
  __shared__ __align__(16) float Ws[16][68];
  const int tid = threadIdx.x;
  const int m0 = blockIdx.x * 128;
  const int b = m0 >> 14;
  const int mm = m0 & 16383;
  const int n0 = blockIdx.y * 64;
  const int tm = tid & 15, tn = tid >> 4;
  float acc[8][4];
  #pragma unroll
  for (int i = 0; i < 8; ++i)
    #pragma unroll
    for (int j = 0; j < 4; ++j) acc[i][j] = 0.f;
  const int amr = (tid & 31) * 4;
  const int akk = tid >> 5;
  const int wnn = (tid & 15) * 4;
  const int wkk = tid >> 4;
  for (int k0 = 0; k0 < 300; k0 += 16) {
    #pragma unroll
    for (int p = 0; p < 2; ++p) {
      int kki = akk + p * 8;
      int kg = k0 + kki;
      float4 v = make_float4(0.f, 0.f, 0.f, 0.f);
      if (kg < 150) {
        v = *(const float4*)&cl[((size_t)b * 150 + kg) * 16384 + mm + amr];
        float4 cs = *(const float4*)&coscl[(size_t)b * 16384 + mm + amr];
        v.x *= cs.x; v.y *= cs.y; v.z *= cs.z; v.w *= cs.w;
      } else if (kg < 300) {
        v = *(const float4*)&z[((size_t)b * 150 + (kg - 150)) * 16384 + mm + amr];
        float4 cs = *(const float4*)&cosz[(size_t)b * 16384 + mm + amr];
        v.x *= cs.x; v.y *= cs.y; v.z *= cs.z; v.w *= cs.w;
      }
      *(float4*)&As[kki][amr] = v;
    }
    {
      int kg = k0 + wkk;
      #pragma unroll
      for (int j = 0; j < 4; ++j) {
        int gn = n0 + wnn + j;
        float t = 0.f;
        if (gn < 150) {
          if (kg < 150) t = tdt2[kg * 150 + gn];
          else if (kg < 300) t = tdt1[(kg - 150) * 150 + gn];
        }
        Ws[wkk][wnn + j] = t;
      }
    }
    __syncthreads();
    #pragma unroll
    for (int kk = 0; kk < 16; ++kk) {
      float4 a0 = *(const float4*)&As[kk][tm * 8];
      float4 a1 = *(const float4*)&As[kk][tm * 8 + 4];
      float4 w0 = *(const float4*)&Ws[kk][tn * 4];
      float av[8] = {a0.x, a0.y, a0.z, a0.w, a1.x, a1.y, a1.z, a1.w};
      float wv[4] = {w0.x, w0.y, w0.z, w0.w};
      #pragma unroll
      for (int i = 0; i < 8; ++i)
        #pragma unroll
        for (int j = 0; j < 4; ++j)
          acc[i][j] = fmaf(av[i], wv[j], acc[i][j]);
    }
    __syncthreads();
  }
  const int ti = mm >> 12;
  const int nn = mm & 4095;
  #pragma unroll
  for (int j = 0; j < 4; ++j) {
    int kc = n0 + tn * 4 + j;
    if (kc >= 150) continue;
    float4 r0 = make_float4(0.5f * acc[0][j], 0.5f * acc[1][j], 0.5f * acc[2][j], 0.5f * acc[3][j]);
    float4 r1 = make_float4(0.5f * acc[4][j], 0.5f * acc[5][j], 0.5f * acc[6][j], 0.5f * acc[7][j]);
    size_t o1 = ((size_t)b * 150 + kc) * 16384 + mm + tm * 8;
    *(float4*)&csz[o1] = r0;
    *(float4*)&csz[o1 + 4] = r1;
    size_t o2 = (((size_t)b * 4 + ti) * 150 + kc) * 4096 + nn + tm * 8;
    *(float4*)&asg[o2] = r0;
    *(float4*)&asg[o2 + 4] = r1;
  }
}

// ---------------- softmax stats per (b,ti,k) row of 4096 ----------------
__global__ __launch_bounds__(256) void softmax_stats(
    const float* __restrict__ csz, float* __restrict__ mr, float* __restrict__ lr_)
{
  __shared__ float red[256];
  int row = blockIdx.x;
  int bt = row / 150, k = row % 150;
  int b = bt >> 2, ti = bt & 3;
  const float* p = csz + ((size_t)b * 150 + k) * 16384 + ti * 4096;
  float v[16];
  float mx = -1e30f;
  #pragma unroll
  for (int i = 0; i < 16; ++i) { v[i] = p[i * 256 + threadIdx.x]; mx = fmaxf(mx, v[i]); }
  mx = bred_max(mx, red);
  float s = 0.f;
  #pragma unroll
  for (int i = 0; i < 16; ++i) s += expf(v[i] - mx);
  s = bred_sum(s, red);
  if (threadIdx.x == 0) { mr[row] = mx; lr_[row] = s; }
}

// ---------------- cen partials ----------------
__global__ __launch_bounds__(256) void gemm_cen(
    const float* __restrict__ csz, const float* __restrict__ x, const float* __restrict__ mem,
    const float* __restrict__ mr, float* __restrict__ part)
{
  __shared__ __align__(16) float As[160][36];
  __shared__ __align__(16) float Bs[32][36];
  const int tid = threadIdx.x;
  const int c0 = blockIdx.x * 32;
  const int bt = blockIdx.y;
  const int sp = blockIdx.z;
  const int b = bt >> 2, ti = bt & 3;
  const float* xf = (ti < 3) ? (mem + (size_t)(b * 3 + ti) * 4096 * 256)
                             : (x + (size_t)b * 4096 * 256);
  const float* crow = csz + (size_t)b * 150 * 16384 + ti * 4096;
  const int tmr = tid >> 3;
  const int tnc = tid & 7;
  const int ann = tnc * 4;
  float acc[5][4];
  #pragma unroll
  for (int i = 0; i < 5; ++i)
    #pragma unroll
    for (int j = 0; j < 4; ++j) acc[i][j] = 0.f;

  for (int n0 = sp * 256; n0 < sp * 256 + 256; n0 += 32) {
    #pragma unroll
    for (int p = 0; p < 5; ++p) {
      int kcl = tmr + p * 32;
      float4 v = make_float4(0.f, 0.f, 0.f, 0.f);
      if (kcl < 150) {
        v = *(const float4*)&crow[(size_t)kcl * 16384 + n0 + ann];
        float mrv = mr[bt * 150 + kcl];
        v.x = expf(v.x - mrv); v.y = expf(v.y - mrv);
        v.z = expf(v.z - mrv); v.w = expf(v.w - mrv);
      }
      *(float4*)&As[kcl][ann] = v;
    }
    {
      int nr = tid >> 3;
      int cc = (tid & 7) * 4;
      *(float4*)&Bs[nr][cc] = *(const float4*)&xf[(size_t)(n0 + nr) * 256 + c0 + cc];
    }
    __syncthreads();
    #pragma unroll
    for (int kk = 0; kk < 32; kk += 4) {
      float4 b0 = *(const float4*)&Bs[kk + 0][tnc * 4];
      float4 b1 = *(const float4*)&Bs[kk + 1][tnc * 4];
      float4 b2 = *(const float4*)&Bs[kk + 2][tnc * 4];
      float4 b3 = *(const float4*)&Bs[kk + 3][tnc * 4];
      #pragma unroll
      for (int i = 0; i < 5; ++i) {
        float4 a = *(const float4*)&As[tmr * 5 + i][kk];
        acc[i][0] = fmaf(a.x, b0.x, acc[i][0]);
        acc[i][1] = fmaf(a.x, b0.y, acc[i][1]);
        acc[i][2] = fmaf(a.x, b0.z, acc[i][2]);
        acc[i][3] = fmaf(a.x, b0.w, acc[i][3]);
        acc[i][0] = fmaf(a.y, b1.x, acc[i][0]);
        acc[i][1] = fmaf(a.y, b1.y, acc[i][1]);
        acc[i][2] = fmaf(a.y, b1.z, acc[i][2]);
        acc[i][3] = fmaf(a.y, b1.w, acc[i][3]);
        acc[i][0] = fmaf(a.z, b2.x, acc[i][0]);
        acc[i][1] = fmaf(a.z, b2.y, acc[i][1]);
        acc[i][2] = fmaf(a.z, b2.z, acc[i][2]);
        acc[i][3] = fmaf(a.z, b2.w, acc[i][3]);
        acc[i][0] = fmaf(a.w, b3.x, acc[i][0]);
        acc[i][1] = fmaf(a.w, b3.y, acc[i][1]);
        acc[i][2] = fmaf(a.w, b3.z, acc[i][2]);
        acc[i][3] = fmaf(a.w, b3.w, acc[i][3]);
      }
    }
    __syncthreads();
  }
  #pragma unroll
  for (int i = 0; i < 5; ++i) {
    int kcl = tmr * 5 + i;
    if (kcl >= 150) continue;
    float4 r = make_float4(acc[i][0], acc[i][1], acc[i][2], acc[i][3]);
    *(float4*)&part[(((size_t)sp * 8 + bt) * 150 + kcl) * 256 + c0 + tnc * 4] = r;
  }
}

__global__ __launch_bounds__(256) void reduce_cen(
    const float* __restrict__ part, const float* __restrict__ lr_, float* __restrict__ cen)
{
  int row = blockIdx.x;
  int c = threadIdx.x;
  float s = 0.f;
  #pragma unroll
  for (int sp = 0; sp < 16; ++sp)
    s += part[((size_t)sp * 1200 + row) * 256 + c];
  cen[(size_t)row * 256 + c] = s / lr_[row];
}

// ---------------- similarity gate + LN -> C_in ----------------
__global__ __launch_bounds__(256) void gate_ln(
    const float* __restrict__ cen, const float* __restrict__ alpha_, const float* __restrict__ beta_,
    const float* __restrict__ nw, const float* __restrict__ nb, float* __restrict__ cin)
{
  __shared__ float red[256];
  int bk = blockIdx.x;
  int b = bk / 150, k = bk % 150;
  int c = threadIdx.x;
  const float* base = cen + ((size_t)b * 4 * 150) * 256;
  float lc  = base[((size_t)3 * 150 + k) * 256 + c];
  float p0  = base[((size_t)0 * 150 + k) * 256 + c];
  float p1v = base[((size_t)1 * 150 + k) * 256 + c];
  float p2v = base[((size_t)2 * 150 + k) * 256 + c];
  float nl = bred_sum(lc * lc, red);
  float q0 = bred_sum(p0 * p0, red);
  float q1 = bred_sum(p1v * p1v, red);
  float q2 = bred_sum(p2v * p2v, red);
  float d0 = bred_sum(lc * p0, red);
  float d1 = bred_sum(lc * p1v, red);
  float d2 = bred_sum(lc * p2v, red);
  float al = alpha_[0], be = beta_[0];
  float snl = sqrtf(nl);
  float g0 = 1.f / (1.f + expf(-(be + al * (d0 / fmaxf(snl * sqrtf(q0), 1e-8f)))));
  float g1 = 1.f / (1.f + expf(-(be + al * (d1 / fmaxf(snl * sqrtf(q1), 1e-8f)))));
  float g2 = 1.f / (1.f + expf(-(be + al * (d2 / fmaxf(snl * sqrtf(q2), 1e-8f)))));
  float ci = lc + g0 * p0 + g1 * p1v + g2 * p2v;
  float mu = bred_sum(ci, red) * (1.f / 256.f);
  float df = ci - mu;
  float var = bred_sum(df * df, red) * (1.f / 256.f);
  cin[(size_t)bk * 256 + c] = df * rsqrtf(var + 1e-5f) * nw[c] + nb[c];
}

// ---------------- attention ----------------
__global__ __launch_bounds__(128) void attn_k(
    const float* __restrict__ q, const float* __restrict__ ks, const float* __restrict__ vs,
    float* __restrict__ o)
{
  __shared__ float Ks[150][32];
  __shared__ float Vs[150][32];
  int bid = blockIdx.x;
  int ntile = bid & 31, bh = bid >> 5;
  int b = bh >> 3, h = bh & 7;
  for (int idx = threadIdx.x; idx < 4800; idx += 128) {
    int kc = idx >> 5, d = idx & 31;
    Ks[kc][d] = ks[((size_t)b * 150 + kc) * 256 + h * 32 + d];
    Vs[kc][d] = vs[((size_t)b * 150 + kc) * 256 + h * 32 + d];
  }
  __syncthreads();
  int n = ntile * 128 + threadIdx.x;
  const float* qp = q + ((size_t)b * 4096 + n) * 256 + h * 32;
  float qr[32];
  #pragma unroll
  for (int d4 = 0; d4 < 8; ++d4) {
    float4 v = *(const float4*)&qp[d4 * 4];
    qr[d4 * 4 + 0] = v.x; qr[d4 * 4 + 1] = v.y; qr[d4 * 4 + 2] = v.z; qr[d4 * 4 + 3] = v.w;
  }
  float m = -1e30f, l = 0.f;
  for (int kc = 0; kc < 150; ++kc) {
    float s = 0.f;
    #pragma unroll
    for (int d = 0; d < 32; ++d) s = fmaf(qr[d], Ks[kc][d], s);
    float nm = fmaxf(m, s);
    l = l * expf(m - nm) + expf(s - nm);
    m = nm;
  }
  float inv = 1.f / l;
  float acc[32];
  #pragma unroll
  for (int d = 0; d < 32; ++d) acc[d] = 0.f;
  for (int kc = 0; kc < 150; ++kc) {
    float s = 0.f;
    #pragma unroll
    for (int d = 0; d < 32; ++d) s = fmaf(qr[d], Ks[kc][d], s);
    float w = expf(s - m);
    #pragma unroll
    for (int d = 0; d < 32; ++d) acc[d] = fmaf(w, Vs[kc][d], acc[d]);
  }
  float* op = o + ((size_t)b * 4096 + n) * 256 + h * 32;
  #pragma unroll
  for (int d4 = 0; d4 < 8; ++d4) {
    float4 v = make_float4(acc[d4 * 4] * inv, acc[d4 * 4 + 1] * inv,
                           acc[d4 * 4 + 2] * inv, acc[d4 * 4 + 3] * inv);
    *(float4*)&op[d4 * 4] = v;
  }
}

// ---------------- dst = res + LN(src) ----------------
__global__ __launch_bounds__(256) void ln_res(
    const float* __restrict__ src, const float* __restrict__ res,
    const float* __restrict__ nw, const float* __restrict__ nb, float* __restrict__ dst)
{
  __shared__ float red[256];
  size_t row = blockIdx.x;
  int c = threadIdx.x;
  float v = src[row * 256 + c];
  float mu = bred_sum(v, red) * (1.f / 256.f);
  float df = v - mu;
  float var = bred_sum(df * df, red) * (1.f / 256.f);
  dst[row * 256 + c] = res[row * 256 + c] + df * rsqrtf(var + 1e-5f) * nw[c] + nb[c];
}

// ---------------- depthwise 3x3 conv + bias + exact gelu ----------------
__global__ __launch_bounds__(256) void conv_gelu(
    const float* __restrict__ h, const float* __restrict__ w, const float* __restrict__ bias,
    float* __restrict__ hc)
{
  int bid = blockIdx.x;
  int chunk = bid & 3;
  int pix = bid >> 2;
  int b = pix >> 12;
  int n = pix & 4095;
  int y = n >> 6, xx = n & 63;
  int ch = chunk * 256 + threadIdx.x;
  float acc = bias[ch];
  #pragma unroll
  for (int dy = 0; dy < 3; ++dy) {
    int yy = y + dy - 1;
    if (yy < 0 || yy > 63) continue;
    #pragma unroll
    for (int dx = 0; dx < 3; ++dx) {
      int xv = xx + dx - 1;
      if (xv < 0 || xv > 63) continue;
      acc = fmaf(h[((size_t)b * 4096 + yy * 64 + xv) * 1024 + ch], w[ch * 9 + dy * 3 + dx], acc);
    }
  }
  float g = 0.5f * acc * (1.f + erff(acc * 0.70710678118654752f));
  hc[((size_t)b * 4096 + n) * 1024 + ch] = g;
}

extern "C" void kernel_launch(void* const* d_in, const int* in_sizes, int n_in,
                              void* d_out, int out_size, void* d_ws, size_t ws_size,
                              hipStream_t stream)
{
  (void)in_sizes; (void)n_in; (void)out_size; (void)ws_size;
  const float* x    = (const float*)d_in[0];
  const float* z    = (const float*)d_in[1];
  const float* mem  = (const float*)d_in[2];
  const float* cw   = (const float*)d_in[3];
  const float* p1   = (const float*)d_in[4];
  const float* tdt1 = (const float*)d_in[5];
  const float* p2   = (const float*)d_in[6];
  const float* tdt2 = (const float*)d_in[7];
  const float* sal  = (const float*)d_in[8];
  const float* sbe  = (const float*)d_in[9];
  const float* q_w  = (const float*)d_in[10];
  const float* q_b  = (const float*)d_in[11];
  const float* k_w  = (const float*)d_in[12];
  const float* k_b  = (const float*)d_in[13];
  const float* v_w  = (const float*)d_in[14];
  const float* v_b  = (const float*)d_in[15];
  const float* pj_w = (const float*)d_in[16];
  const float* pj_b = (const float*)d_in[17];
  const float* nw   = (const float*)d_in[18];
  const float* nb   = (const float*)d_in[19];
  const float* f1w  = (const float*)d_in[20];
  const float* f1b  = (const float*)d_in[21];
  const float* dww  = (const float*)d_in[22];
  const float* dwb  = (const float*)d_in[23];
  const float* f2w  = (const float*)d_in[24];
  const float* f2b  = (const float*)d_in[25];

  float* out = (float*)d_out;                  // (2,4096,256)
  float* csz = out + 2097152;                  // (2,150,16384)
  float* asg = csz + 4915200;                  // (2,4,150,4096)

  float* ws    = (float*)d_ws;
  float* cl    = ws;                 // dead after gemm_csz
  float* part  = ws;                 // reuses cl region (gemm_cen..reduce_cen)
  float* coscl = ws + 4915200;
  float* cosz  = ws + 4948000;
  float* mr    = ws + 4980800;
  float* lr_   = ws + 4982016;
  float* cen   = ws + 6212032;
  float* cin   = ws + 6519232;
  float* q     = ws + 6596032;
  float* ksb   = ws + 8693184;
  float* vsb   = ws + 8769984;
  float* o     = ws + 8846784;
  float* h     = ws;                 // reuses cl/part region
  float* hc    = ws + 8446976;
  float* tmp   = ws + 16835584;
  float* out1  = ws + 18932736;

  dim3 blk(256);
  // 1. cl = xf @ cw^T
  gemm_cl<<<dim3(256, 3), blk, 0, stream>>>(x, mem, cw, cl);
  // 2. cosine clip factors
  cos_stats<<<dim3(128, 2), blk, 0, stream>>>(z, cl, p1, p2, cosz, coscl);
  // 3. cluster_x_z + assigned
  gemm_csz<<<dim3(256, 3), blk, 0, stream>>>(cl, z, coscl, cosz, tdt2, tdt1, csz, asg);
  // 4. softmax stats
  softmax_stats<<<dim3(1200), blk, 0, stream>>>(csz, mr, lr_);
  // 5. cen
  gemm_cen<<<dim3(8, 8, 16), blk, 0, stream>>>(csz, x, mem, mr, part);
  reduce_cen<<<dim3(1200), blk, 0, stream>>>(part, lr_, cen);
  // 6. gate + LN -> C_in
  gate_ln<<<dim3(300), blk, 0, stream>>>(cen, sal, sbe, nw, nb, cin);
  // 7. q/k/v  (q via MFMA; k/v tiny, fp32)
  gemm_mfma<<<dim3(64, 4), blk, 0, stream>>>(x, q_w, q_b, q, 8192, 256, 256, 0.17677669529663687f);
  gemm_nt<<<dim3(3, 4), blk, 0, stream>>>(cin, k_w, k_b, ksb, 300, 256, 256, 1.f);
  gemm_nt<<<dim3(3, 4), blk, 0, stream>>>(cin, v_w, v_b, vsb, 300, 256, 256, 1.f);
  // 8. attention
  attn_k<<<dim3(512), dim3(128), 0, stream>>>(q, ksb, vsb, o);
  // 9. proj + LN + residual (MFMA)
  gemm_mfma<<<dim3(64, 4), blk, 0, stream>>>(o, pj_w, pj_b, tmp, 8192, 256, 256, 1.f);
  ln_res<<<dim3(8192), blk, 0, stream>>>(tmp, x, nw, nb, out1);
  // 10. MLP (MFMA fc1/fc2)
  gemm_mfma<<<dim3(64, 16), blk, 0, stream>>>(out1, f1w, f1b, h, 8192, 1024, 256, 1.f);
  conv_gelu<<<dim3(32768), blk, 0, stream>>>(h, dww, dwb, hc);
  gemm_mfma<<<dim3(64, 4), blk, 0, stream>>>(hc, f2w, f2b, tmp, 8192, 256, 1024, 1.f);
  ln_res<<<dim3(8192), blk, 0, stream>>>(tmp, out1, nw, nb, out);
}

// Round 4
// 531.242 us; speedup vs baseline: 1.5993x; 1.1630x over previous
//
#include <hip/hip_runtime.h>
#include <math.h>

// Dims: B=2, N=4096, C=256, nc=150, T=4, TN=16384, heads=8, hd=32, hid=1024, H=W=64

typedef __attribute__((ext_vector_type(8))) short bf16x8;
typedef __attribute__((ext_vector_type(4))) float f32x4;

__device__ __forceinline__ short f2b(float f) {
  union { float f; unsigned int u; } c; c.f = f;
  unsigned int r = (c.u + 0x7fffu + ((c.u >> 16) & 1u)) >> 16;
  return (short)r;
}

// ---------------- block reduction helpers (blockDim.x == 256) ----------------
__device__ __forceinline__ float bred_sum(float v, float* red) {
  int tid = threadIdx.x;
  red[tid] = v; __syncthreads();
  #pragma unroll
  for (int s = 128; s > 0; s >>= 1) {
    if (tid < s) red[tid] += red[tid + s];
    __syncthreads();
  }
  float r = red[0]; __syncthreads();
  return r;
}
__device__ __forceinline__ float bred_max(float v, float* red) {
  int tid = threadIdx.x;
  red[tid] = v; __syncthreads();
  #pragma unroll
  for (int s = 128; s > 0; s >>= 1) {
    if (tid < s) red[tid] = fmaxf(red[tid], red[tid + s]);
    __syncthreads();
  }
  float r = red[0]; __syncthreads();
  return r;
}

// ---------------- bf16 MFMA GEMM: out[m][n] = alpha*(sum_k A[m,k]*W[n,k] + bias[n]) ----------------
__global__ __launch_bounds__(256) void gemm_mfma(
    const float* __restrict__ A, const float* __restrict__ W,
    const float* __restrict__ bias, float* __restrict__ out,
    int M, int N, int K, float alpha)
{
  __shared__ __align__(16) short As[128 * 72];
  __shared__ __align__(16) short Bs[64 * 72];
  const int tid = threadIdx.x;
  const int m0 = blockIdx.x * 128;
  const int n0 = blockIdx.y * 64;
  const int wave = tid >> 6;
  const int lane = tid & 63;
  const int wm = wave & 1, wn = wave >> 1;
  const int t16 = lane & 15;
  const int k8 = (lane >> 4) * 8;

  f32x4 acc[4][2];
  #pragma unroll
  for (int i = 0; i < 4; ++i)
    #pragma unroll
    for (int j = 0; j < 2; ++j)
      acc[i][j] = (f32x4){0.f, 0.f, 0.f, 0.f};

  const int sr = tid >> 2;
  const int sk = (tid & 3) * 16;

  for (int k0 = 0; k0 < K; k0 += 64) {
    #pragma unroll
    for (int p = 0; p < 2; ++p) {
      const int row = sr + p * 64;
      const float* ap = &A[(size_t)(m0 + row) * K + k0 + sk];
      float4 v0 = *(const float4*)&ap[0];
      float4 v1 = *(const float4*)&ap[4];
      float4 v2 = *(const float4*)&ap[8];
      float4 v3 = *(const float4*)&ap[12];
      bf16x8 w0, w1;
      w0[0] = f2b(v0.x); w0[1] = f2b(v0.y); w0[2] = f2b(v0.z); w0[3] = f2b(v0.w);
      w0[4] = f2b(v1.x); w0[5] = f2b(v1.y); w0[6] = f2b(v1.z); w0[7] = f2b(v1.w);
      w1[0] = f2b(v2.x); w1[1] = f2b(v2.y); w1[2] = f2b(v2.z); w1[3] = f2b(v2.w);
      w1[4] = f2b(v3.x); w1[5] = f2b(v3.y); w1[6] = f2b(v3.z); w1[7] = f2b(v3.w);
      *(bf16x8*)&As[row * 72 + sk] = w0;
      *(bf16x8*)&As[row * 72 + sk + 8] = w1;
    }
    {
      const float* wp = &W[(size_t)(n0 + sr) * K + k0 + sk];
      float4 v0 = *(const float4*)&wp[0];
      float4 v1 = *(const float4*)&wp[4];
      float4 v2 = *(const float4*)&wp[8];
      float4 v3 = *(const float4*)&wp[12];
      bf16x8 w0, w1;
      w0[0] = f2b(v0.x); w0[1] = f2b(v0.y); w0[2] = f2b(v0.z); w0[3] = f2b(v0.w);
      w0[4] = f2b(v1.x); w0[5] = f2b(v1.y); w0[6] = f2b(v1.z); w0[7] = f2b(v1.w);
      w1[0] = f2b(v2.x); w1[1] = f2b(v2.y); w1[2] = f2b(v2.z); w1[3] = f2b(v2.w);
      w1[4] = f2b(v3.x); w1[5] = f2b(v3.y); w1[6] = f2b(v3.z); w1[7] = f2b(v3.w);
      *(bf16x8*)&Bs[sr * 72 + sk] = w0;
      *(bf16x8*)&Bs[sr * 72 + sk + 8] = w1;
    }
    __syncthreads();
    #pragma unroll
    for (int ks = 0; ks < 2; ++ks) {
      const int kofs = ks * 32 + k8;
      bf16x8 af0 = *(const bf16x8*)&As[(wm * 64 +  0 + t16) * 72 + kofs];
      bf16x8 af1 = *(const bf16x8*)&As[(wm * 64 + 16 + t16) * 72 + kofs];
      bf16x8 af2 = *(const bf16x8*)&As[(wm * 64 + 32 + t16) * 72 + kofs];
      bf16x8 af3 = *(const bf16x8*)&As[(wm * 64 + 48 + t16) * 72 + kofs];
      bf16x8 bf0 = *(const bf16x8*)&Bs[(wn * 32 +  0 + t16) * 72 + kofs];
      bf16x8 bf1 = *(const bf16x8*)&Bs[(wn * 32 + 16 + t16) * 72 + kofs];
      acc[0][0] = __builtin_amdgcn_mfma_f32_16x16x32_bf16(af0, bf0, acc[0][0], 0, 0, 0);
      acc[1][0] = __builtin_amdgcn_mfma_f32_16x16x32_bf16(af1, bf0, acc[1][0], 0, 0, 0);
      acc[2][0] = __builtin_amdgcn_mfma_f32_16x16x32_bf16(af2, bf0, acc[2][0], 0, 0, 0);
      acc[3][0] = __builtin_amdgcn_mfma_f32_16x16x32_bf16(af3, bf0, acc[3][0], 0, 0, 0);
      acc[0][1] = __builtin_amdgcn_mfma_f32_16x16x32_bf16(af0, bf1, acc[0][1], 0, 0, 0);
      acc[1][1] = __builtin_amdgcn_mfma_f32_16x16x32_bf16(af1, bf1, acc[1][1], 0, 0, 0);
      acc[2][1] = __builtin_amdgcn_mfma_f32_16x16x32_bf16(af2, bf1, acc[2][1], 0, 0, 0);
      acc[3][1] = __builtin_amdgcn_mfma_f32_16x16x32_bf16(af3, bf1, acc[3][1], 0, 0, 0);
    }
    __syncthreads();
  }
  const int r4 = (lane >> 4) * 4;
  #pragma unroll
  for (int ni = 0; ni < 2; ++ni) {
    const int gcol = n0 + wn * 32 + ni * 16 + t16;
    const float bb = bias[gcol];
    #pragma unroll
    for (int mi = 0; mi < 4; ++mi) {
      #pragma unroll
      for (int r = 0; r < 4; ++r) {
        const int gm = m0 + wm * 64 + mi * 16 + r4 + r;
        out[(size_t)gm * N + gcol] = alpha * (acc[mi][ni][r] + bb);
      }
    }
  }
}

// ---------------- MFMA cl: clr[b*16384 + ti*4096 + n][kc(160 pad)] = xf @ cw^T ----------------
__global__ __launch_bounds__(256) void gemm_cl_mfma(
    const float* __restrict__ x, const float* __restrict__ mem,
    const float* __restrict__ cw, float* __restrict__ clr)
{
  __shared__ __align__(16) short As[128 * 72];
  __shared__ __align__(16) short Bs[64 * 72];
  const int tid = threadIdx.x;
  const int m0 = blockIdx.x * 128;
  const int n0 = blockIdx.y * 64;
  const int bt = m0 >> 12;
  const int b = bt >> 2, ti = bt & 3;
  const int nbase = m0 & 4095;
  const float* Abase = (ti < 3) ? (mem + (size_t)(b * 3 + ti) * 4096 * 256)
                                : (x + (size_t)b * 4096 * 256);
  const int wave = tid >> 6, lane = tid & 63;
  const int wm = wave & 1, wn = wave >> 1;
  const int t16 = lane & 15;
  const int k8 = (lane >> 4) * 8;

  f32x4 acc[4][2];
  #pragma unroll
  for (int i = 0; i < 4; ++i)
    #pragma unroll
    for (int j = 0; j < 2; ++j)
      acc[i][j] = (f32x4){0.f, 0.f, 0.f, 0.f};

  const int sr = tid >> 2;
  const int sk = (tid & 3) * 16;

  for (int k0 = 0; k0 < 256; k0 += 64) {
    #pragma unroll
    for (int p = 0; p < 2; ++p) {
      const int row = sr + p * 64;
      const float* ap = &Abase[(size_t)(nbase + row) * 256 + k0 + sk];
      float4 v0 = *(const float4*)&ap[0];
      float4 v1 = *(const float4*)&ap[4];
      float4 v2 = *(const float4*)&ap[8];
      float4 v3 = *(const float4*)&ap[12];
      bf16x8 w0, w1;
      w0[0] = f2b(v0.x); w0[1] = f2b(v0.y); w0[2] = f2b(v0.z); w0[3] = f2b(v0.w);
      w0[4] = f2b(v1.x); w0[5] = f2b(v1.y); w0[6] = f2b(v1.z); w0[7] = f2b(v1.w);
      w1[0] = f2b(v2.x); w1[1] = f2b(v2.y); w1[2] = f2b(v2.z); w1[3] = f2b(v2.w);
      w1[4] = f2b(v3.x); w1[5] = f2b(v3.y); w1[6] = f2b(v3.z); w1[7] = f2b(v3.w);
      *(bf16x8*)&As[row * 72 + sk] = w0;
      *(bf16x8*)&As[row * 72 + sk + 8] = w1;
    }
    {
      const int gn = n0 + sr;
      bf16x8 w0 = {0,0,0,0,0,0,0,0}, w1 = {0,0,0,0,0,0,0,0};
      if (gn < 150) {
        const float* wp = &cw[(size_t)gn * 256 + k0 + sk];
        float4 v0 = *(const float4*)&wp[0];
        float4 v1 = *(const float4*)&wp[4];
        float4 v2 = *(const float4*)&wp[8];
        float4 v3 = *(const float4*)&wp[12];
        w0[0] = f2b(v0.x); w0[1] = f2b(v0.y); w0[2] = f2b(v0.z); w0[3] = f2b(v0.w);
        w0[4] = f2b(v1.x); w0[5] = f2b(v1.y); w0[6] = f2b(v1.z); w0[7] = f2b(v1.w);
        w1[0] = f2b(v2.x); w1[1] = f2b(v2.y); w1[2] = f2b(v2.z); w1[3] = f2b(v2.w);
        w1[4] = f2b(v3.x); w1[5] = f2b(v3.y); w1[6] = f2b(v3.z); w1[7] = f2b(v3.w);
      }
      *(bf16x8*)&Bs[sr * 72 + sk] = w0;
      *(bf16x8*)&Bs[sr * 72 + sk + 8] = w1;
    }
    __syncthreads();
    #pragma unroll
    for (int ks = 0; ks < 2; ++ks) {
      const int kofs = ks * 32 + k8;
      bf16x8 af0 = *(const bf16x8*)&As[(wm * 64 +  0 + t16) * 72 + kofs];
      bf16x8 af1 = *(const bf16x8*)&As[(wm * 64 + 16 + t16) * 72 + kofs];
      bf16x8 af2 = *(const bf16x8*)&As[(wm * 64 + 32 + t16) * 72 + kofs];
      bf16x8 af3 = *(const bf16x8*)&As[(wm * 64 + 48 + t16) * 72 + kofs];
      bf16x8 bf0 = *(const bf16x8*)&Bs[(wn * 32 +  0 + t16) * 72 + kofs];
      bf16x8 bf1 = *(const bf16x8*)&Bs[(wn * 32 + 16 + t16) * 72 + kofs];
      acc[0][0] = __builtin_amdgcn_mfma_f32_16x16x32_bf16(af0, bf0, acc[0][0], 0, 0, 0);
      acc[1][0] = __builtin_amdgcn_mfma_f32_16x16x32_bf16(af1, bf0, acc[1][0], 0, 0, 0);
      acc[2][0] = __builtin_amdgcn_mfma_f32_16x16x32_bf16(af2, bf0, acc[2][0], 0, 0, 0);
      acc[3][0] = __builtin_amdgcn_mfma_f32_16x16x32_bf16(af3, bf0, acc[3][0], 0, 0, 0);
      acc[0][1] = __builtin_amdgcn_mfma_f32_16x16x32_bf16(af0, bf1, acc[0][1], 0, 0, 0);
      acc[1][1] = __builtin_amdgcn_mfma_f32_16x16x32_bf16(af1, bf1, acc[1][1], 0, 0, 0);
      acc[2][1] = __builtin_amdgcn_mfma_f32_16x16x32_bf16(af2, bf1, acc[2][1], 0, 0, 0);
      acc[3][1] = __builtin_amdgcn_mfma_f32_16x16x32_bf16(af3, bf1, acc[3][1], 0, 0, 0);
    }
    __syncthreads();
  }
  const int r4 = (lane >> 4) * 4;
  const size_t rowbase = (size_t)b * 16384 + ti * 4096 + nbase;
  #pragma unroll
  for (int ni = 0; ni < 2; ++ni) {
    const int col = n0 + wn * 32 + ni * 16 + t16;
    if (col >= 160) continue;
    #pragma unroll
    for (int mi = 0; mi < 4; ++mi) {
      const int mrow = wm * 64 + mi * 16 + r4;
      #pragma unroll
      for (int r = 0; r < 4; ++r)
        clr[(rowbase + mrow + r) * 160 + col] = acc[mi][ni][r];
    }
  }
}

// ---------------- cosine clip factors (y=0: z strided; y=1: clr row-major) ----------------
__global__ __launch_bounds__(256) void cos_stats(
    const float* __restrict__ z, const float* __restrict__ clr,
    const float* __restrict__ p1, const float* __restrict__ p2,
    float* __restrict__ cosz, float* __restrict__ coscl)
{
  int which = blockIdx.y;
  int gid = blockIdx.x * 256 + threadIdx.x;
  int b = gid >> 14, m = gid & 16383;
  float d = 0, s = 0, pn = 0;
  if (which) {
    const float* sp = clr + ((size_t)b * 16384 + m) * 160;
    for (int k = 0; k < 148; k += 4) {
      float4 v = *(const float4*)&sp[k];
      float4 a = *(const float4*)&p2[k];
      d += v.x * a.x + v.y * a.y + v.z * a.z + v.w * a.w;
      s += v.x * v.x + v.y * v.y + v.z * v.z + v.w * v.w;
      pn += a.x * a.x + a.y * a.y + a.z * a.z + a.w * a.w;
    }
    for (int k = 148; k < 150; ++k) {
      float v = sp[k], a = p2[k];
      d += v * a; s += v * v; pn += a * a;
    }
    float c = d / (fmaxf(sqrtf(s), 1e-12f) * fmaxf(sqrtf(pn), 1e-12f));
    coscl[gid] = fminf(fmaxf(c, 0.f), 1.f);
  } else {
    const float* sp = z + (size_t)b * 150 * 16384 + m;
    for (int k = 0; k < 150; ++k) {
      float v = sp[(size_t)k * 16384];
      float a = p1[k];
      d += v * a; s += v * v; pn += a * a;
    }
    float c = d / (fmaxf(sqrtf(s), 1e-12f) * fmaxf(sqrtf(pn), 1e-12f));
    cosz[gid] = fminf(fmaxf(c, 0.f), 1.f);
  }
}

// ---------------- MFMA csz: csz[b][kc][m] = 0.5*(coscl*cl@tdt2 + cosz*z@tdt1), + asg ----------------
// K=320 in BK=32 chunks: 0-4 from clr (row-major), 5-9 from z (LDS transpose staging)
__global__ __launch_bounds__(256) void gemm_csz_mfma(
    const float* __restrict__ clr, const float* __restrict__ z,
    const float* __restrict__ coscl, const float* __restrict__ cosz,
    const float* __restrict__ tdt2, const float* __restrict__ tdt1,
    float* __restrict__ csz, float* __restrict__ asg)
{
  __shared__ __align__(16) short As[128 * 40];
  __shared__ __align__(16) short Bs[64 * 40];
  const int tid = threadIdx.x;
  const int m0 = blockIdx.x * 128;
  const int b = m0 >> 14;
  const int mm = m0 & 16383;
  const int n0 = blockIdx.y * 64;
  const int wave = tid >> 6, lane = tid & 63;
  const int wm = wave & 1, wn = wave >> 1;
  const int t16 = lane & 15;
  const int k8 = (lane >> 4) * 8;

  f32x4 acc[4][2];
  #pragma unroll
  for (int i = 0; i < 4; ++i)
    #pragma unroll
    for (int j = 0; j < 2; ++j)
      acc[i][j] = (f32x4){0.f, 0.f, 0.f, 0.f};

  for (int c = 0; c < 10; ++c) {
    if (c < 5) {
      // cl chunk, row-major: row = tid>>1, 16 cols starting c*32 + (tid&1)*16
      const int row = tid >> 1;
      const int sk0 = (tid & 1) * 16;
      const float* ap = &clr[((size_t)b * 16384 + mm + row) * 160 + c * 32 + sk0];
      const float cs = coscl[(size_t)b * 16384 + mm + row];
      float4 v0 = *(const float4*)&ap[0];
      float4 v1 = *(const float4*)&ap[4];
      float4 v2 = *(const float4*)&ap[8];
      float4 v3 = *(const float4*)&ap[12];
      bf16x8 w0, w1;
      w0[0] = f2b(v0.x * cs); w0[1] = f2b(v0.y * cs); w0[2] = f2b(v0.z * cs); w0[3] = f2b(v0.w * cs);
      w0[4] = f2b(v1.x * cs); w0[5] = f2b(v1.y * cs); w0[6] = f2b(v1.z * cs); w0[7] = f2b(v1.w * cs);
      w1[0] = f2b(v2.x * cs); w1[1] = f2b(v2.y * cs); w1[2] = f2b(v2.z * cs); w1[3] = f2b(v2.w * cs);
      w1[4] = f2b(v3.x * cs); w1[5] = f2b(v3.y * cs); w1[6] = f2b(v3.z * cs); w1[7] = f2b(v3.w * cs);
      *(bf16x8*)&As[row * 40 + sk0] = w0;
      *(bf16x8*)&As[row * 40 + sk0 + 8] = w1;
    } else {
      // z chunk, transpose staging
      const int kgl = tid >> 3;            // 0..31
      const int mb = (tid & 7) * 4;
      const int kg = (c - 5) * 32 + kgl;   // 0..159
      #pragma unroll
      for (int p = 0; p < 4; ++p) {
        const int m = mb + p * 32;
        float4 v = make_float4(0.f, 0.f, 0.f, 0.f);
        if (kg < 150) {
          v = *(const float4*)&z[((size_t)b * 150 + kg) * 16384 + mm + m];
          float4 cz = *(const float4*)&cosz[(size_t)b * 16384 + mm + m];
          v.x *= cz.x; v.y *= cz.y; v.z *= cz.z; v.w *= cz.w;
        }
        As[(m + 0) * 40 + kgl] = f2b(v.x);
        As[(m + 1) * 40 + kgl] = f2b(v.y);
        As[(m + 2) * 40 + kgl] = f2b(v.z);
        As[(m + 3) * 40 + kgl] = f2b(v.w);
      }
    }
    // B: Bs[kc][kgl] = stacked[c*32+kgl][n0+kc]
    {
      const int kc = tid & 63;
      const int gn = n0 + kc;
      #pragma unroll
      for (int p = 0; p < 8; ++p) {
        const int kgl = (tid >> 6) + p * 4;
        const int kg = c * 32 + kgl;
        float t = 0.f;
        if (gn < 150) {
          if (kg < 150) t = tdt2[kg * 150 + gn];
          else if (kg >= 160 && kg < 310) t = tdt1[(kg - 160) * 150 + gn];
        }
        Bs[kc * 40 + kgl] = f2b(t);
      }
    }
    __syncthreads();
    {
      bf16x8 af0 = *(const bf16x8*)&As[(wm * 64 +  0 + t16) * 40 + k8];
      bf16x8 af1 = *(const bf16x8*)&As[(wm * 64 + 16 + t16) * 40 + k8];
      bf16x8 af2 = *(const bf16x8*)&As[(wm * 64 + 32 + t16) * 40 + k8];
      bf16x8 af3 = *(const bf16x8*)&As[(wm * 64 + 48 + t16) * 40 + k8];
      bf16x8 bf0 = *(const bf16x8*)&Bs[(wn * 32 +  0 + t16) * 40 + k8];
      bf16x8 bf1 = *(const bf16x8*)&Bs[(wn * 32 + 16 + t16) * 40 + k8];
      acc[0][0] = __builtin_amdgcn_mfma_f32_16x16x32_bf16(af0, bf0, acc[0][0], 0, 0, 0);
      acc[1][0] = __builtin_amdgcn_mfma_f32_16x16x32_bf16(af1, bf0, acc[1][0], 0, 0, 0);
      acc[2][0] = __builtin_amdgcn_mfma_f32_16x16x32_bf16(af2, bf0, acc[2][0], 0, 0, 0);
      acc[3][0] = __builtin_amdgcn_mfma_f32_16x16x32_bf16(af3, bf0, acc[3][0], 0, 0, 0);
      acc[0][1] = __builtin_amdgcn_mfma_f32_16x16x32_bf16(af0, bf1, acc[0][1], 0, 0, 0);
      acc[1][1] = __builtin_amdgcn_mfma_f32_16x16x32_bf16(af1, bf1, acc[1][1], 0, 0, 0);
      acc[2][1] = __builtin_amdgcn_mfma_f32_16x16x32_bf16(af2, bf1, acc[2][1], 0, 0, 0);
      acc[3][1] = __builtin_amdgcn_mfma_f32_16x16x32_bf16(af3, bf1, acc[3][1], 0, 0, 0);
    }
    __syncthreads();
  }
  const int r4 = (lane >> 4) * 4;
  const int ti = mm >> 12;
  const int nn = mm & 4095;
  #pragma unroll
  for (int ni = 0; ni < 2; ++ni) {
    const int kc = n0 + wn * 32 + ni * 16 + t16;
    if (kc >= 150) continue;
    #pragma unroll
    for (int mi = 0; mi < 4; ++mi) {
      const int mrow = wm * 64 + mi * 16 + r4;
      float4 r;
      r.x = 0.5f * acc[mi][ni][0];
      r.y = 0.5f * acc[mi][ni][1];
      r.z = 0.5f * acc[mi][ni][2];
      r.w = 0.5f * acc[mi][ni][3];
      *(float4*)&csz[((size_t)b * 150 + kc) * 16384 + mm + mrow] = r;
      *(float4*)&asg[(((size_t)b * 4 + ti) * 150 + kc) * 4096 + nn + mrow] = r;
    }
  }
}

// ---------------- softmax stats per (b,ti,k) row of 4096 ----------------
__global__ __launch_bounds__(256) void softmax_stats(
    const float* __restrict__ csz, float* __restrict__ mr, float* __restrict__ lr_)
{
  __shared__ float red[256];
  int row = blockIdx.x;
  int bt = row / 150, k = row % 150;
  int b = bt >> 2, ti = bt & 3;
  const float* p = csz + ((size_t)b * 150 + k) * 16384 + ti * 4096;
  float v[16];
  float mx = -1e30f;
  #pragma unroll
  for (int i = 0; i < 16; ++i) { v[i] = p[i * 256 + threadIdx.x]; mx = fmaxf(mx, v[i]); }
  mx = bred_max(mx, red);
  float s = 0.f;
  #pragma unroll
  for (int i = 0; i < 16; ++i) s += expf(v[i] - mx);
  s = bred_sum(s, red);
  if (threadIdx.x == 0) { mr[row] = mx; lr_[row] = s; }
}

// ---------------- cen partials ----------------
__global__ __launch_bounds__(256) void gemm_cen(
    const float* __restrict__ csz, const float* __restrict__ x, const float* __restrict__ mem,
    const float* __restrict__ mr, float* __restrict__ part)
{
  __shared__ __align__(16) float As[160][36];
  __shared__ __align__(16) float Bs[32][36];
  const int tid = threadIdx.x;
  const int c0 = blockIdx.x * 32;
  const int bt = blockIdx.y;
  const int sp = blockIdx.z;
  const int b = bt >> 2, ti = bt & 3;
  const float* xf = (ti < 3) ? (mem + (size_t)(b * 3 + ti) * 4096 * 256)
                             : (x + (size_t)b * 4096 * 256);
  const float* crow = csz + (size_t)b * 150 * 16384 + ti * 4096;
  const int tmr = tid >> 3;
  const int tnc = tid & 7;
  const int ann = tnc * 4;
  float acc[5][4];
  #pragma unroll
  for (int i = 0; i < 5; ++i)
    #pragma unroll
    for (int j = 0; j < 4; ++j) acc[i][j] = 0.f;

  for (int n0 = sp * 256; n0 < sp * 256 + 256; n0 += 32) {
    #pragma unroll
    for (int p = 0; p < 5; ++p) {
      int kcl = tmr + p * 32;
      float4 v = make_float4(0.f, 0.f, 0.f, 0.f);
      if (kcl < 150) {
        v = *(const float4*)&crow[(size_t)kcl * 16384 + n0 + ann];
        float mrv = mr[bt * 150 + kcl];
        v.x = expf(v.x - mrv); v.y = expf(v.y - mrv);
        v.z = expf(v.z - mrv); v.w = expf(v.w - mrv);
      }
      *(float4*)&As[kcl][ann] = v;
    }
    {
      int nr = tid >> 3;
      int cc = (tid & 7) * 4;
      *(float4*)&Bs[nr][cc] = *(const float4*)&xf[(size_t)(n0 + nr) * 256 + c0 + cc];
    }
    __syncthreads();
    #pragma unroll
    for (int kk = 0; kk < 32; kk += 4) {
      float4 b0 = *(const float4*)&Bs[kk + 0][tnc * 4];
      float4 b1 = *(const float4*)&Bs[kk + 1][tnc * 4];
      float4 b2 = *(const float4*)&Bs[kk + 2][tnc * 4];
      float4 b3 = *(const float4*)&Bs[kk + 3][tnc * 4];
      #pragma unroll
      for (int i = 0; i < 5; ++i) {
        float4 a = *(const float4*)&As[tmr * 5 + i][kk];
        acc[i][0] = fmaf(a.x, b0.x, acc[i][0]);
        acc[i][1] = fmaf(a.x, b0.y, acc[i][1]);
        acc[i][2] = fmaf(a.x, b0.z, acc[i][2]);
        acc[i][3] = fmaf(a.x, b0.w, acc[i][3]);
        acc[i][0] = fmaf(a.y, b1.x, acc[i][0]);
        acc[i][1] = fmaf(a.y, b1.y, acc[i][1]);
        acc[i][2] = fmaf(a.y, b1.z, acc[i][2]);
        acc[i][3] = fmaf(a.y, b1.w, acc[i][3]);
        acc[i][0] = fmaf(a.z, b2.x, acc[i][0]);
        acc[i][1] = fmaf(a.z, b2.y, acc[i][1]);
        acc[i][2] = fmaf(a.z, b2.z, acc[i][2]);
        acc[i][3] = fmaf(a.z, b2.w, acc[i][3]);
        acc[i][0] = fmaf(a.w, b3.x, acc[i][0]);
        acc[i][1] = fmaf(a.w, b3.y, acc[i][1]);
        acc[i][2] = fmaf(a.w, b3.z, acc[i][2]);
        acc[i][3] = fmaf(a.w, b3.w, acc[i][3]);
      }
    }
    __syncthreads();
  }
  #pragma unroll
  for (int i = 0; i < 5; ++i) {
    int kcl = tmr * 5 + i;
    if (kcl >= 150) continue;
    float4 r = make_float4(acc[i][0], acc[i][1], acc[i][2], acc[i][3]);
    *(float4*)&part[(((size_t)sp * 8 + bt) * 150 + kcl) * 256 + c0 + tnc * 4] = r;
  }
}

__global__ __launch_bounds__(256) void reduce_cen(
    const float* __restrict__ part, const float* __restrict__ lr_, float* __restrict__ cen)
{
  int row = blockIdx.x;
  int c = threadIdx.x;
  float s = 0.f;
  #pragma unroll
  for (int sp = 0; sp < 16; ++sp)
    s += part[((size_t)sp * 1200 + row) * 256 + c];
  cen[(size_t)row * 256 + c] = s / lr_[row];
}

// ---------------- similarity gate + LN -> C_in ----------------
__global__ __launch_bounds__(256) void gate_ln(
    const float* __restrict__ cen, const float* __restrict__ alpha_, const float* __restrict__ beta_,
    const float* __restrict__ nw, const float* __restrict__ nb, float* __restrict__ cin)
{
  __shared__ float red[256];
  int bk = blockIdx.x;
  int b = bk / 150, k = bk % 150;
  int c = threadIdx.x;
  const float* base = cen + ((size_t)b * 4 * 150) * 256;
  float lc  = base[((size_t)3 * 150 + k) * 256 + c];
  float p0  = base[((size_t)0 * 150 + k) * 256 + c];
  float p1v = base[((size_t)1 * 150 + k) * 256 + c];
  float p2v = base[((size_t)2 * 150 + k) * 256 + c];
  float nl = bred_sum(lc * lc, red);
  float q0 = bred_sum(p0 * p0, red);
  float q1 = bred_sum(p1v * p1v, red);
  float q2 = bred_sum(p2v * p2v, red);
  float d0 = bred_sum(lc * p0, red);
  float d1 = bred_sum(lc * p1v, red);
  float d2 = bred_sum(lc * p2v, red);
  float al = alpha_[0], be = beta_[0];
  float snl = sqrtf(nl);
  float g0 = 1.f / (1.f + expf(-(be + al * (d0 / fmaxf(snl * sqrtf(q0), 1e-8f)))));
  float g1 = 1.f / (1.f + expf(-(be + al * (d1 / fmaxf(snl * sqrtf(q1), 1e-8f)))));
  float g2 = 1.f / (1.f + expf(-(be + al * (d2 / fmaxf(snl * sqrtf(q2), 1e-8f)))));
  float ci = lc + g0 * p0 + g1 * p1v + g2 * p2v;
  float mu = bred_sum(ci, red) * (1.f / 256.f);
  float df = ci - mu;
  float var = bred_sum(df * df, red) * (1.f / 256.f);
  cin[(size_t)bk * 256 + c] = df * rsqrtf(var + 1e-5f) * nw[c] + nb[c];
}

// ---------------- generic fp32 GEMM (small shapes: k/v) ----------------
__global__ __launch_bounds__(256) void gemm_nt(
    const float* __restrict__ A, const float* __restrict__ W,
    const float* __restrict__ bias, float* __restrict__ out,
    int M, int N, int K, float alpha)
{
  __shared__ __align__(16) float As[16][132];
  __shared__ __align__(16) float Ws[16][68];
  const int tid = threadIdx.x;
  const int m0 = blockIdx.x * 128;
  const int n0 = blockIdx.y * 64;
  const int tm = tid & 15;
  const int tn = tid >> 4;
  float acc[8][4];
  #pragma unroll
  for (int i = 0; i < 8; ++i)
    #pragma unroll
    for (int j = 0; j < 4; ++j) acc[i][j] = 0.f;

  const int lr = tid >> 2;
  const int lk = (tid & 3) * 4;

  for (int k0 = 0; k0 < K; k0 += 16) {
    #pragma unroll
    for (int p = 0; p < 2; ++p) {
      int r = lr + p * 64;
      int gm = m0 + r;
      float4 v = make_float4(0.f, 0.f, 0.f, 0.f);
      if (gm < M) v = *(const float4*)&A[(size_t)gm * K + k0 + lk];
      As[lk + 0][r] = v.x; As[lk + 1][r] = v.y; As[lk + 2][r] = v.z; As[lk + 3][r] = v.w;
    }
    {
      float4 v = *(const float4*)&W[(size_t)(n0 + lr) * K + k0 + lk];
      Ws[lk + 0][lr] = v.x; Ws[lk + 1][lr] = v.y; Ws[lk + 2][lr] = v.z; Ws[lk + 3][lr] = v.w;
    }
    __syncthreads();
    #pragma unroll
    for (int kk = 0; kk < 16; ++kk) {
      float4 a0 = *(const float4*)&As[kk][tm * 8];
      float4 a1 = *(const float4*)&As[kk][tm * 8 + 4];
      float4 w0 = *(const float4*)&Ws[kk][tn * 4];
      float av[8] = {a0.x, a0.y, a0.z, a0.w, a1.x, a1.y, a1.z, a1.w};
      float wv[4] = {w0.x, w0.y, w0.z, w0.w};
      #pragma unroll
      for (int i = 0; i < 8; ++i)
        #pragma unroll
        for (int j = 0; j < 4; ++j)
          acc[i][j] = fmaf(av[i], wv[j], acc[i][j]);
    }
    __syncthreads();
  }
  float4 bv = *(const float4*)&bias[n0 + tn * 4];
  float bb[4] = {bv.x, bv.y, bv.z, bv.w};
  #pragma unroll
  for (int i = 0; i < 8; ++i) {
    int gm = m0 + tm * 8 + i;
    if (gm >= M) continue;
    float4 r;
    r.x = alpha * (acc[i][0] + bb[0]);
    r.y = alpha * (acc[i][1] + bb[1]);
    r.z = alpha * (acc[i][2] + bb[2]);
    r.w = alpha * (acc[i][3] + bb[3]);
    *(float4*)&out[(size_t)gm * N + n0 + tn * 4] = r;
  }
}

// ---------------- MFMA attention: 128 Q-rows/block, per (b,h) ----------------
__global__ __launch_bounds__(256) void attn_mfma(
    const float* __restrict__ q, const float* __restrict__ ks, const float* __restrict__ vs,
    float* __restrict__ o)
{
  __shared__ __align__(16) short Ps[128 * 168];
  __shared__ __align__(16) short VT[32 * 168];
  __shared__ float lrow[128];
  const int tid = threadIdx.x;
  const int bid = blockIdx.x;
  const int ntile = bid & 31;
  const int bh = bid >> 5;
  const int b = bh >> 3, h = bh & 7;
  const int n0 = ntile * 128;
  const int wave = tid >> 6, lane = tid & 63;
  const int t16 = lane & 15, quad = lane >> 4;
  const int k8 = quad * 8;
  const int wr = wave * 32;

  // stage V^T (bf16, zero-pad kc>=150)
  for (int i = tid; i < 5120; i += 256) {
    int d = i / 160, kc = i - d * 160;
    VT[d * 168 + kc] = (kc < 150) ? f2b(vs[((size_t)b * 150 + kc) * 256 + h * 32 + d]) : (short)0;
  }

  // Q A-frags direct from global
  bf16x8 aQ[2];
  #pragma unroll
  for (int mt = 0; mt < 2; ++mt) {
    const float* qp = &q[((size_t)b * 4096 + n0 + wr + mt * 16 + t16) * 256 + h * 32 + k8];
    float4 v0 = *(const float4*)&qp[0];
    float4 v1 = *(const float4*)&qp[4];
    bf16x8 w;
    w[0] = f2b(v0.x); w[1] = f2b(v0.y); w[2] = f2b(v0.z); w[3] = f2b(v0.w);
    w[4] = f2b(v1.x); w[5] = f2b(v1.y); w[6] = f2b(v1.z); w[7] = f2b(v1.w);
    aQ[mt] = w;
  }

  // S = Q @ K^T (10 col-tiles of 16)
  f32x4 s[2][10];
  #pragma unroll
  for (int ct = 0; ct < 10; ++ct) {
    const int c = ct * 16 + t16;
    bf16x8 bK = {0, 0, 0, 0, 0, 0, 0, 0};
    if (c < 150) {
      const float* kp = &ks[((size_t)b * 150 + c) * 256 + h * 32 + k8];
      float4 v0 = *(const float4*)&kp[0];
      float4 v1 = *(const float4*)&kp[4];
      bK[0] = f2b(v0.x); bK[1] = f2b(v0.y); bK[2] = f2b(v0.z); bK[3] = f2b(v0.w);
      bK[4] = f2b(v1.x); bK[5] = f2b(v1.y); bK[6] = f2b(v1.z); bK[7] = f2b(v1.w);
    }
    f32x4 zero = (f32x4){0.f, 0.f, 0.f, 0.f};
    s[0][ct] = __builtin_amdgcn_mfma_f32_16x16x32_bf16(aQ[0], bK, zero, 0, 0, 0);
    s[1][ct] = __builtin_amdgcn_mfma_f32_16x16x32_bf16(aQ[1], bK, zero, 0, 0, 0);
  }

  // softmax per row (row = wr + mt*16 + quad*4 + r, cols spread over 16 lanes x 10 ct)
  #pragma unroll
  for (int mt = 0; mt < 2; ++mt) {
    #pragma unroll
    for (int r = 0; r < 4; ++r) {
      float mx = -1e30f;
      #pragma unroll
      for (int ct = 0; ct < 10; ++ct) {
        float v = s[mt][ct][r];
        if (ct == 9 && t16 >= 6) { v = -1e30f; s[mt][ct][r] = v; }
        mx = fmaxf(mx, v);
      }
      mx = fmaxf(mx, __shfl_xor(mx, 1));
      mx = fmaxf(mx, __shfl_xor(mx, 2));
      mx = fmaxf(mx, __shfl_xor(mx, 4));
      mx = fmaxf(mx, __shfl_xor(mx, 8));
      float ls = 0.f;
      #pragma unroll
      for (int ct = 0; ct < 10; ++ct) {
        float e = expf(s[mt][ct][r] - mx);
        s[mt][ct][r] = e;
        ls += e;
      }
      ls += __shfl_xor(ls, 1);
      ls += __shfl_xor(ls, 2);
      ls += __shfl_xor(ls, 4);
      ls += __shfl_xor(ls, 8);
      if (t16 == 0) lrow[wr + mt * 16 + quad * 4 + r] = 1.f / ls;
      // write P (bf16) to LDS in row-major for A-frag reload
      #pragma unroll
      for (int ct = 0; ct < 10; ++ct)
        Ps[(wr + mt * 16 + quad * 4 + r) * 168 + ct * 16 + t16] = f2b(s[mt][ct][r]);
    }
  }
  __syncthreads();

  // O = P @ V (K=160 in 5 steps of 32)
  f32x4 oacc[2][2];
  #pragma unroll
  for (int i = 0; i < 2; ++i)
    #pragma unroll
    for (int j = 0; j < 2; ++j)
      oacc[i][j] = (f32x4){0.f, 0.f, 0.f, 0.f};
  #pragma unroll
  for (int kstep = 0; kstep < 5; ++kstep) {
    bf16x8 bV0 = *(const bf16x8*)&VT[( 0 + t16) * 168 + kstep * 32 + k8];
    bf16x8 bV1 = *(const bf16x8*)&VT[(16 + t16) * 168 + kstep * 32 + k8];
    #pragma unroll
    for (int mt = 0; mt < 2; ++mt) {
      bf16x8 aP = *(const bf16x8*)&Ps[(wr + mt * 16 + t16) * 168 + kstep * 32 + k8];
      oacc[mt][0] = __builtin_amdgcn_mfma_f32_16x16x32_bf16(aP, bV0, oacc[mt][0], 0, 0, 0);
      oacc[mt][1] = __builtin_amdgcn_mfma_f32_16x16x32_bf16(aP, bV1, oacc[mt][1], 0, 0, 0);
    }
  }
  // epilogue
  #pragma unroll
  for (int mt = 0; mt < 2; ++mt) {
    #pragma unroll
    for (int nt = 0; nt < 2; ++nt) {
      const int d = nt * 16 + t16;
      #pragma unroll
      for (int r = 0; r < 4; ++r) {
        const int row = wr + mt * 16 + quad * 4 + r;
        o[((size_t)b * 4096 + n0 + row) * 256 + h * 32 + d] = oacc[mt][nt][r] * lrow[row];
      }
    }
  }
}

// ---------------- dst = res + LN(src) ----------------
__global__ __launch_bounds__(256) void ln_res(
    const float* __restrict__ src, const float* __restrict__ res,
    const float* __restrict__ nw, const float* __restrict__ nb, float* __restrict__ dst)
{
  __shared__ float red[256];
  size_t row = blockIdx.x;
  int c = threadIdx.x;
  float v = src[row * 256 + c];
  float mu = bred_sum(v, red) * (1.f / 256.f);
  float df = v - mu;
  float var = bred_sum(df * df, red) * (1.f / 256.f);
  dst[row * 256 + c] = res[row * 256 + c] + df * rsqrtf(var + 1e-5f) * nw[c] + nb[c];
}

// ---------------- depthwise 3x3 conv + bias + exact gelu ----------------
__global__ __launch_bounds__(256) void conv_gelu(
    const float* __restrict__ h, const float* __restrict__ w, const float* __restrict__ bias,
    float* __restrict__ hc)
{
  int bid = blockIdx.x;
  int chunk = bid & 3;
  int pix = bid >> 2;
  int b = pix >> 12;
  int n = pix & 4095;
  int y = n >> 6, xx = n & 63;
  int ch = chunk * 256 + threadIdx.x;
  float acc = bias[ch];
  #pragma unroll
  for (int dy = 0; dy < 3; ++dy) {
    int yy = y + dy - 1;
    if (yy < 0 || yy > 63) continue;
    #pragma unroll
    for (int dx = 0; dx < 3; ++dx) {
      int xv = xx + dx - 1;
      if (xv < 0 || xv > 63) continue;
      acc = fmaf(h[((size_t)b * 4096 + yy * 64 + xv) * 1024 + ch], w[ch * 9 + dy * 3 + dx], acc);
    }
  }
  float g = 0.5f * acc * (1.f + erff(acc * 0.70710678118654752f));
  hc[((size_t)b * 4096 + n) * 1024 + ch] = g;
}

extern "C" void kernel_launch(void* const* d_in, const int* in_sizes, int n_in,
                              void* d_out, int out_size, void* d_ws, size_t ws_size,
                              hipStream_t stream)
{
  (void)in_sizes; (void)n_in; (void)out_size; (void)ws_size;
  const float* x    = (const float*)d_in[0];
  const float* z    = (const float*)d_in[1];
  const float* mem  = (const float*)d_in[2];
  const float* cw   = (const float*)d_in[3];
  const float* p1   = (const float*)d_in[4];
  const float* tdt1 = (const float*)d_in[5];
  const float* p2   = (const float*)d_in[6];
  const float* tdt2 = (const float*)d_in[7];
  const float* sal  = (const float*)d_in[8];
  const float* sbe  = (const float*)d_in[9];
  const float* q_w  = (const float*)d_in[10];
  const float* q_b  = (const float*)d_in[11];
  const float* k_w  = (const float*)d_in[12];
  const float* k_b  = (const float*)d_in[13];
  const float* v_w  = (const float*)d_in[14];
  const float* v_b  = (const float*)d_in[15];
  const float* pj_w = (const float*)d_in[16];
  const float* pj_b = (const float*)d_in[17];
  const float* nw   = (const float*)d_in[18];
  const float* nb   = (const float*)d_in[19];
  const float* f1w  = (const float*)d_in[20];
  const float* f1b  = (const float*)d_in[21];
  const float* dww  = (const float*)d_in[22];
  const float* dwb  = (const float*)d_in[23];
  const float* f2w  = (const float*)d_in[24];
  const float* f2b_ = (const float*)d_in[25];

  float* out = (float*)d_out;                  // (2,4096,256)
  float* csz = out + 2097152;                  // (2,150,16384)
  float* asg = csz + 4915200;                  // (2,4,150,4096)

  float* ws    = (float*)d_ws;
  float* clr   = ws;                 // 5,242,880 (row-major 160-wide), dead after gemm_csz
  float* part  = ws;                 // 4,915,200 reuse (gemm_cen..reduce_cen)
  float* coscl = ws + 5242880;       // 32,768
  float* cosz  = ws + 5275648;       // 32,768
  float* mr    = ws + 5308416;       // 1,200
  float* lr_   = ws + 5309616;       // 1,200
  float* cen   = ws + 5310816;       // 307,200
  float* cin   = ws + 5618016;       // 76,800
  float* q     = ws + 5694816;       // 2,097,152 dead after attn
  float* ksb   = ws + 7791968;       // 76,800    dead after attn
  float* vsb   = ws + 7868768;       // 76,800    dead after attn
  float* o     = ws + 7945568;       // 2,097,152 dead after proj gemm
  float* h     = ws;                 // 8,388,608 reuse (all above dead)
  float* hc    = ws + 8388608;       // 8,388,608
  float* tmp   = ws + 16777216;      // 2,097,152
  float* out1  = ws + 18874368;      // 2,097,152  -> total 20,971,520 floats = 83.9 MB

  dim3 blk(256);
  // 1. cl (row-major) = xf @ cw^T   [MFMA]
  gemm_cl_mfma<<<dim3(256, 3), blk, 0, stream>>>(x, mem, cw, clr);
  // 2. cosine clip factors
  cos_stats<<<dim3(128, 2), blk, 0, stream>>>(z, clr, p1, p2, cosz, coscl);
  // 3. cluster_x_z + assigned   [MFMA, K=320]
  gemm_csz_mfma<<<dim3(256, 3), blk, 0, stream>>>(clr, z, coscl, cosz, tdt2, tdt1, csz, asg);
  // 4. softmax stats
  softmax_stats<<<dim3(1200), blk, 0, stream>>>(csz, mr, lr_);
  // 5. cen (split-K x16)
  gemm_cen<<<dim3(8, 8, 16), blk, 0, stream>>>(csz, x, mem, mr, part);
  reduce_cen<<<dim3(1200), blk, 0, stream>>>(part, lr_, cen);
  // 6. gate + LN -> C_in
  gate_ln<<<dim3(300), blk, 0, stream>>>(cen, sal, sbe, nw, nb, cin);
  // 7. q/k/v
  gemm_mfma<<<dim3(64, 4), blk, 0, stream>>>(x, q_w, q_b, q, 8192, 256, 256, 0.17677669529663687f);
  gemm_nt<<<dim3(3, 4), blk, 0, stream>>>(cin, k_w, k_b, ksb, 300, 256, 256, 1.f);
  gemm_nt<<<dim3(3, 4), blk, 0, stream>>>(cin, v_w, v_b, vsb, 300, 256, 256, 1.f);
  // 8. attention [MFMA]
  attn_mfma<<<dim3(512), blk, 0, stream>>>(q, ksb, vsb, o);
  // 9. proj + LN + residual
  gemm_mfma<<<dim3(64, 4), blk, 0, stream>>>(o, pj_w, pj_b, tmp, 8192, 256, 256, 1.f);
  ln_res<<<dim3(8192), blk, 0, stream>>>(tmp, x, nw, nb, out1);
  // 10. MLP
  gemm_mfma<<<dim3(64, 16), blk, 0, stream>>>(out1, f1w, f1b, h, 8192, 1024, 256, 1.f);
  conv_gelu<<<dim3(32768), blk, 0, stream>>>(h, dww, dwb, hc);
  gemm_mfma<<<dim3(64, 4), blk, 0, stream>>>(hc, f2w, f2b_, tmp, 8192, 256, 1024, 1.f);
  ln_res<<<dim3(8192), blk, 0, stream>>>(tmp, out1, nw, nb, out);
}

// Round 5
// 484.635 us; speedup vs baseline: 1.7531x; 1.0962x over previous
//
#include <hip/hip_runtime.h>
#include <math.h>

// Dims: B=2, N=4096, C=256, nc=150, T=4, TN=16384, heads=8, hd=32, hid=1024, H=W=64

typedef __attribute__((ext_vector_type(8))) short bf16x8;
typedef __attribute__((ext_vector_type(4))) float f32x4;

__device__ __forceinline__ short f2b(float f) {
  union { float f; unsigned int u; } c; c.f = f;
  unsigned int r = (c.u + 0x7fffu + ((c.u >> 16) & 1u)) >> 16;
  return (short)r;
}

// ---------------- block reduction helpers (blockDim.x == 256) ----------------
__device__ __forceinline__ float bred_sum(float v, float* red) {
  int tid = threadIdx.x;
  red[tid] = v; __syncthreads();
  #pragma unroll
  for (int s = 128; s > 0; s >>= 1) {
    if (tid < s) red[tid] += red[tid + s];
    __syncthreads();
  }
  float r = red[0]; __syncthreads();
  return r;
}
__device__ __forceinline__ float bred_max(float v, float* red) {
  int tid = threadIdx.x;
  red[tid] = v; __syncthreads();
  #pragma unroll
  for (int s = 128; s > 0; s >>= 1) {
    if (tid < s) red[tid] = fmaxf(red[tid], red[tid + s]);
    __syncthreads();
  }
  float r = red[0]; __syncthreads();
  return r;
}

// ---------------- bf16 MFMA GEMM: out[m][n] = alpha*(sum_k A[m,k]*W[n,k] + bias[n]) ----------------
__global__ __launch_bounds__(256) void gemm_mfma(
    const float* __restrict__ A, const float* __restrict__ W,
    const float* __restrict__ bias, float* __restrict__ out,
    int M, int N, int K, float alpha)
{
  __shared__ __align__(16) short As[128 * 72];
  __shared__ __align__(16) short Bs[64 * 72];
  const int tid = threadIdx.x;
  const int m0 = blockIdx.x * 128;
  const int n0 = blockIdx.y * 64;
  const int wave = tid >> 6;
  const int lane = tid & 63;
  const int wm = wave & 1, wn = wave >> 1;
  const int t16 = lane & 15;
  const int k8 = (lane >> 4) * 8;

  f32x4 acc[4][2];
  #pragma unroll
  for (int i = 0; i < 4; ++i)
    #pragma unroll
    for (int j = 0; j < 2; ++j)
      acc[i][j] = (f32x4){0.f, 0.f, 0.f, 0.f};

  const int sr = tid >> 2;
  const int sk = (tid & 3) * 16;

  for (int k0 = 0; k0 < K; k0 += 64) {
    #pragma unroll
    for (int p = 0; p < 2; ++p) {
      const int row = sr + p * 64;
      const float* ap = &A[(size_t)(m0 + row) * K + k0 + sk];
      float4 v0 = *(const float4*)&ap[0];
      float4 v1 = *(const float4*)&ap[4];
      float4 v2 = *(const float4*)&ap[8];
      float4 v3 = *(const float4*)&ap[12];
      bf16x8 w0, w1;
      w0[0] = f2b(v0.x); w0[1] = f2b(v0.y); w0[2] = f2b(v0.z); w0[3] = f2b(v0.w);
      w0[4] = f2b(v1.x); w0[5] = f2b(v1.y); w0[6] = f2b(v1.z); w0[7] = f2b(v1.w);
      w1[0] = f2b(v2.x); w1[1] = f2b(v2.y); w1[2] = f2b(v2.z); w1[3] = f2b(v2.w);
      w1[4] = f2b(v3.x); w1[5] = f2b(v3.y); w1[6] = f2b(v3.z); w1[7] = f2b(v3.w);
      *(bf16x8*)&As[row * 72 + sk] = w0;
      *(bf16x8*)&As[row * 72 + sk + 8] = w1;
    }
    {
      const float* wp = &W[(size_t)(n0 + sr) * K + k0 + sk];
      float4 v0 = *(const float4*)&wp[0];
      float4 v1 = *(const float4*)&wp[4];
      float4 v2 = *(const float4*)&wp[8];
      float4 v3 = *(const float4*)&wp[12];
      bf16x8 w0, w1;
      w0[0] = f2b(v0.x); w0[1] = f2b(v0.y); w0[2] = f2b(v0.z); w0[3] = f2b(v0.w);
      w0[4] = f2b(v1.x); w0[5] = f2b(v1.y); w0[6] = f2b(v1.z); w0[7] = f2b(v1.w);
      w1[0] = f2b(v2.x); w1[1] = f2b(v2.y); w1[2] = f2b(v2.z); w1[3] = f2b(v2.w);
      w1[4] = f2b(v3.x); w1[5] = f2b(v3.y); w1[6] = f2b(v3.z); w1[7] = f2b(v3.w);
      *(bf16x8*)&Bs[sr * 72 + sk] = w0;
      *(bf16x8*)&Bs[sr * 72 + sk + 8] = w1;
    }
    __syncthreads();
    #pragma unroll
    for (int ks = 0; ks < 2; ++ks) {
      const int kofs = ks * 32 + k8;
      bf16x8 af0 = *(const bf16x8*)&As[(wm * 64 +  0 + t16) * 72 + kofs];
      bf16x8 af1 = *(const bf16x8*)&As[(wm * 64 + 16 + t16) * 72 + kofs];
      bf16x8 af2 = *(const bf16x8*)&As[(wm * 64 + 32 + t16) * 72 + kofs];
      bf16x8 af3 = *(const bf16x8*)&As[(wm * 64 + 48 + t16) * 72 + kofs];
      bf16x8 bf0 = *(const bf16x8*)&Bs[(wn * 32 +  0 + t16) * 72 + kofs];
      bf16x8 bf1 = *(const bf16x8*)&Bs[(wn * 32 + 16 + t16) * 72 + kofs];
      acc[0][0] = __builtin_amdgcn_mfma_f32_16x16x32_bf16(af0, bf0, acc[0][0], 0, 0, 0);
      acc[1][0] = __builtin_amdgcn_mfma_f32_16x16x32_bf16(af1, bf0, acc[1][0], 0, 0, 0);
      acc[2][0] = __builtin_amdgcn_mfma_f32_16x16x32_bf16(af2, bf0, acc[2][0], 0, 0, 0);
      acc[3][0] = __builtin_amdgcn_mfma_f32_16x16x32_bf16(af3, bf0, acc[3][0], 0, 0, 0);
      acc[0][1] = __builtin_amdgcn_mfma_f32_16x16x32_bf16(af0, bf1, acc[0][1], 0, 0, 0);
      acc[1][1] = __builtin_amdgcn_mfma_f32_16x16x32_bf16(af1, bf1, acc[1][1], 0, 0, 0);
      acc[2][1] = __builtin_amdgcn_mfma_f32_16x16x32_bf16(af2, bf1, acc[2][1], 0, 0, 0);
      acc[3][1] = __builtin_amdgcn_mfma_f32_16x16x32_bf16(af3, bf1, acc[3][1], 0, 0, 0);
    }
    __syncthreads();
  }
  const int r4 = (lane >> 4) * 4;
  #pragma unroll
  for (int ni = 0; ni < 2; ++ni) {
    const int gcol = n0 + wn * 32 + ni * 16 + t16;
    const float bb = bias[gcol];
    #pragma unroll
    for (int mi = 0; mi < 4; ++mi) {
      #pragma unroll
      for (int r = 0; r < 4; ++r) {
        const int gm = m0 + wm * 64 + mi * 16 + r4 + r;
        out[(size_t)gm * N + gcol] = alpha * (acc[mi][ni][r] + bb);
      }
    }
  }
}

// ---------------- MFMA cl: clr[b*16384 + ti*4096 + n][kc(160 pad)] = xf @ cw^T ----------------
__global__ __launch_bounds__(256) void gemm_cl_mfma(
    const float* __restrict__ x, const float* __restrict__ mem,
    const float* __restrict__ cw, float* __restrict__ clr)
{
  __shared__ __align__(16) short As[128 * 72];
  __shared__ __align__(16) short Bs[64 * 72];
  const int tid = threadIdx.x;
  const int m0 = blockIdx.x * 128;
  const int n0 = blockIdx.y * 64;
  const int bt = m0 >> 12;
  const int b = bt >> 2, ti = bt & 3;
  const int nbase = m0 & 4095;
  const float* Abase = (ti < 3) ? (mem + (size_t)(b * 3 + ti) * 4096 * 256)
                                : (x + (size_t)b * 4096 * 256);
  const int wave = tid >> 6, lane = tid & 63;
  const int wm = wave & 1, wn = wave >> 1;
  const int t16 = lane & 15;
  const int k8 = (lane >> 4) * 8;

  f32x4 acc[4][2];
  #pragma unroll
  for (int i = 0; i < 4; ++i)
    #pragma unroll
    for (int j = 0; j < 2; ++j)
      acc[i][j] = (f32x4){0.f, 0.f, 0.f, 0.f};

  const int sr = tid >> 2;
  const int sk = (tid & 3) * 16;

  for (int k0 = 0; k0 < 256; k0 += 64) {
    #pragma unroll
    for (int p = 0; p < 2; ++p) {
      const int row = sr + p * 64;
      const float* ap = &Abase[(size_t)(nbase + row) * 256 + k0 + sk];
      float4 v0 = *(const float4*)&ap[0];
      float4 v1 = *(const float4*)&ap[4];
      float4 v2 = *(const float4*)&ap[8];
      float4 v3 = *(const float4*)&ap[12];
      bf16x8 w0, w1;
      w0[0] = f2b(v0.x); w0[1] = f2b(v0.y); w0[2] = f2b(v0.z); w0[3] = f2b(v0.w);
      w0[4] = f2b(v1.x); w0[5] = f2b(v1.y); w0[6] = f2b(v1.z); w0[7] = f2b(v1.w);
      w1[0] = f2b(v2.x); w1[1] = f2b(v2.y); w1[2] = f2b(v2.z); w1[3] = f2b(v2.w);
      w1[4] = f2b(v3.x); w1[5] = f2b(v3.y); w1[6] = f2b(v3.z); w1[7] = f2b(v3.w);
      *(bf16x8*)&As[row * 72 + sk] = w0;
      *(bf16x8*)&As[row * 72 + sk + 8] = w1;
    }
    {
      const int gn = n0 + sr;
      bf16x8 w0 = {0,0,0,0,0,0,0,0}, w1 = {0,0,0,0,0,0,0,0};
      if (gn < 150) {
        const float* wp = &cw[(size_t)gn * 256 + k0 + sk];
        float4 v0 = *(const float4*)&wp[0];
        float4 v1 = *(const float4*)&wp[4];
        float4 v2 = *(const float4*)&wp[8];
        float4 v3 = *(const float4*)&wp[12];
        w0[0] = f2b(v0.x); w0[1] = f2b(v0.y); w0[2] = f2b(v0.z); w0[3] = f2b(v0.w);
        w0[4] = f2b(v1.x); w0[5] = f2b(v1.y); w0[6] = f2b(v1.z); w0[7] = f2b(v1.w);
        w1[0] = f2b(v2.x); w1[1] = f2b(v2.y); w1[2] = f2b(v2.z); w1[3] = f2b(v2.w);
        w1[4] = f2b(v3.x); w1[5] = f2b(v3.y); w1[6] = f2b(v3.z); w1[7] = f2b(v3.w);
      }
      *(bf16x8*)&Bs[sr * 72 + sk] = w0;
      *(bf16x8*)&Bs[sr * 72 + sk + 8] = w1;
    }
    __syncthreads();
    #pragma unroll
    for (int ks = 0; ks < 2; ++ks) {
      const int kofs = ks * 32 + k8;
      bf16x8 af0 = *(const bf16x8*)&As[(wm * 64 +  0 + t16) * 72 + kofs];
      bf16x8 af1 = *(const bf16x8*)&As[(wm * 64 + 16 + t16) * 72 + kofs];
      bf16x8 af2 = *(const bf16x8*)&As[(wm * 64 + 32 + t16) * 72 + kofs];
      bf16x8 af3 = *(const bf16x8*)&As[(wm * 64 + 48 + t16) * 72 + kofs];
      bf16x8 bf0 = *(const bf16x8*)&Bs[(wn * 32 +  0 + t16) * 72 + kofs];
      bf16x8 bf1 = *(const bf16x8*)&Bs[(wn * 32 + 16 + t16) * 72 + kofs];
      acc[0][0] = __builtin_amdgcn_mfma_f32_16x16x32_bf16(af0, bf0, acc[0][0], 0, 0, 0);
      acc[1][0] = __builtin_amdgcn_mfma_f32_16x16x32_bf16(af1, bf0, acc[1][0], 0, 0, 0);
      acc[2][0] = __builtin_amdgcn_mfma_f32_16x16x32_bf16(af2, bf0, acc[2][0], 0, 0, 0);
      acc[3][0] = __builtin_amdgcn_mfma_f32_16x16x32_bf16(af3, bf0, acc[3][0], 0, 0, 0);
      acc[0][1] = __builtin_amdgcn_mfma_f32_16x16x32_bf16(af0, bf1, acc[0][1], 0, 0, 0);
      acc[1][1] = __builtin_amdgcn_mfma_f32_16x16x32_bf16(af1, bf1, acc[1][1], 0, 0, 0);
      acc[2][1] = __builtin_amdgcn_mfma_f32_16x16x32_bf16(af2, bf1, acc[2][1], 0, 0, 0);
      acc[3][1] = __builtin_amdgcn_mfma_f32_16x16x32_bf16(af3, bf1, acc[3][1], 0, 0, 0);
    }
    __syncthreads();
  }
  const int r4 = (lane >> 4) * 4;
  const size_t rowbase = (size_t)b * 16384 + ti * 4096 + nbase;
  #pragma unroll
  for (int ni = 0; ni < 2; ++ni) {
    const int col = n0 + wn * 32 + ni * 16 + t16;
    if (col >= 160) continue;
    #pragma unroll
    for (int mi = 0; mi < 4; ++mi) {
      const int mrow = wm * 64 + mi * 16 + r4;
      #pragma unroll
      for (int r = 0; r < 4; ++r)
        clr[(rowbase + mrow + r) * 160 + col] = acc[mi][ni][r];
    }
  }
}

// ---------------- cosine clip factors (y=0: z strided; y=1: clr row-major) ----------------
__global__ __launch_bounds__(256) void cos_stats(
    const float* __restrict__ z, const float* __restrict__ clr,
    const float* __restrict__ p1, const float* __restrict__ p2,
    float* __restrict__ cosz, float* __restrict__ coscl)
{
  int which = blockIdx.y;
  int gid = blockIdx.x * 256 + threadIdx.x;
  int b = gid >> 14, m = gid & 16383;
  float d = 0, s = 0, pn = 0;
  if (which) {
    const float* sp = clr + ((size_t)b * 16384 + m) * 160;
    for (int k = 0; k < 148; k += 4) {
      float4 v = *(const float4*)&sp[k];
      float4 a = *(const float4*)&p2[k];
      d += v.x * a.x + v.y * a.y + v.z * a.z + v.w * a.w;
      s += v.x * v.x + v.y * v.y + v.z * v.z + v.w * v.w;
      pn += a.x * a.x + a.y * a.y + a.z * a.z + a.w * a.w;
    }
    for (int k = 148; k < 150; ++k) {
      float v = sp[k], a = p2[k];
      d += v * a; s += v * v; pn += a * a;
    }
    float c = d / (fmaxf(sqrtf(s), 1e-12f) * fmaxf(sqrtf(pn), 1e-12f));
    coscl[gid] = fminf(fmaxf(c, 0.f), 1.f);
  } else {
    const float* sp = z + (size_t)b * 150 * 16384 + m;
    for (int k = 0; k < 150; ++k) {
      float v = sp[(size_t)k * 16384];
      float a = p1[k];
      d += v * a; s += v * v; pn += a * a;
    }
    float c = d / (fmaxf(sqrtf(s), 1e-12f) * fmaxf(sqrtf(pn), 1e-12f));
    cosz[gid] = fminf(fmaxf(c, 0.f), 1.f);
  }
}

// ---------------- MFMA csz: csz[b][kc][m] = 0.5*(coscl*cl@tdt2 + cosz*z@tdt1), + asg ----------------
__global__ __launch_bounds__(256) void gemm_csz_mfma(
    const float* __restrict__ clr, const float* __restrict__ z,
    const float* __restrict__ coscl, const float* __restrict__ cosz,
    const float* __restrict__ tdt2, const float* __restrict__ tdt1,
    float* __restrict__ csz, float* __restrict__ asg)
{
  __shared__ __align__(16) short As[128 * 40];
  __shared__ __align__(16) short Bs[64 * 40];
  const int tid = threadIdx.x;
  const int m0 = blockIdx.x * 128;
  const int b = m0 >> 14;
  const int mm = m0 & 16383;
  const int n0 = blockIdx.y * 64;
  const int wave = tid >> 6, lane = tid & 63;
  const int wm = wave & 1, wn = wave >> 1;
  const int t16 = lane & 15;
  const int k8 = (lane >> 4) * 8;

  f32x4 acc[4][2];
  #pragma unroll
  for (int i = 0; i < 4; ++i)
    #pragma unroll
    for (int j = 0; j < 2; ++j)
      acc[i][j] = (f32x4){0.f, 0.f, 0.f, 0.f};

  for (int c = 0; c < 10; ++c) {
    if (c < 5) {
      const int row = tid >> 1;
      const int sk0 = (tid & 1) * 16;
      const float* ap = &clr[((size_t)b * 16384 + mm + row) * 160 + c * 32 + sk0];
      const float cs = coscl[(size_t)b * 16384 + mm + row];
      float4 v0 = *(const float4*)&ap[0];
      float4 v1 = *(const float4*)&ap[4];
      float4 v2 = *(const float4*)&ap[8];
      float4 v3 = *(const float4*)&ap[12];
      bf16x8 w0, w1;
      w0[0] = f2b(v0.x * cs); w0[1] = f2b(v0.y * cs); w0[2] = f2b(v0.z * cs); w0[3] = f2b(v0.w * cs);
      w0[4] = f2b(v1.x * cs); w0[5] = f2b(v1.y * cs); w0[6] = f2b(v1.z * cs); w0[7] = f2b(v1.w * cs);
      w1[0] = f2b(v2.x * cs); w1[1] = f2b(v2.y * cs); w1[2] = f2b(v2.z * cs); w1[3] = f2b(v2.w * cs);
      w1[4] = f2b(v3.x * cs); w1[5] = f2b(v3.y * cs); w1[6] = f2b(v3.z * cs); w1[7] = f2b(v3.w * cs);
      *(bf16x8*)&As[row * 40 + sk0] = w0;
      *(bf16x8*)&As[row * 40 + sk0 + 8] = w1;
    } else {
      const int kgl = tid >> 3;
      const int mb = (tid & 7) * 4;
      const int kg = (c - 5) * 32 + kgl;
      #pragma unroll
      for (int p = 0; p < 4; ++p) {
        const int m = mb + p * 32;
        float4 v = make_float4(0.f, 0.f, 0.f, 0.f);
        if (kg < 150) {
          v = *(const float4*)&z[((size_t)b * 150 + kg) * 16384 + mm + m];
          float4 cz = *(const float4*)&cosz[(size_t)b * 16384 + mm + m];
          v.x *= cz.x; v.y *= cz.y; v.z *= cz.z; v.w *= cz.w;
        }
        As[(m + 0) * 40 + kgl] = f2b(v.x);
        As[(m + 1) * 40 + kgl] = f2b(v.y);
        As[(m + 2) * 40 + kgl] = f2b(v.z);
        As[(m + 3) * 40 + kgl] = f2b(v.w);
      }
    }
    {
      const int kc = tid & 63;
      const int gn = n0 + kc;
      #pragma unroll
      for (int p = 0; p < 8; ++p) {
        const int kgl = (tid >> 6) + p * 4;
        const int kg = c * 32 + kgl;
        float t = 0.f;
        if (gn < 150) {
          if (kg < 150) t = tdt2[kg * 150 + gn];
          else if (kg >= 160 && kg < 310) t = tdt1[(kg - 160) * 150 + gn];
        }
        Bs[kc * 40 + kgl] = f2b(t);
      }
    }
    __syncthreads();
    {
      bf16x8 af0 = *(const bf16x8*)&As[(wm * 64 +  0 + t16) * 40 + k8];
      bf16x8 af1 = *(const bf16x8*)&As[(wm * 64 + 16 + t16) * 40 + k8];
      bf16x8 af2 = *(const bf16x8*)&As[(wm * 64 + 32 + t16) * 40 + k8];
      bf16x8 af3 = *(const bf16x8*)&As[(wm * 64 + 48 + t16) * 40 + k8];
      bf16x8 bf0 = *(const bf16x8*)&Bs[(wn * 32 +  0 + t16) * 40 + k8];
      bf16x8 bf1 = *(const bf16x8*)&Bs[(wn * 32 + 16 + t16) * 40 + k8];
      acc[0][0] = __builtin_amdgcn_mfma_f32_16x16x32_bf16(af0, bf0, acc[0][0], 0, 0, 0);
      acc[1][0] = __builtin_amdgcn_mfma_f32_16x16x32_bf16(af1, bf0, acc[1][0], 0, 0, 0);
      acc[2][0] = __builtin_amdgcn_mfma_f32_16x16x32_bf16(af2, bf0, acc[2][0], 0, 0, 0);
      acc[3][0] = __builtin_amdgcn_mfma_f32_16x16x32_bf16(af3, bf0, acc[3][0], 0, 0, 0);
      acc[0][1] = __builtin_amdgcn_mfma_f32_16x16x32_bf16(af0, bf1, acc[0][1], 0, 0, 0);
      acc[1][1] = __builtin_amdgcn_mfma_f32_16x16x32_bf16(af1, bf1, acc[1][1], 0, 0, 0);
      acc[2][1] = __builtin_amdgcn_mfma_f32_16x16x32_bf16(af2, bf1, acc[2][1], 0, 0, 0);
      acc[3][1] = __builtin_amdgcn_mfma_f32_16x16x32_bf16(af3, bf1, acc[3][1], 0, 0, 0);
    }
    __syncthreads();
  }
  const int r4 = (lane >> 4) * 4;
  const int ti = mm >> 12;
  const int nn = mm & 4095;
  #pragma unroll
  for (int ni = 0; ni < 2; ++ni) {
    const int kc = n0 + wn * 32 + ni * 16 + t16;
    if (kc >= 150) continue;
    #pragma unroll
    for (int mi = 0; mi < 4; ++mi) {
      const int mrow = wm * 64 + mi * 16 + r4;
      float4 r;
      r.x = 0.5f * acc[mi][ni][0];
      r.y = 0.5f * acc[mi][ni][1];
      r.z = 0.5f * acc[mi][ni][2];
      r.w = 0.5f * acc[mi][ni][3];
      *(float4*)&csz[((size_t)b * 150 + kc) * 16384 + mm + mrow] = r;
      *(float4*)&asg[(((size_t)b * 4 + ti) * 150 + kc) * 4096 + nn + mrow] = r;
    }
  }
}

// ---------------- softmax stats per (b,ti,k) row of 4096 ----------------
__global__ __launch_bounds__(256) void softmax_stats(
    const float* __restrict__ csz, float* __restrict__ mr, float* __restrict__ lr_)
{
  __shared__ float red[256];
  int row = blockIdx.x;
  int bt = row / 150, k = row % 150;
  int b = bt >> 2, ti = bt & 3;
  const float* p = csz + ((size_t)b * 150 + k) * 16384 + ti * 4096;
  float v[16];
  float mx = -1e30f;
  #pragma unroll
  for (int i = 0; i < 16; ++i) { v[i] = p[i * 256 + threadIdx.x]; mx = fmaxf(mx, v[i]); }
  mx = bred_max(mx, red);
  float s = 0.f;
  #pragma unroll
  for (int i = 0; i < 16; ++i) s += expf(v[i] - mx);
  s = bred_sum(s, red);
  if (threadIdx.x == 0) { mr[row] = mx; lr_[row] = s; }
}

// ---------------- cen partials ----------------
__global__ __launch_bounds__(256) void gemm_cen(
    const float* __restrict__ csz, const float* __restrict__ x, const float* __restrict__ mem,
    const float* __restrict__ mr, float* __restrict__ part)
{
  __shared__ __align__(16) float As[160][36];
  __shared__ __align__(16) float Bs[32][36];
  const int tid = threadIdx.x;
  const int c0 = blockIdx.x * 32;
  const int bt = blockIdx.y;
  const int sp = blockIdx.z;
  const int b = bt >> 2, ti = bt & 3;
  const float* xf = (ti < 3) ? (mem + (size_t)(b * 3 + ti) * 4096 * 256)
                             : (x + (size_t)b * 4096 * 256);
  const float* crow = csz + (size_t)b * 150 * 16384 + ti * 4096;
  const int tmr = tid >> 3;
  const int tnc = tid & 7;
  const int ann = tnc * 4;
  float acc[5][4];
  #pragma unroll
  for (int i = 0; i < 5; ++i)
    #pragma unroll
    for (int j = 0; j < 4; ++j) acc[i][j] = 0.f;

  for (int n0 = sp * 256; n0 < sp * 256 + 256; n0 += 32) {
    #pragma unroll
    for (int p = 0; p < 5; ++p) {
      int kcl = tmr + p * 32;
      float4 v = make_float4(0.f, 0.f, 0.f, 0.f);
      if (kcl < 150) {
        v = *(const float4*)&crow[(size_t)kcl * 16384 + n0 + ann];
        float mrv = mr[bt * 150 + kcl];
        v.x = expf(v.x - mrv); v.y = expf(v.y - mrv);
        v.z = expf(v.z - mrv); v.w = expf(v.w - mrv);
      }
      *(float4*)&As[kcl][ann] = v;
    }
    {
      int nr = tid >> 3;
      int cc = (tid & 7) * 4;
      *(float4*)&Bs[nr][cc] = *(const float4*)&xf[(size_t)(n0 + nr) * 256 + c0 + cc];
    }
    __syncthreads();
    #pragma unroll
    for (int kk = 0; kk < 32; kk += 4) {
      float4 b0 = *(const float4*)&Bs[kk + 0][tnc * 4];
      float4 b1 = *(const float4*)&Bs[kk + 1][tnc * 4];
      float4 b2 = *(const float4*)&Bs[kk + 2][tnc * 4];
      float4 b3 = *(const float4*)&Bs[kk + 3][tnc * 4];
      #pragma unroll
      for (int i = 0; i < 5; ++i) {
        float4 a = *(const float4*)&As[tmr * 5 + i][kk];
        acc[i][0] = fmaf(a.x, b0.x, acc[i][0]);
        acc[i][1] = fmaf(a.x, b0.y, acc[i][1]);
        acc[i][2] = fmaf(a.x, b0.z, acc[i][2]);
        acc[i][3] = fmaf(a.x, b0.w, acc[i][3]);
        acc[i][0] = fmaf(a.y, b1.x, acc[i][0]);
        acc[i][1] = fmaf(a.y, b1.y, acc[i][1]);
        acc[i][2] = fmaf(a.y, b1.z, acc[i][2]);
        acc[i][3] = fmaf(a.y, b1.w, acc[i][3]);
        acc[i][0] = fmaf(a.z, b2.x, acc[i][0]);
        acc[i][1] = fmaf(a.z, b2.y, acc[i][1]);
        acc[i][2] = fmaf(a.z, b2.z, acc[i][2]);
        acc[i][3] = fmaf(a.z, b2.w, acc[i][3]);
        acc[i][0] = fmaf(a.w, b3.x, acc[i][0]);
        acc[i][1] = fmaf(a.w, b3.y, acc[i][1]);
        acc[i][2] = fmaf(a.w, b3.z, acc[i][2]);
        acc[i][3] = fmaf(a.w, b3.w, acc[i][3]);
      }
    }
    __syncthreads();
  }
  #pragma unroll
  for (int i = 0; i < 5; ++i) {
    int kcl = tmr * 5 + i;
    if (kcl >= 150) continue;
    float4 r = make_float4(acc[i][0], acc[i][1], acc[i][2], acc[i][3]);
    *(float4*)&part[(((size_t)sp * 8 + bt) * 150 + kcl) * 256 + c0 + tnc * 4] = r;
  }
}

__global__ __launch_bounds__(256) void reduce_cen(
    const float* __restrict__ part, const float* __restrict__ lr_, float* __restrict__ cen)
{
  int row = blockIdx.x;
  int c = threadIdx.x;
  float s = 0.f;
  #pragma unroll
  for (int sp = 0; sp < 16; ++sp)
    s += part[((size_t)sp * 1200 + row) * 256 + c];
  cen[(size_t)row * 256 + c] = s / lr_[row];
}

// ---------------- similarity gate + LN -> C_in ----------------
__global__ __launch_bounds__(256) void gate_ln(
    const float* __restrict__ cen, const float* __restrict__ alpha_, const float* __restrict__ beta_,
    const float* __restrict__ nw, const float* __restrict__ nb, float* __restrict__ cin)
{
  __shared__ float red[256];
  int bk = blockIdx.x;
  int b = bk / 150, k = bk % 150;
  int c = threadIdx.x;
  const float* base = cen + ((size_t)b * 4 * 150) * 256;
  float lc  = base[((size_t)3 * 150 + k) * 256 + c];
  float p0  = base[((size_t)0 * 150 + k) * 256 + c];
  float p1v = base[((size_t)1 * 150 + k) * 256 + c];
  float p2v = base[((size_t)2 * 150 + k) * 256 + c];
  float nl = bred_sum(lc * lc, red);
  float q0 = bred_sum(p0 * p0, red);
  float q1 = bred_sum(p1v * p1v, red);
  float q2 = bred_sum(p2v * p2v, red);
  float d0 = bred_sum(lc * p0, red);
  float d1 = bred_sum(lc * p1v, red);
  float d2 = bred_sum(lc * p2v, red);
  float al = alpha_[0], be = beta_[0];
  float snl = sqrtf(nl);
  float g0 = 1.f / (1.f + expf(-(be + al * (d0 / fmaxf(snl * sqrtf(q0), 1e-8f)))));
  float g1 = 1.f / (1.f + expf(-(be + al * (d1 / fmaxf(snl * sqrtf(q1), 1e-8f)))));
  float g2 = 1.f / (1.f + expf(-(be + al * (d2 / fmaxf(snl * sqrtf(q2), 1e-8f)))));
  float ci = lc + g0 * p0 + g1 * p1v + g2 * p2v;
  float mu = bred_sum(ci, red) * (1.f / 256.f);
  float df = ci - mu;
  float var = bred_sum(df * df, red) * (1.f / 256.f);
  cin[(size_t)bk * 256 + c] = df * rsqrtf(var + 1e-5f) * nw[c] + nb[c];
}

// ---------------- generic fp32 GEMM (small shapes: k/v) ----------------
__global__ __launch_bounds__(256) void gemm_nt(
    const float* __restrict__ A, const float* __restrict__ W,
    const float* __restrict__ bias, float* __restrict__ out,
    int M, int N, int K, float alpha)
{
  __shared__ __align__(16) float As[16][132];
  __shared__ __align__(16) float Ws[16][68];
  const int tid = threadIdx.x;
  const int m0 = blockIdx.x * 128;
  const int n0 = blockIdx.y * 64;
  const int tm = tid & 15;
  const int tn = tid >> 4;
  float acc[8][4];
  #pragma unroll
  for (int i = 0; i < 8; ++i)
    #pragma unroll
    for (int j = 0; j < 4; ++j) acc[i][j] = 0.f;

  const int lr = tid >> 2;
  const int lk = (tid & 3) * 4;

  for (int k0 = 0; k0 < K; k0 += 16) {
    #pragma unroll
    for (int p = 0; p < 2; ++p) {
      int r = lr + p * 64;
      int gm = m0 + r;
      float4 v = make_float4(0.f, 0.f, 0.f, 0.f);
      if (gm < M) v = *(const float4*)&A[(size_t)gm * K + k0 + lk];
      As[lk + 0][r] = v.x; As[lk + 1][r] = v.y; As[lk + 2][r] = v.z; As[lk + 3][r] = v.w;
    }
    {
      float4 v = *(const float4*)&W[(size_t)(n0 + lr) * K + k0 + lk];
      Ws[lk + 0][lr] = v.x; Ws[lk + 1][lr] = v.y; Ws[lk + 2][lr] = v.z; Ws[lk + 3][lr] = v.w;
    }
    __syncthreads();
    #pragma unroll
    for (int kk = 0; kk < 16; ++kk) {
      float4 a0 = *(const float4*)&As[kk][tm * 8];
      float4 a1 = *(const float4*)&As[kk][tm * 8 + 4];
      float4 w0 = *(const float4*)&Ws[kk][tn * 4];
      float av[8] = {a0.x, a0.y, a0.z, a0.w, a1.x, a1.y, a1.z, a1.w};
      float wv[4] = {w0.x, w0.y, w0.z, w0.w};
      #pragma unroll
      for (int i = 0; i < 8; ++i)
        #pragma unroll
        for (int j = 0; j < 4; ++j)
          acc[i][j] = fmaf(av[i], wv[j], acc[i][j]);
    }
    __syncthreads();
  }
  float4 bv = *(const float4*)&bias[n0 + tn * 4];
  float bb[4] = {bv.x, bv.y, bv.z, bv.w};
  #pragma unroll
  for (int i = 0; i < 8; ++i) {
    int gm = m0 + tm * 8 + i;
    if (gm >= M) continue;
    float4 r;
    r.x = alpha * (acc[i][0] + bb[0]);
    r.y = alpha * (acc[i][1] + bb[1]);
    r.z = alpha * (acc[i][2] + bb[2]);
    r.w = alpha * (acc[i][3] + bb[3]);
    *(float4*)&out[(size_t)gm * N + n0 + tn * 4] = r;
  }
}

// ---------------- MFMA attention: 128 Q-rows/block, per (b,h) ----------------
__global__ __launch_bounds__(256) void attn_mfma(
    const float* __restrict__ q, const float* __restrict__ ks, const float* __restrict__ vs,
    float* __restrict__ o)
{
  __shared__ __align__(16) short Ps[128 * 168];
  __shared__ __align__(16) short VT[32 * 168];
  __shared__ float lrow[128];
  const int tid = threadIdx.x;
  const int bid = blockIdx.x;
  const int ntile = bid & 31;
  const int bh = bid >> 5;
  const int b = bh >> 3, h = bh & 7;
  const int n0 = ntile * 128;
  const int wave = tid >> 6, lane = tid & 63;
  const int t16 = lane & 15, quad = lane >> 4;
  const int k8 = quad * 8;
  const int wr = wave * 32;

  for (int i = tid; i < 5120; i += 256) {
    int d = i / 160, kc = i - d * 160;
    VT[d * 168 + kc] = (kc < 150) ? f2b(vs[((size_t)b * 150 + kc) * 256 + h * 32 + d]) : (short)0;
  }

  bf16x8 aQ[2];
  #pragma unroll
  for (int mt = 0; mt < 2; ++mt) {
    const float* qp = &q[((size_t)b * 4096 + n0 + wr + mt * 16 + t16) * 256 + h * 32 + k8];
    float4 v0 = *(const float4*)&qp[0];
    float4 v1 = *(const float4*)&qp[4];
    bf16x8 w;
    w[0] = f2b(v0.x); w[1] = f2b(v0.y); w[2] = f2b(v0.z); w[3] = f2b(v0.w);
    w[4] = f2b(v1.x); w[5] = f2b(v1.y); w[6] = f2b(v1.z); w[7] = f2b(v1.w);
    aQ[mt] = w;
  }

  f32x4 s[2][10];
  #pragma unroll
  for (int ct = 0; ct < 10; ++ct) {
    const int c = ct * 16 + t16;
    bf16x8 bK = {0, 0, 0, 0, 0, 0, 0, 0};
    if (c < 150) {
      const float* kp = &ks[((size_t)b * 150 + c) * 256 + h * 32 + k8];
      float4 v0 = *(const float4*)&kp[0];
      float4 v1 = *(const float4*)&kp[4];
      bK[0] = f2b(v0.x); bK[1] = f2b(v0.y); bK[2] = f2b(v0.z); bK[3] = f2b(v0.w);
      bK[4] = f2b(v1.x); bK[5] = f2b(v1.y); bK[6] = f2b(v1.z); bK[7] = f2b(v1.w);
    }
    f32x4 zero = (f32x4){0.f, 0.f, 0.f, 0.f};
    s[0][ct] = __builtin_amdgcn_mfma_f32_16x16x32_bf16(aQ[0], bK, zero, 0, 0, 0);
    s[1][ct] = __builtin_amdgcn_mfma_f32_16x16x32_bf16(aQ[1], bK, zero, 0, 0, 0);
  }

  #pragma unroll
  for (int mt = 0; mt < 2; ++mt) {
    #pragma unroll
    for (int r = 0; r < 4; ++r) {
      float mx = -1e30f;
      #pragma unroll
      for (int ct = 0; ct < 10; ++ct) {
        float v = s[mt][ct][r];
        if (ct == 9 && t16 >= 6) { v = -1e30f; s[mt][ct][r] = v; }
        mx = fmaxf(mx, v);
      }
      mx = fmaxf(mx, __shfl_xor(mx, 1));
      mx = fmaxf(mx, __shfl_xor(mx, 2));
      mx = fmaxf(mx, __shfl_xor(mx, 4));
      mx = fmaxf(mx, __shfl_xor(mx, 8));
      float ls = 0.f;
      #pragma unroll
      for (int ct = 0; ct < 10; ++ct) {
        float e = expf(s[mt][ct][r] - mx);
        s[mt][ct][r] = e;
        ls += e;
      }
      ls += __shfl_xor(ls, 1);
      ls += __shfl_xor(ls, 2);
      ls += __shfl_xor(ls, 4);
      ls += __shfl_xor(ls, 8);
      if (t16 == 0) lrow[wr + mt * 16 + quad * 4 + r] = 1.f / ls;
      #pragma unroll
      for (int ct = 0; ct < 10; ++ct)
        Ps[(wr + mt * 16 + quad * 4 + r) * 168 + ct * 16 + t16] = f2b(s[mt][ct][r]);
    }
  }
  __syncthreads();

  f32x4 oacc[2][2];
  #pragma unroll
  for (int i = 0; i < 2; ++i)
    #pragma unroll
    for (int j = 0; j < 2; ++j)
      oacc[i][j] = (f32x4){0.f, 0.f, 0.f, 0.f};
  #pragma unroll
  for (int kstep = 0; kstep < 5; ++kstep) {
    bf16x8 bV0 = *(const bf16x8*)&VT[( 0 + t16) * 168 + kstep * 32 + k8];
    bf16x8 bV1 = *(const bf16x8*)&VT[(16 + t16) * 168 + kstep * 32 + k8];
    #pragma unroll
    for (int mt = 0; mt < 2; ++mt) {
      bf16x8 aP = *(const bf16x8*)&Ps[(wr + mt * 16 + t16) * 168 + kstep * 32 + k8];
      oacc[mt][0] = __builtin_amdgcn_mfma_f32_16x16x32_bf16(aP, bV0, oacc[mt][0], 0, 0, 0);
      oacc[mt][1] = __builtin_amdgcn_mfma_f32_16x16x32_bf16(aP, bV1, oacc[mt][1], 0, 0, 0);
    }
  }
  #pragma unroll
  for (int mt = 0; mt < 2; ++mt) {
    #pragma unroll
    for (int nt = 0; nt < 2; ++nt) {
      const int d = nt * 16 + t16;
      #pragma unroll
      for (int r = 0; r < 4; ++r) {
        const int row = wr + mt * 16 + quad * 4 + r;
        o[((size_t)b * 4096 + n0 + row) * 256 + h * 32 + d] = oacc[mt][nt][r] * lrow[row];
      }
    }
  }
}

// ---------------- dst = res + LN(src), wave-per-row (row=256 cols) ----------------
__global__ __launch_bounds__(256) void ln_res(
    const float* __restrict__ src, const float* __restrict__ res,
    const float* __restrict__ nw, const float* __restrict__ nb, float* __restrict__ dst)
{
  const int wave = threadIdx.x >> 6;
  const int lane = threadIdx.x & 63;
  const size_t row = (size_t)blockIdx.x * 4 + wave;
  const int c = lane * 4;
  float4 v = *(const float4*)&src[row * 256 + c];
  float s  = v.x + v.y + v.z + v.w;
  float s2 = v.x * v.x + v.y * v.y + v.z * v.z + v.w * v.w;
  #pragma unroll
  for (int off = 1; off < 64; off <<= 1) {
    s  += __shfl_xor(s, off);
    s2 += __shfl_xor(s2, off);
  }
  const float mu = s * (1.f / 256.f);
  const float var = s2 * (1.f / 256.f) - mu * mu;
  const float inv = rsqrtf(var + 1e-5f);
  float4 w = *(const float4*)&nw[c];
  float4 bb = *(const float4*)&nb[c];
  float4 rr = *(const float4*)&res[row * 256 + c];
  float4 d;
  d.x = rr.x + (v.x - mu) * inv * w.x + bb.x;
  d.y = rr.y + (v.y - mu) * inv * w.y + bb.y;
  d.z = rr.z + (v.z - mu) * inv * w.z + bb.z;
  d.w = rr.w + (v.w - mu) * inv * w.w + bb.w;
  *(float4*)&dst[row * 256 + c] = d;
}

// ---------------- transpose depthwise weights: wt[tap][1024] = w[ch][tap] ----------------
__global__ __launch_bounds__(256) void conv_wt(
    const float* __restrict__ w, float* __restrict__ wt)
{
  int i = blockIdx.x * 256 + threadIdx.x;   // 0..9215
  if (i < 9216) {
    int ch = i / 9, tap = i - ch * 9;
    wt[tap * 1024 + ch] = w[i];
  }
}

// ---------------- depthwise 3x3 conv + bias + exact gelu (float4 channels) ----------------
__global__ __launch_bounds__(256) void conv_gelu(
    const float* __restrict__ h, const float* __restrict__ wt, const float* __restrict__ bias,
    float* __restrict__ hc)
{
  const int pix = blockIdx.x;            // 0..8191
  const int b = pix >> 12;
  const int n = pix & 4095;
  const int y = n >> 6, xx = n & 63;
  const int c4 = threadIdx.x * 4;        // 0..1020
  float4 acc = *(const float4*)&bias[c4];
  const float* hb = h + ((size_t)b * 4096) * 1024 + c4;
  #pragma unroll
  for (int dy = 0; dy < 3; ++dy) {
    const int yy = y + dy - 1;
    if (yy < 0 || yy > 63) continue;
    #pragma unroll
    for (int dx = 0; dx < 3; ++dx) {
      const int xv = xx + dx - 1;
      if (xv < 0 || xv > 63) continue;
      float4 hv = *(const float4*)&hb[(size_t)(yy * 64 + xv) * 1024];
      float4 wv = *(const float4*)&wt[(dy * 3 + dx) * 1024 + c4];
      acc.x = fmaf(hv.x, wv.x, acc.x);
      acc.y = fmaf(hv.y, wv.y, acc.y);
      acc.z = fmaf(hv.z, wv.z, acc.z);
      acc.w = fmaf(hv.w, wv.w, acc.w);
    }
  }
  float4 g;
  g.x = 0.5f * acc.x * (1.f + erff(acc.x * 0.70710678118654752f));
  g.y = 0.5f * acc.y * (1.f + erff(acc.y * 0.70710678118654752f));
  g.z = 0.5f * acc.z * (1.f + erff(acc.z * 0.70710678118654752f));
  g.w = 0.5f * acc.w * (1.f + erff(acc.w * 0.70710678118654752f));
  *(float4*)&hc[((size_t)b * 4096 + n) * 1024 + c4] = g;
}

extern "C" void kernel_launch(void* const* d_in, const int* in_sizes, int n_in,
                              void* d_out, int out_size, void* d_ws, size_t ws_size,
                              hipStream_t stream)
{
  (void)in_sizes; (void)n_in; (void)out_size; (void)ws_size;
  const float* x    = (const float*)d_in[0];
  const float* z    = (const float*)d_in[1];
  const float* mem  = (const float*)d_in[2];
  const float* cw   = (const float*)d_in[3];
  const float* p1   = (const float*)d_in[4];
  const float* tdt1 = (const float*)d_in[5];
  const float* p2   = (const float*)d_in[6];
  const float* tdt2 = (const float*)d_in[7];
  const float* sal  = (const float*)d_in[8];
  const float* sbe  = (const float*)d_in[9];
  const float* q_w  = (const float*)d_in[10];
  const float* q_b  = (const float*)d_in[11];
  const float* k_w  = (const float*)d_in[12];
  const float* k_b  = (const float*)d_in[13];
  const float* v_w  = (const float*)d_in[14];
  const float* v_b  = (const float*)d_in[15];
  const float* pj_w = (const float*)d_in[16];
  const float* pj_b = (const float*)d_in[17];
  const float* nw   = (const float*)d_in[18];
  const float* nb   = (const float*)d_in[19];
  const float* f1w  = (const float*)d_in[20];
  const float* f1b  = (const float*)d_in[21];
  const float* dww  = (const float*)d_in[22];
  const float* dwb  = (const float*)d_in[23];
  const float* f2w  = (const float*)d_in[24];
  const float* f2b_ = (const float*)d_in[25];

  float* out = (float*)d_out;                  // (2,4096,256)
  float* csz = out + 2097152;                  // (2,150,16384)
  float* asg = csz + 4915200;                  // (2,4,150,4096)

  float* ws    = (float*)d_ws;
  float* clr   = ws;                 // 5,242,880 (row-major 160-wide), dead after gemm_csz
  float* part  = ws;                 // 4,915,200 reuse (gemm_cen..reduce_cen)
  float* coscl = ws + 5242880;
  float* cosz  = ws + 5275648;
  float* mr    = ws + 5308416;
  float* lr_   = ws + 5309616;
  float* cen   = ws + 5310816;
  float* cin   = ws + 5618016;
  float* q     = ws + 5694816;
  float* ksb   = ws + 7791968;
  float* vsb   = ws + 7868768;
  float* o     = ws + 7945568;
  float* h     = ws;                 // 8,388,608 reuse
  float* hc    = ws + 8388608;
  float* tmp   = ws + 16777216;
  float* out1  = ws + 18874368;
  float* wt    = ws + 20971520;      // 9,216 -> total 20,980,736 floats = 83.9 MB

  dim3 blk(256);
  // 1. cl (row-major) = xf @ cw^T   [MFMA]
  gemm_cl_mfma<<<dim3(256, 3), blk, 0, stream>>>(x, mem, cw, clr);
  // 2. cosine clip factors
  cos_stats<<<dim3(128, 2), blk, 0, stream>>>(z, clr, p1, p2, cosz, coscl);
  // 3. cluster_x_z + assigned   [MFMA, K=320]
  gemm_csz_mfma<<<dim3(256, 3), blk, 0, stream>>>(clr, z, coscl, cosz, tdt2, tdt1, csz, asg);
  // 4. softmax stats
  softmax_stats<<<dim3(1200), blk, 0, stream>>>(csz, mr, lr_);
  // 5. cen (split-K x16)
  gemm_cen<<<dim3(8, 8, 16), blk, 0, stream>>>(csz, x, mem, mr, part);
  reduce_cen<<<dim3(1200), blk, 0, stream>>>(part, lr_, cen);
  // 6. gate + LN -> C_in
  gate_ln<<<dim3(300), blk, 0, stream>>>(cen, sal, sbe, nw, nb, cin);
  // 7. q/k/v
  gemm_mfma<<<dim3(64, 4), blk, 0, stream>>>(x, q_w, q_b, q, 8192, 256, 256, 0.17677669529663687f);
  gemm_nt<<<dim3(3, 4), blk, 0, stream>>>(cin, k_w, k_b, ksb, 300, 256, 256, 1.f);
  gemm_nt<<<dim3(3, 4), blk, 0, stream>>>(cin, v_w, v_b, vsb, 300, 256, 256, 1.f);
  // 8. attention [MFMA]
  attn_mfma<<<dim3(512), blk, 0, stream>>>(q, ksb, vsb, o);
  // 9. proj + LN + residual
  gemm_mfma<<<dim3(64, 4), blk, 0, stream>>>(o, pj_w, pj_b, tmp, 8192, 256, 256, 1.f);
  ln_res<<<dim3(2048), blk, 0, stream>>>(tmp, x, nw, nb, out1);
  // 10. MLP
  gemm_mfma<<<dim3(64, 16), blk, 0, stream>>>(out1, f1w, f1b, h, 8192, 1024, 256, 1.f);
  conv_wt<<<dim3(36), blk, 0, stream>>>(dww, wt);
  conv_gelu<<<dim3(8192), blk, 0, stream>>>(h, wt, dwb, hc);
  gemm_mfma<<<dim3(64, 4), blk, 0, stream>>>(hc, f2w, f2b_, tmp, 8192, 256, 1024, 1.f);
  ln_res<<<dim3(2048), blk, 0, stream>>>(tmp, out1, nw, nb, out);
}

// Round 6
// 448.746 us; speedup vs baseline: 1.8933x; 1.0800x over previous
//
#include <hip/hip_runtime.h>
#include <math.h>

// Dims: B=2, N=4096, C=256, nc=150, T=4, TN=16384, heads=8, hd=32, hid=1024, H=W=64

typedef __attribute__((ext_vector_type(8))) short bf16x8;
typedef __attribute__((ext_vector_type(4))) float f32x4;

__device__ __forceinline__ short f2b(float f) {
  union { float f; unsigned int u; } c; c.f = f;
  unsigned int r = (c.u + 0x7fffu + ((c.u >> 16) & 1u)) >> 16;
  return (short)r;
}

// ---------------- block reduction helpers (blockDim.x == 256) ----------------
__device__ __forceinline__ float bred_sum(float v, float* red) {
  int tid = threadIdx.x;
  red[tid] = v; __syncthreads();
  #pragma unroll
  for (int s = 128; s > 0; s >>= 1) {
    if (tid < s) red[tid] += red[tid + s];
    __syncthreads();
  }
  float r = red[0]; __syncthreads();
  return r;
}

// ---------------- bf16 MFMA GEMM: out[m][n] = alpha*(sum_k A[m,k]*W[n,k] + bias[n]) ----------------
__global__ __launch_bounds__(256) void gemm_mfma(
    const float* __restrict__ A, const float* __restrict__ W,
    const float* __restrict__ bias, float* __restrict__ out,
    int M, int N, int K, float alpha)
{
  __shared__ __align__(16) short As[128 * 72];
  __shared__ __align__(16) short Bs[64 * 72];
  const int tid = threadIdx.x;
  const int m0 = blockIdx.x * 128;
  const int n0 = blockIdx.y * 64;
  const int wave = tid >> 6;
  const int lane = tid & 63;
  const int wm = wave & 1, wn = wave >> 1;
  const int t16 = lane & 15;
  const int k8 = (lane >> 4) * 8;

  f32x4 acc[4][2];
  #pragma unroll
  for (int i = 0; i < 4; ++i)
    #pragma unroll
    for (int j = 0; j < 2; ++j)
      acc[i][j] = (f32x4){0.f, 0.f, 0.f, 0.f};

  const int sr = tid >> 2;
  const int sk = (tid & 3) * 16;

  for (int k0 = 0; k0 < K; k0 += 64) {
    #pragma unroll
    for (int p = 0; p < 2; ++p) {
      const int row = sr + p * 64;
      const float* ap = &A[(size_t)(m0 + row) * K + k0 + sk];
      float4 v0 = *(const float4*)&ap[0];
      float4 v1 = *(const float4*)&ap[4];
      float4 v2 = *(const float4*)&ap[8];
      float4 v3 = *(const float4*)&ap[12];
      bf16x8 w0, w1;
      w0[0] = f2b(v0.x); w0[1] = f2b(v0.y); w0[2] = f2b(v0.z); w0[3] = f2b(v0.w);
      w0[4] = f2b(v1.x); w0[5] = f2b(v1.y); w0[6] = f2b(v1.z); w0[7] = f2b(v1.w);
      w1[0] = f2b(v2.x); w1[1] = f2b(v2.y); w1[2] = f2b(v2.z); w1[3] = f2b(v2.w);
      w1[4] = f2b(v3.x); w1[5] = f2b(v3.y); w1[6] = f2b(v3.z); w1[7] = f2b(v3.w);
      *(bf16x8*)&As[row * 72 + sk] = w0;
      *(bf16x8*)&As[row * 72 + sk + 8] = w1;
    }
    {
      const float* wp = &W[(size_t)(n0 + sr) * K + k0 + sk];
      float4 v0 = *(const float4*)&wp[0];
      float4 v1 = *(const float4*)&wp[4];
      float4 v2 = *(const float4*)&wp[8];
      float4 v3 = *(const float4*)&wp[12];
      bf16x8 w0, w1;
      w0[0] = f2b(v0.x); w0[1] = f2b(v0.y); w0[2] = f2b(v0.z); w0[3] = f2b(v0.w);
      w0[4] = f2b(v1.x); w0[5] = f2b(v1.y); w0[6] = f2b(v1.z); w0[7] = f2b(v1.w);
      w1[0] = f2b(v2.x); w1[1] = f2b(v2.y); w1[2] = f2b(v2.z); w1[3] = f2b(v2.w);
      w1[4] = f2b(v3.x); w1[5] = f2b(v3.y); w1[6] = f2b(v3.z); w1[7] = f2b(v3.w);
      *(bf16x8*)&Bs[sr * 72 + sk] = w0;
      *(bf16x8*)&Bs[sr * 72 + sk + 8] = w1;
    }
    __syncthreads();
    #pragma unroll
    for (int ks = 0; ks < 2; ++ks) {
      const int kofs = ks * 32 + k8;
      bf16x8 af0 = *(const bf16x8*)&As[(wm * 64 +  0 + t16) * 72 + kofs];
      bf16x8 af1 = *(const bf16x8*)&As[(wm * 64 + 16 + t16) * 72 + kofs];
      bf16x8 af2 = *(const bf16x8*)&As[(wm * 64 + 32 + t16) * 72 + kofs];
      bf16x8 af3 = *(const bf16x8*)&As[(wm * 64 + 48 + t16) * 72 + kofs];
      bf16x8 bf0 = *(const bf16x8*)&Bs[(wn * 32 +  0 + t16) * 72 + kofs];
      bf16x8 bf1 = *(const bf16x8*)&Bs[(wn * 32 + 16 + t16) * 72 + kofs];
      acc[0][0] = __builtin_amdgcn_mfma_f32_16x16x32_bf16(af0, bf0, acc[0][0], 0, 0, 0);
      acc[1][0] = __builtin_amdgcn_mfma_f32_16x16x32_bf16(af1, bf0, acc[1][0], 0, 0, 0);
      acc[2][0] = __builtin_amdgcn_mfma_f32_16x16x32_bf16(af2, bf0, acc[2][0], 0, 0, 0);
      acc[3][0] = __builtin_amdgcn_mfma_f32_16x16x32_bf16(af3, bf0, acc[3][0], 0, 0, 0);
      acc[0][1] = __builtin_amdgcn_mfma_f32_16x16x32_bf16(af0, bf1, acc[0][1], 0, 0, 0);
      acc[1][1] = __builtin_amdgcn_mfma_f32_16x16x32_bf16(af1, bf1, acc[1][1], 0, 0, 0);
      acc[2][1] = __builtin_amdgcn_mfma_f32_16x16x32_bf16(af2, bf1, acc[2][1], 0, 0, 0);
      acc[3][1] = __builtin_amdgcn_mfma_f32_16x16x32_bf16(af3, bf1, acc[3][1], 0, 0, 0);
    }
    __syncthreads();
  }
  const int r4 = (lane >> 4) * 4;
  #pragma unroll
  for (int ni = 0; ni < 2; ++ni) {
    const int gcol = n0 + wn * 32 + ni * 16 + t16;
    const float bb = bias[gcol];
    #pragma unroll
    for (int mi = 0; mi < 4; ++mi) {
      #pragma unroll
      for (int r = 0; r < 4; ++r) {
        const int gm = m0 + wm * 64 + mi * 16 + r4 + r;
        out[(size_t)gm * N + gcol] = alpha * (acc[mi][ni][r] + bb);
      }
    }
  }
}

// ---------------- MFMA cl: clr[b*16384 + ti*4096 + n][kc(160 pad)] = xf @ cw^T ----------------
__global__ __launch_bounds__(256) void gemm_cl_mfma(
    const float* __restrict__ x, const float* __restrict__ mem,
    const float* __restrict__ cw, float* __restrict__ clr)
{
  __shared__ __align__(16) short As[128 * 72];
  __shared__ __align__(16) short Bs[64 * 72];
  const int tid = threadIdx.x;
  const int m0 = blockIdx.x * 128;
  const int n0 = blockIdx.y * 64;
  const int bt = m0 >> 12;
  const int b = bt >> 2, ti = bt & 3;
  const int nbase = m0 & 4095;
  const float* Abase = (ti < 3) ? (mem + (size_t)(b * 3 + ti) * 4096 * 256)
                                : (x + (size_t)b * 4096 * 256);
  const int wave = tid >> 6, lane = tid & 63;
  const int wm = wave & 1, wn = wave >> 1;
  const int t16 = lane & 15;
  const int k8 = (lane >> 4) * 8;

  f32x4 acc[4][2];
  #pragma unroll
  for (int i = 0; i < 4; ++i)
    #pragma unroll
    for (int j = 0; j < 2; ++j)
      acc[i][j] = (f32x4){0.f, 0.f, 0.f, 0.f};

  const int sr = tid >> 2;
  const int sk = (tid & 3) * 16;

  for (int k0 = 0; k0 < 256; k0 += 64) {
    #pragma unroll
    for (int p = 0; p < 2; ++p) {
      const int row = sr + p * 64;
      const float* ap = &Abase[(size_t)(nbase + row) * 256 + k0 + sk];
      float4 v0 = *(const float4*)&ap[0];
      float4 v1 = *(const float4*)&ap[4];
      float4 v2 = *(const float4*)&ap[8];
      float4 v3 = *(const float4*)&ap[12];
      bf16x8 w0, w1;
      w0[0] = f2b(v0.x); w0[1] = f2b(v0.y); w0[2] = f2b(v0.z); w0[3] = f2b(v0.w);
      w0[4] = f2b(v1.x); w0[5] = f2b(v1.y); w0[6] = f2b(v1.z); w0[7] = f2b(v1.w);
      w1[0] = f2b(v2.x); w1[1] = f2b(v2.y); w1[2] = f2b(v2.z); w1[3] = f2b(v2.w);
      w1[4] = f2b(v3.x); w1[5] = f2b(v3.y); w1[6] = f2b(v3.z); w1[7] = f2b(v3.w);
      *(bf16x8*)&As[row * 72 + sk] = w0;
      *(bf16x8*)&As[row * 72 + sk + 8] = w1;
    }
    {
      const int gn = n0 + sr;
      bf16x8 w0 = {0,0,0,0,0,0,0,0}, w1 = {0,0,0,0,0,0,0,0};
      if (gn < 150) {
        const float* wp = &cw[(size_t)gn * 256 + k0 + sk];
        float4 v0 = *(const float4*)&wp[0];
        float4 v1 = *(const float4*)&wp[4];
        float4 v2 = *(const float4*)&wp[8];
        float4 v3 = *(const float4*)&wp[12];
        w0[0] = f2b(v0.x); w0[1] = f2b(v0.y); w0[2] = f2b(v0.z); w0[3] = f2b(v0.w);
        w0[4] = f2b(v1.x); w0[5] = f2b(v1.y); w0[6] = f2b(v1.z); w0[7] = f2b(v1.w);
        w1[0] = f2b(v2.x); w1[1] = f2b(v2.y); w1[2] = f2b(v2.z); w1[3] = f2b(v2.w);
        w1[4] = f2b(v3.x); w1[5] = f2b(v3.y); w1[6] = f2b(v3.z); w1[7] = f2b(v3.w);
      }
      *(bf16x8*)&Bs[sr * 72 + sk] = w0;
      *(bf16x8*)&Bs[sr * 72 + sk + 8] = w1;
    }
    __syncthreads();
    #pragma unroll
    for (int ks = 0; ks < 2; ++ks) {
      const int kofs = ks * 32 + k8;
      bf16x8 af0 = *(const bf16x8*)&As[(wm * 64 +  0 + t16) * 72 + kofs];
      bf16x8 af1 = *(const bf16x8*)&As[(wm * 64 + 16 + t16) * 72 + kofs];
      bf16x8 af2 = *(const bf16x8*)&As[(wm * 64 + 32 + t16) * 72 + kofs];
      bf16x8 af3 = *(const bf16x8*)&As[(wm * 64 + 48 + t16) * 72 + kofs];
      bf16x8 bf0 = *(const bf16x8*)&Bs[(wn * 32 +  0 + t16) * 72 + kofs];
      bf16x8 bf1 = *(const bf16x8*)&Bs[(wn * 32 + 16 + t16) * 72 + kofs];
      acc[0][0] = __builtin_amdgcn_mfma_f32_16x16x32_bf16(af0, bf0, acc[0][0], 0, 0, 0);
      acc[1][0] = __builtin_amdgcn_mfma_f32_16x16x32_bf16(af1, bf0, acc[1][0], 0, 0, 0);
      acc[2][0] = __builtin_amdgcn_mfma_f32_16x16x32_bf16(af2, bf0, acc[2][0], 0, 0, 0);
      acc[3][0] = __builtin_amdgcn_mfma_f32_16x16x32_bf16(af3, bf0, acc[3][0], 0, 0, 0);
      acc[0][1] = __builtin_amdgcn_mfma_f32_16x16x32_bf16(af0, bf1, acc[0][1], 0, 0, 0);
      acc[1][1] = __builtin_amdgcn_mfma_f32_16x16x32_bf16(af1, bf1, acc[1][1], 0, 0, 0);
      acc[2][1] = __builtin_amdgcn_mfma_f32_16x16x32_bf16(af2, bf1, acc[2][1], 0, 0, 0);
      acc[3][1] = __builtin_amdgcn_mfma_f32_16x16x32_bf16(af3, bf1, acc[3][1], 0, 0, 0);
    }
    __syncthreads();
  }
  const int r4 = (lane >> 4) * 4;
  const size_t rowbase = (size_t)b * 16384 + ti * 4096 + nbase;
  #pragma unroll
  for (int ni = 0; ni < 2; ++ni) {
    const int col = n0 + wn * 32 + ni * 16 + t16;
    if (col >= 160) continue;
    #pragma unroll
    for (int mi = 0; mi < 4; ++mi) {
      const int mrow = wm * 64 + mi * 16 + r4;
      #pragma unroll
      for (int r = 0; r < 4; ++r)
        clr[(rowbase + mrow + r) * 160 + col] = acc[mi][ni][r];
    }
  }
}

// ---------------- cosine clip factors (y=0: z strided; y=1: clr row-major) ----------------
__global__ __launch_bounds__(256) void cos_stats(
    const float* __restrict__ z, const float* __restrict__ clr,
    const float* __restrict__ p1, const float* __restrict__ p2,
    float* __restrict__ cosz, float* __restrict__ coscl)
{
  int which = blockIdx.y;
  int gid = blockIdx.x * 256 + threadIdx.x;
  int b = gid >> 14, m = gid & 16383;
  float d = 0, s = 0, pn = 0;
  if (which) {
    const float* sp = clr + ((size_t)b * 16384 + m) * 160;
    for (int k = 0; k < 148; k += 4) {
      float4 v = *(const float4*)&sp[k];
      float4 a = *(const float4*)&p2[k];
      d += v.x * a.x + v.y * a.y + v.z * a.z + v.w * a.w;
      s += v.x * v.x + v.y * v.y + v.z * v.z + v.w * v.w;
      pn += a.x * a.x + a.y * a.y + a.z * a.z + a.w * a.w;
    }
    for (int k = 148; k < 150; ++k) {
      float v = sp[k], a = p2[k];
      d += v * a; s += v * v; pn += a * a;
    }
    float c = d / (fmaxf(sqrtf(s), 1e-12f) * fmaxf(sqrtf(pn), 1e-12f));
    coscl[gid] = fminf(fmaxf(c, 0.f), 1.f);
  } else {
    const float* sp = z + (size_t)b * 150 * 16384 + m;
    for (int k = 0; k < 150; ++k) {
      float v = sp[(size_t)k * 16384];
      float a = p1[k];
      d += v * a; s += v * v; pn += a * a;
    }
    float c = d / (fmaxf(sqrtf(s), 1e-12f) * fmaxf(sqrtf(pn), 1e-12f));
    cosz[gid] = fminf(fmaxf(c, 0.f), 1.f);
  }
}

// ---------------- MFMA csz: csz[b][kc][m] = 0.5*(coscl*cl@tdt2 + cosz*z@tdt1), + asg ----------------
__global__ __launch_bounds__(256) void gemm_csz_mfma(
    const float* __restrict__ clr, const float* __restrict__ z,
    const float* __restrict__ coscl, const float* __restrict__ cosz,
    const float* __restrict__ tdt2, const float* __restrict__ tdt1,
    float* __restrict__ csz, float* __restrict__ asg)
{
  __shared__ __align__(16) short As[128 * 40];
  __shared__ __align__(16) short Bs[64 * 40];
  const int tid = threadIdx.x;
  const int m0 = blockIdx.x * 128;
  const int b = m0 >> 14;
  const int mm = m0 & 16383;
  const int n0 = blockIdx.y * 64;
  const int wave = tid >> 6, lane = tid & 63;
  const int wm = wave & 1, wn = wave >> 1;
  const int t16 = lane & 15;
  const int k8 = (lane >> 4) * 8;

  f32x4 acc[4][2];
  #pragma unroll
  for (int i = 0; i < 4; ++i)
    #pragma unroll
    for (int j = 0; j < 2; ++j)
      acc[i][j] = (f32x4){0.f, 0.f, 0.f, 0.f};

  for (int c = 0; c < 10; ++c) {
    if (c < 5) {
      const int row = tid >> 1;
      const int sk0 = (tid & 1) * 16;
      const float* ap = &clr[((size_t)b * 16384 + mm + row) * 160 + c * 32 + sk0];
      const float cs = coscl[(size_t)b * 16384 + mm + row];
      float4 v0 = *(const float4*)&ap[0];
      float4 v1 = *(const float4*)&ap[4];
      float4 v2 = *(const float4*)&ap[8];
      float4 v3 = *(const float4*)&ap[12];
      bf16x8 w0, w1;
      w0[0] = f2b(v0.x * cs); w0[1] = f2b(v0.y * cs); w0[2] = f2b(v0.z * cs); w0[3] = f2b(v0.w * cs);
      w0[4] = f2b(v1.x * cs); w0[5] = f2b(v1.y * cs); w0[6] = f2b(v1.z * cs); w0[7] = f2b(v1.w * cs);
      w1[0] = f2b(v2.x * cs); w1[1] = f2b(v2.y * cs); w1[2] = f2b(v2.z * cs); w1[3] = f2b(v2.w * cs);
      w1[4] = f2b(v3.x * cs); w1[5] = f2b(v3.y * cs); w1[6] = f2b(v3.z * cs); w1[7] = f2b(v3.w * cs);
      *(bf16x8*)&As[row * 40 + sk0] = w0;
      *(bf16x8*)&As[row * 40 + sk0 + 8] = w1;
    } else {
      const int kgl = tid >> 3;
      const int mb = (tid & 7) * 4;
      const int kg = (c - 5) * 32 + kgl;
      #pragma unroll
      for (int p = 0; p < 4; ++p) {
        const int m = mb + p * 32;
        float4 v = make_float4(0.f, 0.f, 0.f, 0.f);
        if (kg < 150) {
          v = *(const float4*)&z[((size_t)b * 150 + kg) * 16384 + mm + m];
          float4 cz = *(const float4*)&cosz[(size_t)b * 16384 + mm + m];
          v.x *= cz.x; v.y *= cz.y; v.z *= cz.z; v.w *= cz.w;
        }
        As[(m + 0) * 40 + kgl] = f2b(v.x);
        As[(m + 1) * 40 + kgl] = f2b(v.y);
        As[(m + 2) * 40 + kgl] = f2b(v.z);
        As[(m + 3) * 40 + kgl] = f2b(v.w);
      }
    }
    {
      const int kc = tid & 63;
      const int gn = n0 + kc;
      #pragma unroll
      for (int p = 0; p < 8; ++p) {
        const int kgl = (tid >> 6) + p * 4;
        const int kg = c * 32 + kgl;
        float t = 0.f;
        if (gn < 150) {
          if (kg < 150) t = tdt2[kg * 150 + gn];
          else if (kg >= 160 && kg < 310) t = tdt1[(kg - 160) * 150 + gn];
        }
        Bs[kc * 40 + kgl] = f2b(t);
      }
    }
    __syncthreads();
    {
      bf16x8 af0 = *(const bf16x8*)&As[(wm * 64 +  0 + t16) * 40 + k8];
      bf16x8 af1 = *(const bf16x8*)&As[(wm * 64 + 16 + t16) * 40 + k8];
      bf16x8 af2 = *(const bf16x8*)&As[(wm * 64 + 32 + t16) * 40 + k8];
      bf16x8 af3 = *(const bf16x8*)&As[(wm * 64 + 48 + t16) * 40 + k8];
      bf16x8 bf0 = *(const bf16x8*)&Bs[(wn * 32 +  0 + t16) * 40 + k8];
      bf16x8 bf1 = *(const bf16x8*)&Bs[(wn * 32 + 16 + t16) * 40 + k8];
      acc[0][0] = __builtin_amdgcn_mfma_f32_16x16x32_bf16(af0, bf0, acc[0][0], 0, 0, 0);
      acc[1][0] = __builtin_amdgcn_mfma_f32_16x16x32_bf16(af1, bf0, acc[1][0], 0, 0, 0);
      acc[2][0] = __builtin_amdgcn_mfma_f32_16x16x32_bf16(af2, bf0, acc[2][0], 0, 0, 0);
      acc[3][0] = __builtin_amdgcn_mfma_f32_16x16x32_bf16(af3, bf0, acc[3][0], 0, 0, 0);
      acc[0][1] = __builtin_amdgcn_mfma_f32_16x16x32_bf16(af0, bf1, acc[0][1], 0, 0, 0);
      acc[1][1] = __builtin_amdgcn_mfma_f32_16x16x32_bf16(af1, bf1, acc[1][1], 0, 0, 0);
      acc[2][1] = __builtin_amdgcn_mfma_f32_16x16x32_bf16(af2, bf1, acc[2][1], 0, 0, 0);
      acc[3][1] = __builtin_amdgcn_mfma_f32_16x16x32_bf16(af3, bf1, acc[3][1], 0, 0, 0);
    }
    __syncthreads();
  }
  const int r4 = (lane >> 4) * 4;
  const int ti = mm >> 12;
  const int nn = mm & 4095;
  #pragma unroll
  for (int ni = 0; ni < 2; ++ni) {
    const int kc = n0 + wn * 32 + ni * 16 + t16;
    if (kc >= 150) continue;
    #pragma unroll
    for (int mi = 0; mi < 4; ++mi) {
      const int mrow = wm * 64 + mi * 16 + r4;
      float4 r;
      r.x = 0.5f * acc[mi][ni][0];
      r.y = 0.5f * acc[mi][ni][1];
      r.z = 0.5f * acc[mi][ni][2];
      r.w = 0.5f * acc[mi][ni][3];
      *(float4*)&csz[((size_t)b * 150 + kc) * 16384 + mm + mrow] = r;
      *(float4*)&asg[(((size_t)b * 4 + ti) * 150 + kc) * 4096 + nn + mrow] = r;
    }
  }
}

// ---------------- softmax stats + exp materialization (bf16) ----------------
// row = bt*150+k; writes ecsz[bt][160pad][4096] bf16 = exp(csz - rowmax); lr = rowsum
__global__ __launch_bounds__(256) void softmax_stats_e(
    const float* __restrict__ csz, float* __restrict__ lr_, short* __restrict__ ecsz)
{
  __shared__ float wred[8];
  const int row = blockIdx.x;
  const int bt = row / 150, k = row - bt * 150;
  const int b = bt >> 2, ti = bt & 3;
  const float* p = csz + ((size_t)b * 150 + k) * 16384 + ti * 4096;
  const int base = threadIdx.x * 16;
  float4 v[4];
  #pragma unroll
  for (int i = 0; i < 4; ++i) v[i] = *(const float4*)&p[base + i * 4];
  float mx = -1e30f;
  #pragma unroll
  for (int i = 0; i < 4; ++i)
    mx = fmaxf(mx, fmaxf(fmaxf(v[i].x, v[i].y), fmaxf(v[i].z, v[i].w)));
  #pragma unroll
  for (int off = 1; off < 64; off <<= 1) mx = fmaxf(mx, __shfl_xor(mx, off));
  const int wave = threadIdx.x >> 6, lane = threadIdx.x & 63;
  if (lane == 0) wred[wave] = mx;
  __syncthreads();
  mx = fmaxf(fmaxf(wred[0], wred[1]), fmaxf(wred[2], wred[3]));
  const float L = 1.4426950408889634f;
  float s = 0.f;
  bf16x8 e0, e1;
  #pragma unroll
  for (int i = 0; i < 2; ++i) {
    float a = exp2f((v[i].x - mx) * L);
    float bq = exp2f((v[i].y - mx) * L);
    float cq = exp2f((v[i].z - mx) * L);
    float dq = exp2f((v[i].w - mx) * L);
    s += a + bq + cq + dq;
    e0[i * 4 + 0] = f2b(a); e0[i * 4 + 1] = f2b(bq); e0[i * 4 + 2] = f2b(cq); e0[i * 4 + 3] = f2b(dq);
  }
  #pragma unroll
  for (int i = 2; i < 4; ++i) {
    float a = exp2f((v[i].x - mx) * L);
    float bq = exp2f((v[i].y - mx) * L);
    float cq = exp2f((v[i].z - mx) * L);
    float dq = exp2f((v[i].w - mx) * L);
    s += a + bq + cq + dq;
    e1[(i - 2) * 4 + 0] = f2b(a); e1[(i - 2) * 4 + 1] = f2b(bq);
    e1[(i - 2) * 4 + 2] = f2b(cq); e1[(i - 2) * 4 + 3] = f2b(dq);
  }
  #pragma unroll
  for (int off = 1; off < 64; off <<= 1) s += __shfl_xor(s, off);
  if (lane == 0) wred[4 + wave] = s;
  __syncthreads();
  short* er = ecsz + ((size_t)bt * 160 + k) * 4096 + base;
  *(bf16x8*)&er[0] = e0;
  *(bf16x8*)&er[8] = e1;
  if (threadIdx.x == 0) lr_[row] = wred[4] + wred[5] + wred[6] + wred[7];
}

// ---------------- cen numerator via MFMA + atomic split-K ----------------
// grid (2 chalf, 8 bt, 16 sp); block 256 = 4 waves; M=160(k) x N=128(c-half) x K=256(n)
__global__ __launch_bounds__(256) void gemm_cen_at(
    const short* __restrict__ ecsz, const float* __restrict__ x, const float* __restrict__ mem,
    float* __restrict__ cen)
{
  __shared__ __align__(16) short As[160 * 136];
  const int tid = threadIdx.x;
  const int chalf = blockIdx.x;
  const int bt = blockIdx.y;
  const int sp = blockIdx.z;
  const int b = bt >> 2, ti = bt & 3;
  const float* xf = (ti < 3) ? (mem + (size_t)(b * 3 + ti) * 4096 * 256)
                             : (x + (size_t)b * 4096 * 256);
  const int n0 = sp * 256;
  const int wave = tid >> 6, lane = tid & 63;
  const int t16 = lane & 15, quad = lane >> 4, k8 = quad * 8;
  const int cbase = chalf * 128 + wave * 32;

  f32x4 acc[10][2];
  #pragma unroll
  for (int i = 0; i < 10; ++i) {
    acc[i][0] = (f32x4){0.f, 0.f, 0.f, 0.f};
    acc[i][1] = (f32x4){0.f, 0.f, 0.f, 0.f};
  }

  const short* erow = ecsz + (size_t)bt * 160 * 4096 + n0;
  #pragma unroll
  for (int half = 0; half < 2; ++half) {
    // stage A: 160 rows x 128 k-cols (b128 in/out)
    #pragma unroll
    for (int p = 0; p < 10; ++p) {
      const int g = p * 256 + tid;
      const int row = g >> 4;
      const int col8 = (g & 15) * 8;
      *(bf16x8*)&As[row * 136 + col8] =
          *(const bf16x8*)&erow[(size_t)row * 4096 + half * 128 + col8];
    }
    __syncthreads();
    #pragma unroll
    for (int kc = 0; kc < 4; ++kc) {
      bf16x8 bB[2];
      #pragma unroll
      for (int nt = 0; nt < 2; ++nt) {
        bf16x8 w;
        #pragma unroll
        for (int j = 0; j < 8; ++j)
          w[j] = f2b(xf[(size_t)(n0 + half * 128 + kc * 32 + k8 + j) * 256 + cbase + nt * 16 + t16]);
        bB[nt] = w;
      }
      #pragma unroll
      for (int mt = 0; mt < 10; ++mt) {
        bf16x8 aA = *(const bf16x8*)&As[(mt * 16 + t16) * 136 + kc * 32 + k8];
        acc[mt][0] = __builtin_amdgcn_mfma_f32_16x16x32_bf16(aA, bB[0], acc[mt][0], 0, 0, 0);
        acc[mt][1] = __builtin_amdgcn_mfma_f32_16x16x32_bf16(aA, bB[1], acc[mt][1], 0, 0, 0);
      }
    }
    __syncthreads();
  }
  #pragma unroll
  for (int mt = 0; mt < 10; ++mt) {
    #pragma unroll
    for (int r = 0; r < 4; ++r) {
      const int grow = mt * 16 + quad * 4 + r;
      if (grow < 150) {
        atomicAdd(&cen[((size_t)bt * 150 + grow) * 256 + cbase + t16], acc[mt][0][r]);
        atomicAdd(&cen[((size_t)bt * 150 + grow) * 256 + cbase + 16 + t16], acc[mt][1][r]);
      }
    }
  }
}

// ---------------- similarity gate + LN -> C_in (cen holds numerators; /lr here) ----------------
__global__ __launch_bounds__(256) void gate_ln(
    const float* __restrict__ cen, const float* __restrict__ lr_,
    const float* __restrict__ alpha_, const float* __restrict__ beta_,
    const float* __restrict__ nw, const float* __restrict__ nb, float* __restrict__ cin)
{
  __shared__ float red[256];
  int bk = blockIdx.x;
  int b = bk / 150, k = bk % 150;
  int c = threadIdx.x;
  const float* base = cen + ((size_t)b * 4 * 150) * 256;
  const float* lrb = lr_ + (size_t)b * 4 * 150;
  float lc  = base[((size_t)3 * 150 + k) * 256 + c] / lrb[3 * 150 + k];
  float p0  = base[((size_t)0 * 150 + k) * 256 + c] / lrb[0 * 150 + k];
  float p1v = base[((size_t)1 * 150 + k) * 256 + c] / lrb[1 * 150 + k];
  float p2v = base[((size_t)2 * 150 + k) * 256 + c] / lrb[2 * 150 + k];
  float nl = bred_sum(lc * lc, red);
  float q0 = bred_sum(p0 * p0, red);
  float q1 = bred_sum(p1v * p1v, red);
  float q2 = bred_sum(p2v * p2v, red);
  float d0 = bred_sum(lc * p0, red);
  float d1 = bred_sum(lc * p1v, red);
  float d2 = bred_sum(lc * p2v, red);
  float al = alpha_[0], be = beta_[0];
  float snl = sqrtf(nl);
  float g0 = 1.f / (1.f + expf(-(be + al * (d0 / fmaxf(snl * sqrtf(q0), 1e-8f)))));
  float g1 = 1.f / (1.f + expf(-(be + al * (d1 / fmaxf(snl * sqrtf(q1), 1e-8f)))));
  float g2 = 1.f / (1.f + expf(-(be + al * (d2 / fmaxf(snl * sqrtf(q2), 1e-8f)))));
  float ci = lc + g0 * p0 + g1 * p1v + g2 * p2v;
  float mu = bred_sum(ci, red) * (1.f / 256.f);
  float df = ci - mu;
  float var = bred_sum(df * df, red) * (1.f / 256.f);
  cin[(size_t)bk * 256 + c] = df * rsqrtf(var + 1e-5f) * nw[c] + nb[c];
}

// ---------------- generic fp32 GEMM (small shapes: k/v) ----------------
__global__ __launch_bounds__(256) void gemm_nt(
    const float* __restrict__ A, const float* __restrict__ W,
    const float* __restrict__ bias, float* __restrict__ out,
    int M, int N, int K, float alpha)
{
  __shared__ __align__(16) float As[16][132];
  __shared__ __align__(16) float Ws[16][68];
  const int tid = threadIdx.x;
  const int m0 = blockIdx.x * 128;
  const int n0 = blockIdx.y * 64;
  const int tm = tid & 15;
  const int tn = tid >> 4;
  float acc[8][4];
  #pragma unroll
  for (int i = 0; i < 8; ++i)
    #pragma unroll
    for (int j = 0; j < 4; ++j) acc[i][j] = 0.f;

  const int lr = tid >> 2;
  const int lk = (tid & 3) * 4;

  for (int k0 = 0; k0 < K; k0 += 16) {
    #pragma unroll
    for (int p = 0; p < 2; ++p) {
      int r = lr + p * 64;
      int gm = m0 + r;
      float4 v = make_float4(0.f, 0.f, 0.f, 0.f);
      if (gm < M) v = *(const float4*)&A[(size_t)gm * K + k0 + lk];
      As[lk + 0][r] = v.x; As[lk + 1][r] = v.y; As[lk + 2][r] = v.z; As[lk + 3][r] = v.w;
    }
    {
      float4 v = *(const float4*)&W[(size_t)(n0 + lr) * K + k0 + lk];
      Ws[lk + 0][lr] = v.x; Ws[lk + 1][lr] = v.y; Ws[lk + 2][lr] = v.z; Ws[lk + 3][lr] = v.w;
    }
    __syncthreads();
    #pragma unroll
    for (int kk = 0; kk < 16; ++kk) {
      float4 a0 = *(const float4*)&As[kk][tm * 8];
      float4 a1 = *(const float4*)&As[kk][tm * 8 + 4];
      float4 w0 = *(const float4*)&Ws[kk][tn * 4];
      float av[8] = {a0.x, a0.y, a0.z, a0.w, a1.x, a1.y, a1.z, a1.w};
      float wv[4] = {w0.x, w0.y, w0.z, w0.w};
      #pragma unroll
      for (int i = 0; i < 8; ++i)
        #pragma unroll
        for (int j = 0; j < 4; ++j)
          acc[i][j] = fmaf(av[i], wv[j], acc[i][j]);
    }
    __syncthreads();
  }
  float4 bv = *(const float4*)&bias[n0 + tn * 4];
  float bb[4] = {bv.x, bv.y, bv.z, bv.w};
  #pragma unroll
  for (int i = 0; i < 8; ++i) {
    int gm = m0 + tm * 8 + i;
    if (gm >= M) continue;
    float4 r;
    r.x = alpha * (acc[i][0] + bb[0]);
    r.y = alpha * (acc[i][1] + bb[1]);
    r.z = alpha * (acc[i][2] + bb[2]);
    r.w = alpha * (acc[i][3] + bb[3]);
    *(float4*)&out[(size_t)gm * N + n0 + tn * 4] = r;
  }
}

// ---------------- MFMA attention: 128 Q-rows/block, per (b,h) ----------------
__global__ __launch_bounds__(256) void attn_mfma(
    const float* __restrict__ q, const float* __restrict__ ks, const float* __restrict__ vs,
    float* __restrict__ o)
{
  __shared__ __align__(16) short Ps[128 * 168];
  __shared__ __align__(16) short VT[32 * 168];
  __shared__ float lrow[128];
  const int tid = threadIdx.x;
  const int bid = blockIdx.x;
  const int ntile = bid & 31;
  const int bh = bid >> 5;
  const int b = bh >> 3, h = bh & 7;
  const int n0 = ntile * 128;
  const int wave = tid >> 6, lane = tid & 63;
  const int t16 = lane & 15, quad = lane >> 4;
  const int k8 = quad * 8;
  const int wr = wave * 32;

  for (int i = tid; i < 5120; i += 256) {
    int d = i / 160, kc = i - d * 160;
    VT[d * 168 + kc] = (kc < 150) ? f2b(vs[((size_t)b * 150 + kc) * 256 + h * 32 + d]) : (short)0;
  }

  bf16x8 aQ[2];
  #pragma unroll
  for (int mt = 0; mt < 2; ++mt) {
    const float* qp = &q[((size_t)b * 4096 + n0 + wr + mt * 16 + t16) * 256 + h * 32 + k8];
    float4 v0 = *(const float4*)&qp[0];
    float4 v1 = *(const float4*)&qp[4];
    bf16x8 w;
    w[0] = f2b(v0.x); w[1] = f2b(v0.y); w[2] = f2b(v0.z); w[3] = f2b(v0.w);
    w[4] = f2b(v1.x); w[5] = f2b(v1.y); w[6] = f2b(v1.z); w[7] = f2b(v1.w);
    aQ[mt] = w;
  }

  f32x4 s[2][10];
  #pragma unroll
  for (int ct = 0; ct < 10; ++ct) {
    const int c = ct * 16 + t16;
    bf16x8 bK = {0, 0, 0, 0, 0, 0, 0, 0};
    if (c < 150) {
      const float* kp = &ks[((size_t)b * 150 + c) * 256 + h * 32 + k8];
      float4 v0 = *(const float4*)&kp[0];
      float4 v1 = *(const float4*)&kp[4];
      bK[0] = f2b(v0.x); bK[1] = f2b(v0.y); bK[2] = f2b(v0.z); bK[3] = f2b(v0.w);
      bK[4] = f2b(v1.x); bK[5] = f2b(v1.y); bK[6] = f2b(v1.z); bK[7] = f2b(v1.w);
    }
    f32x4 zero = (f32x4){0.f, 0.f, 0.f, 0.f};
    s[0][ct] = __builtin_amdgcn_mfma_f32_16x16x32_bf16(aQ[0], bK, zero, 0, 0, 0);
    s[1][ct] = __builtin_amdgcn_mfma_f32_16x16x32_bf16(aQ[1], bK, zero, 0, 0, 0);
  }

  #pragma unroll
  for (int mt = 0; mt < 2; ++mt) {
    #pragma unroll
    for (int r = 0; r < 4; ++r) {
      float mx = -1e30f;
      #pragma unroll
      for (int ct = 0; ct < 10; ++ct) {
        float v = s[mt][ct][r];
        if (ct == 9 && t16 >= 6) { v = -1e30f; s[mt][ct][r] = v; }
        mx = fmaxf(mx, v);
      }
      mx = fmaxf(mx, __shfl_xor(mx, 1));
      mx = fmaxf(mx, __shfl_xor(mx, 2));
      mx = fmaxf(mx, __shfl_xor(mx, 4));
      mx = fmaxf(mx, __shfl_xor(mx, 8));
      float ls = 0.f;
      #pragma unroll
      for (int ct = 0; ct < 10; ++ct) {
        float e = expf(s[mt][ct][r] - mx);
        s[mt][ct][r] = e;
        ls += e;
      }
      ls += __shfl_xor(ls, 1);
      ls += __shfl_xor(ls, 2);
      ls += __shfl_xor(ls, 4);
      ls += __shfl_xor(ls, 8);
      if (t16 == 0) lrow[wr + mt * 16 + quad * 4 + r] = 1.f / ls;
      #pragma unroll
      for (int ct = 0; ct < 10; ++ct)
        Ps[(wr + mt * 16 + quad * 4 + r) * 168 + ct * 16 + t16] = f2b(s[mt][ct][r]);
    }
  }
  __syncthreads();

  f32x4 oacc[2][2];
  #pragma unroll
  for (int i = 0; i < 2; ++i)
    #pragma unroll
    for (int j = 0; j < 2; ++j)
      oacc[i][j] = (f32x4){0.f, 0.f, 0.f, 0.f};
  #pragma unroll
  for (int kstep = 0; kstep < 5; ++kstep) {
    bf16x8 bV0 = *(const bf16x8*)&VT[( 0 + t16) * 168 + kstep * 32 + k8];
    bf16x8 bV1 = *(const bf16x8*)&VT[(16 + t16) * 168 + kstep * 32 + k8];
    #pragma unroll
    for (int mt = 0; mt < 2; ++mt) {
      bf16x8 aP = *(const bf16x8*)&Ps[(wr + mt * 16 + t16) * 168 + kstep * 32 + k8];
      oacc[mt][0] = __builtin_amdgcn_mfma_f32_16x16x32_bf16(aP, bV0, oacc[mt][0], 0, 0, 0);
      oacc[mt][1] = __builtin_amdgcn_mfma_f32_16x16x32_bf16(aP, bV1, oacc[mt][1], 0, 0, 0);
    }
  }
  #pragma unroll
  for (int mt = 0; mt < 2; ++mt) {
    #pragma unroll
    for (int nt = 0; nt < 2; ++nt) {
      const int d = nt * 16 + t16;
      #pragma unroll
      for (int r = 0; r < 4; ++r) {
        const int row = wr + mt * 16 + quad * 4 + r;
        o[((size_t)b * 4096 + n0 + row) * 256 + h * 32 + d] = oacc[mt][nt][r] * lrow[row];
      }
    }
  }
}

// ---------------- dst = res + LN(src), wave-per-row (row=256 cols) ----------------
__global__ __launch_bounds__(256) void ln_res(
    const float* __restrict__ src, const float* __restrict__ res,
    const float* __restrict__ nw, const float* __restrict__ nb, float* __restrict__ dst)
{
  const int wave = threadIdx.x >> 6;
  const int lane = threadIdx.x & 63;
  const size_t row = (size_t)blockIdx.x * 4 + wave;
  const int c = lane * 4;
  float4 v = *(const float4*)&src[row * 256 + c];
  float s  = v.x + v.y + v.z + v.w;
  float s2 = v.x * v.x + v.y * v.y + v.z * v.z + v.w * v.w;
  #pragma unroll
  for (int off = 1; off < 64; off <<= 1) {
    s  += __shfl_xor(s, off);
    s2 += __shfl_xor(s2, off);
  }
  const float mu = s * (1.f / 256.f);
  const float var = s2 * (1.f / 256.f) - mu * mu;
  const float inv = rsqrtf(var + 1e-5f);
  float4 w = *(const float4*)&nw[c];
  float4 bb = *(const float4*)&nb[c];
  float4 rr = *(const float4*)&res[row * 256 + c];
  float4 d;
  d.x = rr.x + (v.x - mu) * inv * w.x + bb.x;
  d.y = rr.y + (v.y - mu) * inv * w.y + bb.y;
  d.z = rr.z + (v.z - mu) * inv * w.z + bb.z;
  d.w = rr.w + (v.w - mu) * inv * w.w + bb.w;
  *(float4*)&dst[row * 256 + c] = d;
}

// ---------------- transpose depthwise weights: wt[tap][1024] = w[ch][tap] ----------------
__global__ __launch_bounds__(256) void conv_wt(
    const float* __restrict__ w, float* __restrict__ wt)
{
  int i = blockIdx.x * 256 + threadIdx.x;
  if (i < 9216) {
    int ch = i / 9, tap = i - ch * 9;
    wt[tap * 1024 + ch] = w[i];
  }
}

// ---------------- depthwise 3x3 conv + bias + exact gelu (float4 channels) ----------------
__global__ __launch_bounds__(256) void conv_gelu(
    const float* __restrict__ h, const float* __restrict__ wt, const float* __restrict__ bias,
    float* __restrict__ hc)
{
  const int pix = blockIdx.x;
  const int b = pix >> 12;
  const int n = pix & 4095;
  const int y = n >> 6, xx = n & 63;
  const int c4 = threadIdx.x * 4;
  float4 acc = *(const float4*)&bias[c4];
  const float* hb = h + ((size_t)b * 4096) * 1024 + c4;
  #pragma unroll
  for (int dy = 0; dy < 3; ++dy) {
    const int yy = y + dy - 1;
    if (yy < 0 || yy > 63) continue;
    #pragma unroll
    for (int dx = 0; dx < 3; ++dx) {
      const int xv = xx + dx - 1;
      if (xv < 0 || xv > 63) continue;
      float4 hv = *(const float4*)&hb[(size_t)(yy * 64 + xv) * 1024];
      float4 wv = *(const float4*)&wt[(dy * 3 + dx) * 1024 + c4];
      acc.x = fmaf(hv.x, wv.x, acc.x);
      acc.y = fmaf(hv.y, wv.y, acc.y);
      acc.z = fmaf(hv.z, wv.z, acc.z);
      acc.w = fmaf(hv.w, wv.w, acc.w);
    }
  }
  float4 g;
  g.x = 0.5f * acc.x * (1.f + erff(acc.x * 0.70710678118654752f));
  g.y = 0.5f * acc.y * (1.f + erff(acc.y * 0.70710678118654752f));
  g.z = 0.5f * acc.z * (1.f + erff(acc.z * 0.70710678118654752f));
  g.w = 0.5f * acc.w * (1.f + erff(acc.w * 0.70710678118654752f));
  *(float4*)&hc[((size_t)b * 4096 + n) * 1024 + c4] = g;
}

extern "C" void kernel_launch(void* const* d_in, const int* in_sizes, int n_in,
                              void* d_out, int out_size, void* d_ws, size_t ws_size,
                              hipStream_t stream)
{
  (void)in_sizes; (void)n_in; (void)out_size; (void)ws_size;
  const float* x    = (const float*)d_in[0];
  const float* z    = (const float*)d_in[1];
  const float* mem  = (const float*)d_in[2];
  const float* cw   = (const float*)d_in[3];
  const float* p1   = (const float*)d_in[4];
  const float* tdt1 = (const float*)d_in[5];
  const float* p2   = (const float*)d_in[6];
  const float* tdt2 = (const float*)d_in[7];
  const float* sal  = (const float*)d_in[8];
  const float* sbe  = (const float*)d_in[9];
  const float* q_w  = (const float*)d_in[10];
  const float* q_b  = (const float*)d_in[11];
  const float* k_w  = (const float*)d_in[12];
  const float* k_b  = (const float*)d_in[13];
  const float* v_w  = (const float*)d_in[14];
  const float* v_b  = (const float*)d_in[15];
  const float* pj_w = (const float*)d_in[16];
  const float* pj_b = (const float*)d_in[17];
  const float* nw   = (const float*)d_in[18];
  const float* nb   = (const float*)d_in[19];
  const float* f1w  = (const float*)d_in[20];
  const float* f1b  = (const float*)d_in[21];
  const float* dww  = (const float*)d_in[22];
  const float* dwb  = (const float*)d_in[23];
  const float* f2w  = (const float*)d_in[24];
  const float* f2b_ = (const float*)d_in[25];

  float* out = (float*)d_out;                  // (2,4096,256)
  float* csz = out + 2097152;                  // (2,150,16384)
  float* asg = csz + 4915200;                  // (2,4,150,4096)

  float* ws    = (float*)d_ws;
  float* clr   = ws;                 // 5,242,880 floats, dead after gemm_csz
  short* ecsz  = (short*)ws;         // 5,242,880 shorts (reuses clr region after csz done)
  float* coscl = ws + 5242880;
  float* cosz  = ws + 5275648;
  float* lr_   = ws + 5308416;       // 1,200
  float* cen   = ws + 5310816;       // 307,200
  float* cin   = ws + 5618016;       // 76,800
  float* q     = ws + 5694816;       // 2,097,152
  float* ksb   = ws + 7791968;       // 76,800
  float* vsb   = ws + 7868768;       // 76,800
  float* o     = ws + 7945568;       // 2,097,152
  float* h     = ws;                 // 8,388,608 reuse (ecsz dead by step 10)
  float* hc    = ws + 8388608;
  float* tmp   = ws + 16777216;
  float* out1  = ws + 18874368;
  float* wt    = ws + 20971520;      // 9,216

  dim3 blk(256);
  // 1. cl (row-major) = xf @ cw^T   [MFMA]
  gemm_cl_mfma<<<dim3(256, 3), blk, 0, stream>>>(x, mem, cw, clr);
  // 2. cosine clip factors
  cos_stats<<<dim3(128, 2), blk, 0, stream>>>(z, clr, p1, p2, cosz, coscl);
  // 3. cluster_x_z + assigned   [MFMA, K=320]
  gemm_csz_mfma<<<dim3(256, 3), blk, 0, stream>>>(clr, z, coscl, cosz, tdt2, tdt1, csz, asg);
  // 4. softmax stats + exp(csz-m) materialized bf16 (clr region is dead now)
  softmax_stats_e<<<dim3(1200), blk, 0, stream>>>(csz, lr_, ecsz);
  // 5. cen numerators via MFMA + atomics (cen zeroed first)
  hipMemsetAsync(cen, 0, (size_t)1200 * 256 * sizeof(float), stream);
  gemm_cen_at<<<dim3(2, 8, 16), blk, 0, stream>>>(ecsz, x, mem, cen);
  // 6. gate + LN -> C_in (divides by lr)
  gate_ln<<<dim3(300), blk, 0, stream>>>(cen, lr_, sal, sbe, nw, nb, cin);
  // 7. q/k/v
  gemm_mfma<<<dim3(64, 4), blk, 0, stream>>>(x, q_w, q_b, q, 8192, 256, 256, 0.17677669529663687f);
  gemm_nt<<<dim3(3, 4), blk, 0, stream>>>(cin, k_w, k_b, ksb, 300, 256, 256, 1.f);
  gemm_nt<<<dim3(3, 4), blk, 0, stream>>>(cin, v_w, v_b, vsb, 300, 256, 256, 1.f);
  // 8. attention [MFMA]
  attn_mfma<<<dim3(512), blk, 0, stream>>>(q, ksb, vsb, o);
  // 9. proj + LN + residual
  gemm_mfma<<<dim3(64, 4), blk, 0, stream>>>(o, pj_w, pj_b, tmp, 8192, 256, 256, 1.f);
  ln_res<<<dim3(2048), blk, 0, stream>>>(tmp, x, nw, nb, out1);
  // 10. MLP
  gemm_mfma<<<dim3(64, 16), blk, 0, stream>>>(out1, f1w, f1b, h, 8192, 1024, 256, 1.f);
  conv_wt<<<dim3(36), blk, 0, stream>>>(dww, wt);
  conv_gelu<<<dim3(8192), blk, 0, stream>>>(h, wt, dwb, hc);
  gemm_mfma<<<dim3(64, 4), blk, 0, stream>>>(hc, f2w, f2b_, tmp, 8192, 256, 1024, 1.f);
  ln_res<<<dim3(2048), blk, 0, stream>>>(tmp, out1, nw, nb, out);
}